// Round 12
// baseline (159.316 us; speedup 1.0000x reference)
//
#include <hip/hip_runtime.h>
#include <cstdint>
#include <cstddef>

#define G 256
#define EPER 4096
#define F 128
#define TILE_U32 16384  // fragment tile: 16 ko * 128 row * 8 j (u32 each)

typedef __attribute__((ext_vector_type(8))) short short8;
typedef __attribute__((ext_vector_type(4))) float f32x4;

__device__ inline unsigned short f2bf(float f) {
    unsigned u = __float_as_uint(f);
    u += 0x7FFFu + ((u >> 16) & 1u);
    return (unsigned short)(u >> 16);
}
__device__ inline float bf2f(unsigned short b) { return __uint_as_float(((unsigned)b) << 16); }

// -------------------- W pre-split: [Wr;Wl] -> fragment-major bf16 hi/lo --------------------
// Per stage (shorts): hi[32 ko][128 col][8 j] at s*65536, lo at s*65536+32768.
__global__ __launch_bounds__(256) void k_wsplit(const float* __restrict__ Wr1, const float* __restrict__ Wl1,
                                                const float* __restrict__ Wr2, const float* __restrict__ Wl2,
                                                const float* __restrict__ Wr3, const float* __restrict__ Wl3,
                                                unsigned short* __restrict__ Wf) {
    int gid = blockIdx.x * 256 + threadIdx.x;   // 0..98303
    int s = gid >> 15;
    int idx = gid & 32767;
    int j = idx & 7, col = (idx >> 3) & 127, ko = idx >> 10;
    int k = ko * 8 + j;
    const float* Wr = (s == 0) ? Wr1 : (s == 1) ? Wr2 : Wr3;
    const float* Wl = (s == 0) ? Wl1 : (s == 1) ? Wl2 : Wl3;
    float f = (k < 128) ? Wr[(size_t)k * 128 + col] : Wl[(size_t)(k - 128) * 128 + col];
    unsigned short h1 = f2bf(f), h2 = f2bf(f - bf2f(h1));
    Wf[(size_t)s * 65536 + idx] = h1;
    Wf[(size_t)s * 65536 + 32768 + idx] = h2;
}

// -------------------- aggregation: agg = Adj @ x on MFMA --------------------
// Adj counts exact in bf16; x consumed as 2-way bf16 split (2^-17 rel).
// Stage 1 splits f32 x in VALU; stages 2/3 read pre-packed pooled rows (XF).
// Output written as packed (hi|lo) u32 in gemm-fragment layout AGGF[tile][ko][row][j],
// tile = global_m >> 7 with global_m = g*NS + node.
template<int NS, int BM, bool USE_MAP>
__global__ __launch_bounds__(256) void k_agg(const float* __restrict__ X,
                                             const int* __restrict__ src,
                                             const int* __restrict__ dst,
                                             const int* __restrict__ cmap,
                                             const unsigned* __restrict__ XF,
                                             unsigned* __restrict__ AGGF) {
    constexpr bool SPLIT = (NS > BM);
    constexpr int RW = BM / 4;
    constexpr int MT = RW / 16;
    constexpr int NS4 = NS / 4;
    __shared__ unsigned adjc[BM * NS4];
    __shared__ short adjT[4 * BM * 8];
    __shared__ short xs[2][4 * 128 * 8];
    __shared__ int smap[256];

    const int b = blockIdx.x, t = threadIdx.x;
    const int g = SPLIT ? (b >> 1) : b;
    const int mbase = SPLIT ? (b & 1) * BM : 0;

    {
        uint4* z = (uint4*)adjc;
        #pragma unroll
        for (int i = t; i < BM * NS4 / 4; i += 256) z[i] = uint4{0, 0, 0, 0};
    }
    if (USE_MAP) smap[t] = cmap[g * 256 + t];
    __syncthreads();

    const int* sg = src + (size_t)g * EPER;
    const int* dg = dst + (size_t)g * EPER;
    #pragma unroll 4
    for (int j = 0; j < 16; ++j) {
        int e = j * 256 + t;
        int s = sg[e], d = dg[e];
        if (USE_MAP) { s = smap[s]; d = smap[d]; }
        int m = d - mbase;
        if (s >= 0 && (unsigned)m < (unsigned)BM) {
            int pos = (s + 4 * m) & (NS - 1);
            __hip_atomic_fetch_add(&adjc[m * NS4 + (pos >> 2)], 1u << ((pos & 3) * 8),
                                   __ATOMIC_RELAXED, __HIP_MEMORY_SCOPE_WORKGROUP);
        }
    }

    f32x4 acc[MT][8];
    #pragma unroll
    for (int i = 0; i < MT; ++i)
        #pragma unroll
        for (int c = 0; c < 8; ++c) acc[i][c] = f32x4{0.f, 0.f, 0.f, 0.f};

    const int lane = t & 63, wv = t >> 6;
    constexpr int TPR = 256 / BM;
    constexpr int CPT = 32 / TPR;
    const int mA = t / TPR, kgA = (t % TPR) * CPT;
    const int nX = t & 127, kgX = (t >> 7) * 16;
    const size_t colb = (size_t)(nX >> 3) * 1024 + (nX & 7);

    for (int k0 = 0; k0 < NS; k0 += 32) {
        __syncthreads();
        // --- convert adj u8 tile -> bf16 [koct][m][8k] ---
        {
            unsigned short cs[CPT];
            #pragma unroll
            for (int q = 0; q < CPT / 4; ++q) {
                unsigned w = adjc[mA * NS4 + ((((k0 + kgA) >> 2) + mA + q) & (NS4 - 1))];
                cs[q * 4 + 0] = f2bf((float)(w & 255u));
                cs[q * 4 + 1] = f2bf((float)((w >> 8) & 255u));
                cs[q * 4 + 2] = f2bf((float)((w >> 16) & 255u));
                cs[q * 4 + 3] = f2bf((float)(w >> 24));
            }
            #pragma unroll
            for (int c = 0; c < CPT / 8; ++c) {
                short8 w8;
                #pragma unroll
                for (int j = 0; j < 8; ++j) w8[j] = (short)cs[c * 8 + j];
                *(short8*)&adjT[((kgA >> 3) + c) * BM * 8 + mA * 8] = w8;
            }
        }
        // --- stage x rows k0..k0+31 as 2-way bf16 split ---
        if constexpr (USE_MAP) {
            #pragma unroll
            for (int c = 0; c < 2; ++c) {
                short8 h1, h2;
                #pragma unroll
                for (int j = 0; j < 8; ++j) {
                    int m_in = g * NS + k0 + kgX + c * 8 + j;
                    unsigned w = XF[(size_t)(m_in >> 7) * TILE_U32 + colb + (size_t)(m_in & 127) * 8];
                    h1[j] = (short)(w & 0xffffu);
                    h2[j] = (short)(w >> 16);
                }
                int ko = (kgX >> 3) + c;
                *(short8*)&xs[0][ko * 1024 + nX * 8] = h1;
                *(short8*)&xs[1][ko * 1024 + nX * 8] = h2;
            }
        } else {
            float v[16];
            #pragma unroll
            for (int i = 0; i < 16; ++i)
                v[i] = X[(size_t)g * 32768 + (size_t)(k0 + kgX + i) * F + nX];
            #pragma unroll
            for (int c = 0; c < 2; ++c) {
                short8 h1, h2;
                #pragma unroll
                for (int j = 0; j < 8; ++j) {
                    float f = v[c * 8 + j];
                    unsigned short a1 = f2bf(f);
                    unsigned short a2 = f2bf(f - bf2f(a1));
                    h1[j] = (short)a1; h2[j] = (short)a2;
                }
                int ko = (kgX >> 3) + c;
                *(short8*)&xs[0][ko * 1024 + nX * 8] = h1;
                *(short8*)&xs[1][ko * 1024 + nX * 8] = h2;
            }
        }
        __syncthreads();
        short8 afr[MT];
        #pragma unroll
        for (int mt = 0; mt < MT; ++mt)
            afr[mt] = *(const short8*)&adjT[(lane >> 4) * BM * 8 + (wv * RW + mt * 16 + (lane & 15)) * 8];
        #pragma unroll
        for (int s = 0; s < 2; ++s) {
            #pragma unroll
            for (int ct = 0; ct < 8; ++ct) {
                short8 bfr = *(const short8*)&xs[s][(lane >> 4) * 1024 + (ct * 16 + (lane & 15)) * 8];
                #pragma unroll
                for (int mt = 0; mt < MT; ++mt)
                    acc[mt][ct] = __builtin_amdgcn_mfma_f32_16x16x32_bf16(afr[mt], bfr, acc[mt][ct], 0, 0, 0);
            }
        }
    }

    // epilogue: pack to (hi|lo) u32 in fragment layout
    #pragma unroll
    for (int mt = 0; mt < MT; ++mt) {
        int r0 = mbase + wv * RW + mt * 16 + (lane >> 4) * 4;
        #pragma unroll
        for (int ct = 0; ct < 8; ++ct) {
            int feat = ct * 16 + (lane & 15);
            size_t fb = (size_t)(feat >> 3) * 1024 + (feat & 7);
            #pragma unroll
            for (int r = 0; r < 4; ++r) {
                int m = g * NS + r0 + r;
                float v = acc[mt][ct][r];
                unsigned short hi = f2bf(v);
                unsigned short lo = f2bf(v - bf2f(hi));
                AGGF[(size_t)(m >> 7) * TILE_U32 + fb + (size_t)(m & 127) * 8] =
                    (unsigned)hi | ((unsigned)lo << 16);
            }
        }
    }
}

// -------------------- conv GEMM on MFMA: h = relu([X | AGG] @ [Wr;Wl] + b) -----------
// 512 threads / 8 waves, wave tile 32x64. LDS 80 KB (Whi 64 + A-tile 16) -> 2 blocks/CU.
// W-lo streamed from L2. A-operand: stage1 kt<4 = f32 X + in-VALU 2-split;
// all other kt = coalesced uint4 copy from packed XF/AGGF + trivial unpack.
// 3 MFMA passes (a1w1 + a2w1 + a1w2).
template<int NS, bool FIRST>
__global__ __launch_bounds__(512, 4) void k_gemm(const float* __restrict__ X,
                                                 float* __restrict__ A,
                                                 const unsigned* __restrict__ AGGF,
                                                 const unsigned* __restrict__ XF,
                                                 const unsigned short* __restrict__ Wf,
                                                 const float* __restrict__ bias) {
    constexpr int L2NS = (NS == 256) ? 8 : (NS == 128) ? 7 : 6;
    __shared__ uint4 Whi[32][128];     // 64 KB
    __shared__ uint4 Afs[2][4][128];   // 16 KB
    const int t = threadIdx.x;
    const int m0 = blockIdx.x * 128;
    const int lane = t & 63;
    const int wv = t >> 6, wr = wv >> 1, wc = wv & 1;
    const int l15 = lane & 15, lko = lane >> 4;
    const unsigned short* Wlo = Wf + 32768;

    // prologue: coalesced copy of pre-split W-hi fragments into LDS
    {
        const uint4* Wf4 = (const uint4*)Wf;
        uint4* Wd = (uint4*)Whi;
        #pragma unroll
        for (int i = 0; i < 8; ++i) Wd[t + i * 512] = Wf4[t + i * 512];
    }

    f32x4 acc[2][4];
    #pragma unroll
    for (int i = 0; i < 2; ++i)
        #pragma unroll
        for (int c = 0; c < 4; ++c) acc[i][c] = f32x4{0.f, 0.f, 0.f, 0.f};

    // staging maps: f32 path (rs, ck); packed path (rowp, kop)
    const int rs = t >> 2, ck = t & 3;
    const int rowp = t & 127, kop = t >> 7;
    const float* xrow = FIRST ? (X + (size_t)(m0 + rs) * F) : nullptr;

    for (int kt = 0; kt < 8; ++kt) {
        __syncthreads();  // prev-iter readers done (kt=0: fences Whi copy)
        if (FIRST && kt < 4) {
            const float* srow = xrow + kt * 32 + ck * 8;
            float4 fa = *(const float4*)srow;
            float4 fb = *(const float4*)(srow + 4);
            float vv[8] = {fa.x, fa.y, fa.z, fa.w, fb.x, fb.y, fb.z, fb.w};
            short8 h1, h2;
            #pragma unroll
            for (int j = 0; j < 8; ++j) {
                unsigned short a1 = f2bf(vv[j]);
                unsigned short a2 = f2bf(vv[j] - bf2f(a1));
                h1[j] = (short)a1; h2[j] = (short)a2;
            }
            int rw = rs ^ (ck << 2);
            *reinterpret_cast<short8*>(&Afs[0][ck][rw]) = h1;
            *reinterpret_cast<short8*>(&Afs[1][ck][rw]) = h2;
        } else {
            const unsigned* P = (kt < 4) ? XF : AGGF;
            int ko = (kt & 3) * 4 + kop;
            size_t idx = (size_t)blockIdx.x * TILE_U32 + (size_t)ko * 1024 + (size_t)rowp * 8;
            uint4 qa = *(const uint4*)(P + idx);
            uint4 qb = *(const uint4*)(P + idx + 4);
            short8 h1, h2;
            h1[0] = (short)qa.x; h2[0] = (short)(qa.x >> 16);
            h1[1] = (short)qa.y; h2[1] = (short)(qa.y >> 16);
            h1[2] = (short)qa.z; h2[2] = (short)(qa.z >> 16);
            h1[3] = (short)qa.w; h2[3] = (short)(qa.w >> 16);
            h1[4] = (short)qb.x; h2[4] = (short)(qb.x >> 16);
            h1[5] = (short)qb.y; h2[5] = (short)(qb.y >> 16);
            h1[6] = (short)qb.z; h2[6] = (short)(qb.z >> 16);
            h1[7] = (short)qb.w; h2[7] = (short)(qb.w >> 16);
            int rw = rowp ^ (kop << 2);
            *reinterpret_cast<short8*>(&Afs[0][kop][rw]) = h1;
            *reinterpret_cast<short8*>(&Afs[1][kop][rw]) = h2;
        }
        __syncthreads();

        short8 a1f[2], a2f[2];
        #pragma unroll
        for (int mt = 0; mt < 2; ++mt) {
            int row = (wr * 32 + mt * 16 + l15) ^ (lko << 2);
            a1f[mt] = *reinterpret_cast<const short8*>(&Afs[0][lko][row]);
            a2f[mt] = *reinterpret_cast<const short8*>(&Afs[1][lko][row]);
        }
        const int kog = kt * 4 + lko;
        #pragma unroll
        for (int ct = 0; ct < 4; ++ct) {
            int col = wc * 64 + ct * 16 + l15;
            short8 w1 = *reinterpret_cast<const short8*>(&Whi[kog][col]);
            short8 w2 = *reinterpret_cast<const short8*>(Wlo + ((size_t)kog * 128 + col) * 8);
            #pragma unroll
            for (int mt = 0; mt < 2; ++mt) {
                acc[mt][ct] = __builtin_amdgcn_mfma_f32_16x16x32_bf16(a1f[mt], w1, acc[mt][ct], 0, 0, 0);
                acc[mt][ct] = __builtin_amdgcn_mfma_f32_16x16x32_bf16(a2f[mt], w1, acc[mt][ct], 0, 0, 0);
                acc[mt][ct] = __builtin_amdgcn_mfma_f32_16x16x32_bf16(a1f[mt], w2, acc[mt][ct], 0, 0, 0);
            }
        }
    }

    // epilogue: D col=lane&15 (per ct), row=(lane>>4)*4+reg
    #pragma unroll
    for (int ct = 0; ct < 4; ++ct) {
        int col = wc * 64 + ct * 16 + l15;
        float bv = bias[col];
        #pragma unroll
        for (int mt = 0; mt < 2; ++mt) {
            int r0 = m0 + wr * 32 + mt * 16 + lko * 4;
            #pragma unroll
            for (int r = 0; r < 4; ++r) {
                int m = r0 + r;
                int gg = m >> L2NS, nn = m & (NS - 1);
                A[(size_t)gg * 32768 + (size_t)nn * F + col] = fmaxf(acc[mt][ct][r] + bv, 0.f);
            }
        }
    }
}

// -------------------- top-k pool + readout + cmap update (1024 threads) --------------------
// Pooled rows written as packed (hi|lo) u32 fragments into XF (consumed by next
// stage's gemm kt<4 and agg x-staging).
template<int N, int K, int STAGE>
__global__ __launch_bounds__(1024) void k_pool(float* __restrict__ A,
                                               float* __restrict__ R,
                                               int* __restrict__ cmap,
                                               const float* __restrict__ wp,
                                               unsigned* __restrict__ XF) {
    __shared__ float sc[N];
    __shared__ unsigned long long keys[N];
    __shared__ float hp[K * F];
    __shared__ int sel[K];
    __shared__ int inv[N];
    __shared__ float wn[F];
    __shared__ float gates[K];
    __shared__ float pmx[8 * F];
    __shared__ float psm[8 * F];
    __shared__ float snorm_s;
    const int g = blockIdx.x, t = threadIdx.x;
    const float* h = A + (size_t)g * 32768;
    const int lane = t & 63, wv16 = t >> 6;

    if (t < 64) {
        float v = wp[t] * wp[t] + wp[t + 64] * wp[t + 64];
        #pragma unroll
        for (int o = 32; o; o >>= 1) v += __shfl_xor(v, o);
        if (t == 0) snorm_s = sqrtf(v);
    }
    __syncthreads();
    if (t < 128) wn[t] = wp[t] / snorm_s;
    __syncthreads();

    {
        const int r16 = lane >> 4, l16 = lane & 15;
        float4 w0 = *(const float4*)&wn[l16 * 8];
        float4 w1 = *(const float4*)&wn[l16 * 8 + 4];
        #pragma unroll
        for (int n0 = 0; n0 < N; n0 += 64) {
            int r = n0 + wv16 * 4 + r16;
            const float* hr = h + (size_t)r * F + l16 * 8;
            float4 v0 = *(const float4*)hr;
            float4 v1 = *(const float4*)(hr + 4);
            float p = v0.x * w0.x + v0.y * w0.y + v0.z * w0.z + v0.w * w0.w
                    + v1.x * w1.x + v1.y * w1.y + v1.z * w1.z + v1.w * w1.w;
            p += __shfl_xor(p, 1); p += __shfl_xor(p, 2);
            p += __shfl_xor(p, 4); p += __shfl_xor(p, 8);
            if (l16 == 0) sc[r] = p;
        }
    }
    __syncthreads();

    if (t < N) {
        unsigned u = __float_as_uint(sc[t]);
        u = (u & 0x80000000u) ? ~u : (u | 0x80000000u);
        keys[t] = ((unsigned long long)u << 32) | (unsigned)(~t);
    }
    __syncthreads();
    for (int kk = 2; kk <= N; kk <<= 1) {
        for (int j = kk >> 1; j > 0; j >>= 1) {
            if (t < N) {
                int ixj = t ^ j;
                if (ixj > t) {
                    unsigned long long a = keys[t], b = keys[ixj];
                    bool up = (t & kk) == 0;
                    if (up ? (a < b) : (a > b)) { keys[t] = b; keys[ixj] = a; }
                }
            }
            __syncthreads();
        }
    }

    if (t < K) sel[t] = (int)(~(unsigned)keys[t]);
    if (t < N) inv[t] = -1;
    __syncthreads();
    if (t < K) {
        inv[sel[t]] = t;
        gates[t] = tanhf(sc[sel[t]]);
    }
    __syncthreads();
    if (t < 256) {
        int c = (STAGE == 1) ? t : cmap[g * 256 + t];
        cmap[g * 256 + t] = (c >= 0) ? inv[c] : -1;
    }

    {
        const int f = t & 127, seg = t >> 7;
        float mx = -INFINITY, sm = 0.f;
        for (int j = seg; j < K; j += 8) {
            float v = h[(size_t)sel[j] * F + f] * gates[j];
            hp[j * F + f] = v;
            mx = fmaxf(mx, v);
            sm += v;
        }
        pmx[seg * F + f] = mx;
        psm[seg * F + f] = sm;
    }
    __syncthreads();

    if (t < 128) {
        float m = -INFINITY, s = 0.f;
        #pragma unroll
        for (int q = 0; q < 8; ++q) {
            m = fmaxf(m, pmx[q * F + t]);
            s += psm[q * F + t];
        }
        R[(size_t)g * 768 + (STAGE - 1) * 256 + t] = m;
        R[(size_t)g * 768 + (STAGE - 1) * 256 + 128 + t] = s * (1.0f / K);
    }

    if (STAGE < 3) {
        for (int i = t; i < K * F; i += 1024) {
            int j = i >> 7, f = i & 127;
            float v = hp[j * F + f];
            unsigned short hi = f2bf(v);
            unsigned short lo = f2bf(v - bf2f(hi));
            int m = g * K + j;
            XF[(size_t)(m >> 7) * TILE_U32 + (size_t)(f >> 3) * 1024 + (size_t)(m & 127) * 8 + (f & 7)] =
                (unsigned)hi | ((unsigned)lo << 16);
        }
    }
}

// -------------------- final MLP + log_softmax (split-K, 1024 threads) --------------------
__global__ __launch_bounds__(1024) void k_mlp(const float* __restrict__ R,
                                              const float* __restrict__ W1, const float* __restrict__ b1,
                                              const float* __restrict__ W2, const float* __restrict__ b2,
                                              const float* __restrict__ W3, const float* __restrict__ b3,
                                              float* __restrict__ out) {
    __shared__ float z[768];
    __shared__ float part[8][128];
    __shared__ float z2[128];
    __shared__ float z3[64];
    __shared__ float lg[10];
    __shared__ float lse;
    const int g = blockIdx.x, t = threadIdx.x;

    if (t < 768) z[t] = R[(size_t)g * 768 + t];
    __syncthreads();

    {
        const int f = t & 127, seg = t >> 7;
        float acc = 0.f;
        const float* w = W1 + (size_t)(seg * 96) * 128 + f;
        const float* zz = z + seg * 96;
        #pragma unroll 8
        for (int k = 0; k < 96; ++k) acc = fmaf(zz[k], w[(size_t)k * 128], acc);
        part[seg][f] = acc;
    }
    __syncthreads();
    if (t < 128) {
        float a = b1[t];
        #pragma unroll
        for (int q = 0; q < 8; ++q) a += part[q][t];
        z2[t] = fmaxf(a, 0.f);
    }
    __syncthreads();

    if (t < 512) {
        const int f = t & 63, seg = t >> 6;
        float acc = 0.f;
        const float* w = W2 + (size_t)(seg * 16) * 64 + f;
        const float* zz = z2 + seg * 16;
        #pragma unroll
        for (int k = 0; k < 16; ++k) acc = fmaf(zz[k], w[(size_t)k * 64], acc);
        part[seg][f] = acc;
    }
    __syncthreads();
    if (t < 64) {
        float a = b2[t];
        #pragma unroll
        for (int q = 0; q < 8; ++q) a += part[q][t];
        z3[t] = fmaxf(a, 0.f);
    }
    __syncthreads();

    if (t < 10) {
        float a3 = b3[t];
        #pragma unroll 8
        for (int k = 0; k < 64; ++k) a3 = fmaf(z3[k], W3[(size_t)k * 10 + t], a3);
        lg[t] = a3;
    }
    __syncthreads();

    if (t == 0) {
        float m = lg[0];
        for (int c = 1; c < 10; ++c) m = fmaxf(m, lg[c]);
        float s = 0.f;
        for (int c = 0; c < 10; ++c) s += expf(lg[c] - m);
        lse = m + logf(s);
    }
    __syncthreads();
    if (t < 10) out[(size_t)g * 10 + t] = lg[t] - lse;
}

extern "C" void kernel_launch(void* const* d_in, const int* in_sizes, int n_in,
                              void* d_out, int out_size, void* d_ws, size_t ws_size,
                              hipStream_t stream) {
    (void)in_sizes; (void)n_in; (void)out_size; (void)ws_size;
    const float* x    = (const float*)d_in[0];
    const int*   src  = (const int*)d_in[1];
    const int*   dst  = (const int*)d_in[2];
    const float* Wr1  = (const float*)d_in[3];
    const float* Wrel1= (const float*)d_in[4];
    const float* b1   = (const float*)d_in[5];
    const float* wp1  = (const float*)d_in[6];
    const float* Wr2  = (const float*)d_in[7];
    const float* Wrel2= (const float*)d_in[8];
    const float* b2   = (const float*)d_in[9];
    const float* wp2  = (const float*)d_in[10];
    const float* Wr3  = (const float*)d_in[11];
    const float* Wrel3= (const float*)d_in[12];
    const float* b3   = (const float*)d_in[13];
    const float* wp3  = (const float*)d_in[14];
    const float* L1w  = (const float*)d_in[15];
    const float* L1b  = (const float*)d_in[16];
    const float* L2w  = (const float*)d_in[17];
    const float* L2b  = (const float*)d_in[18];
    const float* L3w  = (const float*)d_in[19];
    const float* L3b  = (const float*)d_in[20];

    float*    A    = (float*)d_ws;                               // G*32768 f32 (h)
    int*      cmap = (int*)(A + (size_t)G * 32768);              // G*256 i32
    float*    R    = (float*)(cmap + (size_t)G * 256);           // G*768 f32
    unsigned* AGGF = (unsigned*)(R + (size_t)G * 768);           // G*2 tiles * 16384 u32
    unsigned* XF   = AGGF + (size_t)G * 2 * TILE_U32;            // G tiles * 16384 u32
    unsigned short* Wf = (unsigned short*)(XF + (size_t)G * TILE_U32);  // 3*65536 shorts
    float* out = (float*)d_out;

    // W pre-split (once per launch, all 3 stages)
    k_wsplit<<<384, 256, 0, stream>>>(Wr1, Wrel1, Wr2, Wrel2, Wr3, Wrel3, Wf);

    // stage 1
    k_agg<256, 128, false><<<G * 2, 256, 0, stream>>>(x, src, dst, nullptr, nullptr, AGGF);
    k_gemm<256, true><<<512, 512, 0, stream>>>(x, A, AGGF, nullptr, Wf, b1);
    k_pool<256, 128, 1><<<G, 1024, 0, stream>>>(A, R, cmap, wp1, XF);
    // stage 2
    k_agg<128, 128, true><<<G, 256, 0, stream>>>(nullptr, src, dst, cmap, XF, AGGF);
    k_gemm<128, false><<<256, 512, 0, stream>>>(nullptr, A, AGGF, XF, Wf + 65536, b2);
    k_pool<128, 64, 2><<<G, 1024, 0, stream>>>(A, R, cmap, wp2, XF);
    // stage 3
    k_agg<64, 64, true><<<G, 256, 0, stream>>>(nullptr, src, dst, cmap, XF, AGGF);
    k_gemm<64, false><<<128, 512, 0, stream>>>(nullptr, A, AGGF, XF, Wf + 131072, b3);
    k_pool<64, 32, 3><<<G, 1024, 0, stream>>>(A, R, cmap, wp3, XF);
    // head
    k_mlp<<<G, 1024, 0, stream>>>(R, L1w, L1b, L2w, L2b, L3w, L3b, out);
}

// Round 13
// 144.144 us; speedup vs baseline: 1.1053x; 1.1053x over previous
//
#include <hip/hip_runtime.h>
#include <cstdint>
#include <cstddef>

#define G 256
#define EPER 4096
#define F 128
#define TILE_U32 16384  // fragment tile: 16 ko * 128 row * 8 j (u32 each)

typedef __attribute__((ext_vector_type(8))) short short8;
typedef __attribute__((ext_vector_type(4))) float f32x4;

__device__ inline unsigned short f2bf(float f) {
    unsigned u = __float_as_uint(f);
    u += 0x7FFFu + ((u >> 16) & 1u);
    return (unsigned short)(u >> 16);
}
__device__ inline float bf2f(unsigned short b) { return __uint_as_float(((unsigned)b) << 16); }

// -------------------- W pre-split: [Wr;Wl] -> fragment-major bf16 hi/lo --------------------
__global__ __launch_bounds__(256) void k_wsplit(const float* __restrict__ Wr1, const float* __restrict__ Wl1,
                                                const float* __restrict__ Wr2, const float* __restrict__ Wl2,
                                                const float* __restrict__ Wr3, const float* __restrict__ Wl3,
                                                unsigned short* __restrict__ Wf) {
    int gid = blockIdx.x * 256 + threadIdx.x;   // 0..98303
    int s = gid >> 15;
    int idx = gid & 32767;
    int j = idx & 7, col = (idx >> 3) & 127, ko = idx >> 10;
    int k = ko * 8 + j;
    const float* Wr = (s == 0) ? Wr1 : (s == 1) ? Wr2 : Wr3;
    const float* Wl = (s == 0) ? Wl1 : (s == 1) ? Wl2 : Wl3;
    float f = (k < 128) ? Wr[(size_t)k * 128 + col] : Wl[(size_t)(k - 128) * 128 + col];
    unsigned short h1 = f2bf(f), h2 = f2bf(f - bf2f(h1));
    Wf[(size_t)s * 65536 + idx] = h1;
    Wf[(size_t)s * 65536 + 32768 + idx] = h2;
}

// -------------------- stage-1 aggregation: agg = Adj @ x on MFMA --------------------
__global__ __launch_bounds__(256) void k_agg1(const float* __restrict__ X,
                                              const int* __restrict__ src,
                                              const int* __restrict__ dst,
                                              unsigned* __restrict__ AGGF) {
    constexpr int NS = 256, BM = 128, NS4 = NS / 4;
    __shared__ unsigned adjc[BM * NS4];
    __shared__ short adjT[4 * BM * 8];
    __shared__ short xs[2][4 * 128 * 8];

    const int b = blockIdx.x, t = threadIdx.x;
    const int g = b >> 1;
    const int mbase = (b & 1) * BM;

    {
        uint4* z = (uint4*)adjc;
        #pragma unroll
        for (int i = t; i < BM * NS4 / 4; i += 256) z[i] = uint4{0, 0, 0, 0};
    }
    __syncthreads();

    const int* sg = src + (size_t)g * EPER;
    const int* dg = dst + (size_t)g * EPER;
    #pragma unroll 4
    for (int j = 0; j < 16; ++j) {
        int e = j * 256 + t;
        int s = sg[e], d = dg[e];
        int m = d - mbase;
        if ((unsigned)m < (unsigned)BM) {
            int pos = (s + 4 * m) & (NS - 1);
            __hip_atomic_fetch_add(&adjc[m * NS4 + (pos >> 2)], 1u << ((pos & 3) * 8),
                                   __ATOMIC_RELAXED, __HIP_MEMORY_SCOPE_WORKGROUP);
        }
    }

    f32x4 acc[2][8];
    #pragma unroll
    for (int i = 0; i < 2; ++i)
        #pragma unroll
        for (int c = 0; c < 8; ++c) acc[i][c] = f32x4{0.f, 0.f, 0.f, 0.f};

    const int lane = t & 63, wv = t >> 6;
    const int mA = t >> 1, kgA = (t & 1) * 16;
    const int nX = t & 127, kgX = (t >> 7) * 16;

    for (int k0 = 0; k0 < NS; k0 += 32) {
        __syncthreads();
        {
            unsigned short cs[16];
            #pragma unroll
            for (int q = 0; q < 4; ++q) {
                unsigned w = adjc[mA * NS4 + ((((k0 + kgA) >> 2) + mA + q) & (NS4 - 1))];
                cs[q * 4 + 0] = f2bf((float)(w & 255u));
                cs[q * 4 + 1] = f2bf((float)((w >> 8) & 255u));
                cs[q * 4 + 2] = f2bf((float)((w >> 16) & 255u));
                cs[q * 4 + 3] = f2bf((float)(w >> 24));
            }
            #pragma unroll
            for (int c = 0; c < 2; ++c) {
                short8 w8;
                #pragma unroll
                for (int j = 0; j < 8; ++j) w8[j] = (short)cs[c * 8 + j];
                *(short8*)&adjT[((kgA >> 3) + c) * BM * 8 + mA * 8] = w8;
            }
        }
        {
            float v[16];
            #pragma unroll
            for (int i = 0; i < 16; ++i)
                v[i] = X[(size_t)g * 32768 + (size_t)(k0 + kgX + i) * F + nX];
            #pragma unroll
            for (int c = 0; c < 2; ++c) {
                short8 h1, h2;
                #pragma unroll
                for (int j = 0; j < 8; ++j) {
                    float f = v[c * 8 + j];
                    unsigned short a1 = f2bf(f);
                    unsigned short a2 = f2bf(f - bf2f(a1));
                    h1[j] = (short)a1; h2[j] = (short)a2;
                }
                int ko = (kgX >> 3) + c;
                *(short8*)&xs[0][ko * 1024 + nX * 8] = h1;
                *(short8*)&xs[1][ko * 1024 + nX * 8] = h2;
            }
        }
        __syncthreads();
        short8 afr[2];
        #pragma unroll
        for (int mt = 0; mt < 2; ++mt)
            afr[mt] = *(const short8*)&adjT[(lane >> 4) * BM * 8 + (wv * 32 + mt * 16 + (lane & 15)) * 8];
        #pragma unroll
        for (int s = 0; s < 2; ++s) {
            #pragma unroll
            for (int ct = 0; ct < 8; ++ct) {
                short8 bfr = *(const short8*)&xs[s][(lane >> 4) * 1024 + (ct * 16 + (lane & 15)) * 8];
                #pragma unroll
                for (int mt = 0; mt < 2; ++mt)
                    acc[mt][ct] = __builtin_amdgcn_mfma_f32_16x16x32_bf16(afr[mt], bfr, acc[mt][ct], 0, 0, 0);
            }
        }
    }

    #pragma unroll
    for (int mt = 0; mt < 2; ++mt) {
        int r0 = mbase + wv * 32 + mt * 16 + (lane >> 4) * 4;
        #pragma unroll
        for (int ct = 0; ct < 8; ++ct) {
            int feat = ct * 16 + (lane & 15);
            size_t fb = (size_t)(feat >> 3) * 1024 + (feat & 7);
            #pragma unroll
            for (int r = 0; r < 4; ++r) {
                int m = g * NS + r0 + r;
                float v = acc[mt][ct][r];
                unsigned short hi = f2bf(v);
                unsigned short lo = f2bf(v - bf2f(hi));
                AGGF[(size_t)(m >> 7) * TILE_U32 + fb + (size_t)(m & 127) * 8] =
                    (unsigned)hi | ((unsigned)lo << 16);
            }
        }
    }
}

// -------------------- conv GEMM on MFMA (unchanged from R12) --------------------
template<int NS, bool FIRST>
__global__ __launch_bounds__(512, 4) void k_gemm(const float* __restrict__ X,
                                                 float* __restrict__ A,
                                                 const unsigned* __restrict__ AGGF,
                                                 const unsigned* __restrict__ XF,
                                                 const unsigned short* __restrict__ Wf,
                                                 const float* __restrict__ bias) {
    constexpr int L2NS = (NS == 256) ? 8 : (NS == 128) ? 7 : 6;
    __shared__ uint4 Whi[32][128];
    __shared__ uint4 Afs[2][4][128];
    const int t = threadIdx.x;
    const int m0 = blockIdx.x * 128;
    const int lane = t & 63;
    const int wv = t >> 6, wr = wv >> 1, wc = wv & 1;
    const int l15 = lane & 15, lko = lane >> 4;
    const unsigned short* Wlo = Wf + 32768;

    {
        const uint4* Wf4 = (const uint4*)Wf;
        uint4* Wd = (uint4*)Whi;
        #pragma unroll
        for (int i = 0; i < 8; ++i) Wd[t + i * 512] = Wf4[t + i * 512];
    }

    f32x4 acc[2][4];
    #pragma unroll
    for (int i = 0; i < 2; ++i)
        #pragma unroll
        for (int c = 0; c < 4; ++c) acc[i][c] = f32x4{0.f, 0.f, 0.f, 0.f};

    const int rs = t >> 2, ck = t & 3;
    const int rowp = t & 127, kop = t >> 7;
    const float* xrow = FIRST ? (X + (size_t)(m0 + rs) * F) : nullptr;

    for (int kt = 0; kt < 8; ++kt) {
        __syncthreads();
        if (FIRST && kt < 4) {
            const float* srow = xrow + kt * 32 + ck * 8;
            float4 fa = *(const float4*)srow;
            float4 fb = *(const float4*)(srow + 4);
            float vv[8] = {fa.x, fa.y, fa.z, fa.w, fb.x, fb.y, fb.z, fb.w};
            short8 h1, h2;
            #pragma unroll
            for (int j = 0; j < 8; ++j) {
                unsigned short a1 = f2bf(vv[j]);
                unsigned short a2 = f2bf(vv[j] - bf2f(a1));
                h1[j] = (short)a1; h2[j] = (short)a2;
            }
            int rw = rs ^ (ck << 2);
            *reinterpret_cast<short8*>(&Afs[0][ck][rw]) = h1;
            *reinterpret_cast<short8*>(&Afs[1][ck][rw]) = h2;
        } else {
            const unsigned* P = (kt < 4) ? XF : AGGF;
            int ko = (kt & 3) * 4 + kop;
            size_t idx = (size_t)blockIdx.x * TILE_U32 + (size_t)ko * 1024 + (size_t)rowp * 8;
            uint4 qa = *(const uint4*)(P + idx);
            uint4 qb = *(const uint4*)(P + idx + 4);
            short8 h1, h2;
            h1[0] = (short)qa.x; h2[0] = (short)(qa.x >> 16);
            h1[1] = (short)qa.y; h2[1] = (short)(qa.y >> 16);
            h1[2] = (short)qa.z; h2[2] = (short)(qa.z >> 16);
            h1[3] = (short)qa.w; h2[3] = (short)(qa.w >> 16);
            h1[4] = (short)qb.x; h2[4] = (short)(qb.x >> 16);
            h1[5] = (short)qb.y; h2[5] = (short)(qb.y >> 16);
            h1[6] = (short)qb.z; h2[6] = (short)(qb.z >> 16);
            h1[7] = (short)qb.w; h2[7] = (short)(qb.w >> 16);
            int rw = rowp ^ (kop << 2);
            *reinterpret_cast<short8*>(&Afs[0][kop][rw]) = h1;
            *reinterpret_cast<short8*>(&Afs[1][kop][rw]) = h2;
        }
        __syncthreads();

        short8 a1f[2], a2f[2];
        #pragma unroll
        for (int mt = 0; mt < 2; ++mt) {
            int row = (wr * 32 + mt * 16 + l15) ^ (lko << 2);
            a1f[mt] = *reinterpret_cast<const short8*>(&Afs[0][lko][row]);
            a2f[mt] = *reinterpret_cast<const short8*>(&Afs[1][lko][row]);
        }
        const int kog = kt * 4 + lko;
        #pragma unroll
        for (int ct = 0; ct < 4; ++ct) {
            int col = wc * 64 + ct * 16 + l15;
            short8 w1 = *reinterpret_cast<const short8*>(&Whi[kog][col]);
            short8 w2 = *reinterpret_cast<const short8*>(Wlo + ((size_t)kog * 128 + col) * 8);
            #pragma unroll
            for (int mt = 0; mt < 2; ++mt) {
                acc[mt][ct] = __builtin_amdgcn_mfma_f32_16x16x32_bf16(a1f[mt], w1, acc[mt][ct], 0, 0, 0);
                acc[mt][ct] = __builtin_amdgcn_mfma_f32_16x16x32_bf16(a2f[mt], w1, acc[mt][ct], 0, 0, 0);
                acc[mt][ct] = __builtin_amdgcn_mfma_f32_16x16x32_bf16(a1f[mt], w2, acc[mt][ct], 0, 0, 0);
            }
        }
    }

    #pragma unroll
    for (int ct = 0; ct < 4; ++ct) {
        int col = wc * 64 + ct * 16 + l15;
        float bv = bias[col];
        #pragma unroll
        for (int mt = 0; mt < 2; ++mt) {
            int r0 = m0 + wr * 32 + mt * 16 + lko * 4;
            #pragma unroll
            for (int r = 0; r < 4; ++r) {
                int m = r0 + r;
                int gg = m >> L2NS, nn = m & (NS - 1);
                A[(size_t)gg * 32768 + (size_t)nn * F + col] = fmaxf(acc[mt][ct][r] + bv, 0.f);
            }
        }
    }
}

// -------------------- fused pool + next-stage agg (1024 threads, 1 block/graph) ------------
// Pool over N nodes -> keep K; then build next-stage Adj (NS_next=K) and run the
// agg MFMA directly from the pooled rows in LDS (hp). Writes R, cmap, XF (packed
// pooled rows for next gemm kt<4), AGGF (packed agg for next gemm kt>=4).
template<int N, int K, int STAGE>
__global__ __launch_bounds__(1024) void k_poolagg(const float* __restrict__ A,
                                                  float* __restrict__ R,
                                                  int* __restrict__ cmap,
                                                  const float* __restrict__ wp,
                                                  const int* __restrict__ src,
                                                  const int* __restrict__ dst,
                                                  unsigned* __restrict__ XF,
                                                  unsigned* __restrict__ AGGF) {
    constexpr int NS4 = K / 4;
    __shared__ float sc[N];
    __shared__ unsigned long long keys[N];
    __shared__ float hp[K * F];
    __shared__ int sel[K];
    __shared__ int inv[N];
    __shared__ float wn[F];
    __shared__ float gates[K];
    __shared__ float pmx[8 * F];
    __shared__ float psm[8 * F];
    __shared__ float snorm_s;
    __shared__ int ncm[256];
    __shared__ unsigned adjc[K * NS4];
    __shared__ short adjT[4 * K * 8];
    __shared__ short xs[2][4 * 128 * 8];

    const int g = blockIdx.x, t = threadIdx.x;
    const float* h = A + (size_t)g * 32768;
    const int lane = t & 63, wv16 = t >> 6;

    // zero adjc early (no conflict with pool LDS)
    {
        uint4* z = (uint4*)adjc;
        for (int i = t; i < K * NS4 / 4; i += 1024) z[i] = uint4{0, 0, 0, 0};
    }
    if (t < 64) {
        float v = wp[t] * wp[t] + wp[t + 64] * wp[t + 64];
        #pragma unroll
        for (int o = 32; o; o >>= 1) v += __shfl_xor(v, o);
        if (t == 0) snorm_s = sqrtf(v);
    }
    __syncthreads();
    if (t < 128) wn[t] = wp[t] / snorm_s;
    __syncthreads();

    // scores
    {
        const int r16 = lane >> 4, l16 = lane & 15;
        float4 w0 = *(const float4*)&wn[l16 * 8];
        float4 w1 = *(const float4*)&wn[l16 * 8 + 4];
        #pragma unroll
        for (int n0 = 0; n0 < N; n0 += 64) {
            int r = n0 + wv16 * 4 + r16;
            const float* hr = h + (size_t)r * F + l16 * 8;
            float4 v0 = *(const float4*)hr;
            float4 v1 = *(const float4*)(hr + 4);
            float p = v0.x * w0.x + v0.y * w0.y + v0.z * w0.z + v0.w * w0.w
                    + v1.x * w1.x + v1.y * w1.y + v1.z * w1.z + v1.w * w1.w;
            p += __shfl_xor(p, 1); p += __shfl_xor(p, 2);
            p += __shfl_xor(p, 4); p += __shfl_xor(p, 8);
            if (l16 == 0) sc[r] = p;
        }
    }
    __syncthreads();

    // bitonic sort N keys descending
    if (t < N) {
        unsigned u = __float_as_uint(sc[t]);
        u = (u & 0x80000000u) ? ~u : (u | 0x80000000u);
        keys[t] = ((unsigned long long)u << 32) | (unsigned)(~t);
    }
    __syncthreads();
    for (int kk = 2; kk <= N; kk <<= 1) {
        for (int j = kk >> 1; j > 0; j >>= 1) {
            if (t < N) {
                int ixj = t ^ j;
                if (ixj > t) {
                    unsigned long long a = keys[t], b = keys[ixj];
                    bool up = (t & kk) == 0;
                    if (up ? (a < b) : (a > b)) { keys[t] = b; keys[ixj] = a; }
                }
            }
            __syncthreads();
        }
    }

    if (t < K) sel[t] = (int)(~(unsigned)keys[t]);
    if (t < N) inv[t] = -1;
    __syncthreads();
    if (t < K) {
        inv[sel[t]] = t;
        gates[t] = tanhf(sc[sel[t]]);
    }
    __syncthreads();

    // phase A: composed map (LDS + global) || hp gather + partial readout
    if (t < 256) {
        int c = (STAGE == 1) ? t : cmap[g * 256 + t];
        int nc = (c >= 0) ? inv[c] : -1;
        ncm[t] = nc;
        cmap[g * 256 + t] = nc;
    }
    {
        const int f = t & 127, seg = t >> 7;
        float mx = -INFINITY, sm = 0.f;
        for (int j = seg; j < K; j += 8) {
            float v = h[(size_t)sel[j] * F + f] * gates[j];
            hp[j * F + f] = v;
            mx = fmaxf(mx, v);
            sm += v;
        }
        pmx[seg * F + f] = mx;
        psm[seg * F + f] = sm;
    }
    __syncthreads();

    // phase B: edge-count build + readout write + XF write
    {
        const int* sg = src + (size_t)g * EPER;
        const int* dg = dst + (size_t)g * EPER;
        #pragma unroll
        for (int j = 0; j < 4; ++j) {
            int e = j * 1024 + t;
            int s = ncm[sg[e]], d = ncm[dg[e]];
            if (s >= 0 && d >= 0) {
                int pos = (s + 4 * d) & (K - 1);
                __hip_atomic_fetch_add(&adjc[d * NS4 + (pos >> 2)], 1u << ((pos & 3) * 8),
                                       __ATOMIC_RELAXED, __HIP_MEMORY_SCOPE_WORKGROUP);
            }
        }
    }
    if (t < 128) {
        float m = -INFINITY, s = 0.f;
        #pragma unroll
        for (int q = 0; q < 8; ++q) {
            m = fmaxf(m, pmx[q * F + t]);
            s += psm[q * F + t];
        }
        R[(size_t)g * 768 + (STAGE - 1) * 256 + t] = m;
        R[(size_t)g * 768 + (STAGE - 1) * 256 + 128 + t] = s * (1.0f / K);
    }
    for (int i = t; i < K * F; i += 1024) {
        int j = i >> 7, f = i & 127;
        float v = hp[j * F + f];
        unsigned short hi = f2bf(v);
        unsigned short lo = f2bf(v - bf2f(hi));
        int m = g * K + j;
        XF[(size_t)(m >> 7) * TILE_U32 + (size_t)(f >> 3) * 1024 + (size_t)(m & 127) * 8 + (f & 7)] =
            (unsigned)hi | ((unsigned)lo << 16);
    }
    __syncthreads();

    // agg for next stage: acc = Adj @ hp, 16 waves
    constexpr int CTN = (K == 128) ? 4 : 2;           // col-tiles per wave
    const int rt = (K == 128) ? (wv16 >> 1) : (wv16 >> 2);
    const int cq = (K == 128) ? (wv16 & 1) : (wv16 & 3);
    f32x4 acc[CTN];
    #pragma unroll
    for (int c = 0; c < CTN; ++c) acc[c] = f32x4{0.f, 0.f, 0.f, 0.f};

    for (int k0 = 0; k0 < K; k0 += 32) {
        __syncthreads();
        if (t < K * 4) {      // adjT convert: m = t>>2, k-octet = t&3
            const int m = t >> 2, kg = (t & 3) * 8;
            unsigned short cs[8];
            #pragma unroll
            for (int q = 0; q < 2; ++q) {
                unsigned w = adjc[m * NS4 + ((((k0 + kg) >> 2) + m + q) & (NS4 - 1))];
                cs[q * 4 + 0] = f2bf((float)(w & 255u));
                cs[q * 4 + 1] = f2bf((float)((w >> 8) & 255u));
                cs[q * 4 + 2] = f2bf((float)((w >> 16) & 255u));
                cs[q * 4 + 3] = f2bf((float)(w >> 24));
            }
            short8 w8;
            #pragma unroll
            for (int j = 0; j < 8; ++j) w8[j] = (short)cs[j];
            *(short8*)&adjT[(t & 3) * K * 8 + m * 8] = w8;
        }
        if (t >= 512) {       // xs staging from hp: feat = t&127, octet o = (t>>7)&3
            const int feat = t & 127, o = (t >> 7) & 3;
            short8 h1, h2;
            #pragma unroll
            for (int j = 0; j < 8; ++j) {
                float f = hp[(k0 + o * 8 + j) * F + feat];
                unsigned short a1 = f2bf(f);
                unsigned short a2 = f2bf(f - bf2f(a1));
                h1[j] = (short)a1; h2[j] = (short)a2;
            }
            *(short8*)&xs[0][o * 1024 + feat * 8] = h1;
            *(short8*)&xs[1][o * 1024 + feat * 8] = h2;
        }
        __syncthreads();

        short8 afr = *(const short8*)&adjT[(lane >> 4) * K * 8 + (rt * 16 + (lane & 15)) * 8];
        #pragma unroll
        for (int s = 0; s < 2; ++s) {
            #pragma unroll
            for (int ct = 0; ct < CTN; ++ct) {
                int feat = cq * (CTN * 16) + ct * 16 + (lane & 15);
                short8 bfr = *(const short8*)&xs[s][(lane >> 4) * 1024 + feat * 8];
                acc[ct] = __builtin_amdgcn_mfma_f32_16x16x32_bf16(afr, bfr, acc[ct], 0, 0, 0);
            }
        }
    }

    // epilogue: pack agg to AGGF fragments
    #pragma unroll
    for (int ct = 0; ct < CTN; ++ct) {
        int feat = cq * (CTN * 16) + ct * 16 + (lane & 15);
        size_t fb = (size_t)(feat >> 3) * 1024 + (feat & 7);
        int r0 = rt * 16 + (lane >> 4) * 4;
        #pragma unroll
        for (int r = 0; r < 4; ++r) {
            int m = g * K + r0 + r;
            float v = acc[ct][r];
            unsigned short hi = f2bf(v);
            unsigned short lo = f2bf(v - bf2f(hi));
            AGGF[(size_t)(m >> 7) * TILE_U32 + fb + (size_t)(m & 127) * 8] =
                (unsigned)hi | ((unsigned)lo << 16);
        }
    }
}

// -------------------- final top-k pool + readout (stage 3, standalone) --------------------
template<int N, int K, int STAGE>
__global__ __launch_bounds__(1024) void k_pool(float* __restrict__ A,
                                               float* __restrict__ R,
                                               int* __restrict__ cmap,
                                               const float* __restrict__ wp) {
    __shared__ float sc[N];
    __shared__ unsigned long long keys[N];
    __shared__ float hp[K * F];
    __shared__ int sel[K];
    __shared__ float wn[F];
    __shared__ float gates[K];
    __shared__ float pmx[8 * F];
    __shared__ float psm[8 * F];
    __shared__ float snorm_s;
    const int g = blockIdx.x, t = threadIdx.x;
    const float* h = A + (size_t)g * 32768;
    const int lane = t & 63, wv16 = t >> 6;

    if (t < 64) {
        float v = wp[t] * wp[t] + wp[t + 64] * wp[t + 64];
        #pragma unroll
        for (int o = 32; o; o >>= 1) v += __shfl_xor(v, o);
        if (t == 0) snorm_s = sqrtf(v);
    }
    __syncthreads();
    if (t < 128) wn[t] = wp[t] / snorm_s;
    __syncthreads();

    {
        const int r16 = lane >> 4, l16 = lane & 15;
        float4 w0 = *(const float4*)&wn[l16 * 8];
        float4 w1 = *(const float4*)&wn[l16 * 8 + 4];
        #pragma unroll
        for (int n0 = 0; n0 < N; n0 += 64) {
            int r = n0 + wv16 * 4 + r16;
            if (r < N) {
                const float* hr = h + (size_t)r * F + l16 * 8;
                float4 v0 = *(const float4*)hr;
                float4 v1 = *(const float4*)(hr + 4);
                float p = v0.x * w0.x + v0.y * w0.y + v0.z * w0.z + v0.w * w0.w
                        + v1.x * w1.x + v1.y * w1.y + v1.z * w1.z + v1.w * w1.w;
                p += __shfl_xor(p, 1); p += __shfl_xor(p, 2);
                p += __shfl_xor(p, 4); p += __shfl_xor(p, 8);
                if (l16 == 0) sc[r] = p;
            }
        }
    }
    __syncthreads();

    if (t < N) {
        unsigned u = __float_as_uint(sc[t]);
        u = (u & 0x80000000u) ? ~u : (u | 0x80000000u);
        keys[t] = ((unsigned long long)u << 32) | (unsigned)(~t);
    }
    __syncthreads();
    for (int kk = 2; kk <= N; kk <<= 1) {
        for (int j = kk >> 1; j > 0; j >>= 1) {
            if (t < N) {
                int ixj = t ^ j;
                if (ixj > t) {
                    unsigned long long a = keys[t], b = keys[ixj];
                    bool up = (t & kk) == 0;
                    if (up ? (a < b) : (a > b)) { keys[t] = b; keys[ixj] = a; }
                }
            }
            __syncthreads();
        }
    }

    if (t < K) {
        sel[t] = (int)(~(unsigned)keys[t]);
        gates[t] = tanhf(sc[sel[t]]);
    }
    __syncthreads();

    {
        const int f = t & 127, seg = t >> 7;
        float mx = -INFINITY, sm = 0.f;
        for (int j = seg; j < K; j += 8) {
            float v = h[(size_t)sel[j] * F + f] * gates[j];
            hp[j * F + f] = v;
            mx = fmaxf(mx, v);
            sm += v;
        }
        pmx[seg * F + f] = mx;
        psm[seg * F + f] = sm;
    }
    __syncthreads();

    if (t < 128) {
        float m = -INFINITY, s = 0.f;
        #pragma unroll
        for (int q = 0; q < 8; ++q) {
            m = fmaxf(m, pmx[q * F + t]);
            s += psm[q * F + t];
        }
        R[(size_t)g * 768 + (STAGE - 1) * 256 + t] = m;
        R[(size_t)g * 768 + (STAGE - 1) * 256 + 128 + t] = s * (1.0f / K);
    }
}

// -------------------- final MLP + log_softmax (split-K, 1024 threads) --------------------
__global__ __launch_bounds__(1024) void k_mlp(const float* __restrict__ R,
                                              const float* __restrict__ W1, const float* __restrict__ b1,
                                              const float* __restrict__ W2, const float* __restrict__ b2,
                                              const float* __restrict__ W3, const float* __restrict__ b3,
                                              float* __restrict__ out) {
    __shared__ float z[768];
    __shared__ float part[8][128];
    __shared__ float z2[128];
    __shared__ float z3[64];
    __shared__ float lg[10];
    __shared__ float lse;
    const int g = blockIdx.x, t = threadIdx.x;

    if (t < 768) z[t] = R[(size_t)g * 768 + t];
    __syncthreads();

    {
        const int f = t & 127, seg = t >> 7;
        float acc = 0.f;
        const float* w = W1 + (size_t)(seg * 96) * 128 + f;
        const float* zz = z + seg * 96;
        #pragma unroll 8
        for (int k = 0; k < 96; ++k) acc = fmaf(zz[k], w[(size_t)k * 128], acc);
        part[seg][f] = acc;
    }
    __syncthreads();
    if (t < 128) {
        float a = b1[t];
        #pragma unroll
        for (int q = 0; q < 8; ++q) a += part[q][t];
        z2[t] = fmaxf(a, 0.f);
    }
    __syncthreads();

    if (t < 512) {
        const int f = t & 63, seg = t >> 6;
        float acc = 0.f;
        const float* w = W2 + (size_t)(seg * 16) * 64 + f;
        const float* zz = z2 + seg * 16;
        #pragma unroll
        for (int k = 0; k < 16; ++k) acc = fmaf(zz[k], w[(size_t)k * 64], acc);
        part[seg][f] = acc;
    }
    __syncthreads();
    if (t < 64) {
        float a = b2[t];
        #pragma unroll
        for (int q = 0; q < 8; ++q) a += part[q][t];
        z3[t] = fmaxf(a, 0.f);
    }
    __syncthreads();

    if (t < 10) {
        float a3 = b3[t];
        #pragma unroll 8
        for (int k = 0; k < 64; ++k) a3 = fmaf(z3[k], W3[(size_t)k * 10 + t], a3);
        lg[t] = a3;
    }
    __syncthreads();

    if (t == 0) {
        float m = lg[0];
        for (int c = 1; c < 10; ++c) m = fmaxf(m, lg[c]);
        float s = 0.f;
        for (int c = 0; c < 10; ++c) s += expf(lg[c] - m);
        lse = m + logf(s);
    }
    __syncthreads();
    if (t < 10) out[(size_t)g * 10 + t] = lg[t] - lse;
}

extern "C" void kernel_launch(void* const* d_in, const int* in_sizes, int n_in,
                              void* d_out, int out_size, void* d_ws, size_t ws_size,
                              hipStream_t stream) {
    (void)in_sizes; (void)n_in; (void)out_size; (void)ws_size;
    const float* x    = (const float*)d_in[0];
    const int*   src  = (const int*)d_in[1];
    const int*   dst  = (const int*)d_in[2];
    const float* Wr1  = (const float*)d_in[3];
    const float* Wrel1= (const float*)d_in[4];
    const float* b1   = (const float*)d_in[5];
    const float* wp1  = (const float*)d_in[6];
    const float* Wr2  = (const float*)d_in[7];
    const float* Wrel2= (const float*)d_in[8];
    const float* b2   = (const float*)d_in[9];
    const float* wp2  = (const float*)d_in[10];
    const float* Wr3  = (const float*)d_in[11];
    const float* Wrel3= (const float*)d_in[12];
    const float* b3   = (const float*)d_in[13];
    const float* wp3  = (const float*)d_in[14];
    const float* L1w  = (const float*)d_in[15];
    const float* L1b  = (const float*)d_in[16];
    const float* L2w  = (const float*)d_in[17];
    const float* L2b  = (const float*)d_in[18];
    const float* L3w  = (const float*)d_in[19];
    const float* L3b  = (const float*)d_in[20];

    float*    A    = (float*)d_ws;                               // G*32768 f32 (h)
    int*      cmap = (int*)(A + (size_t)G * 32768);              // G*256 i32
    float*    R    = (float*)(cmap + (size_t)G * 256);           // G*768 f32
    unsigned* AGGF = (unsigned*)(R + (size_t)G * 768);           // G*2 tiles * 16384 u32
    unsigned* XF   = AGGF + (size_t)G * 2 * TILE_U32;            // G tiles * 16384 u32
    unsigned short* Wf = (unsigned short*)(XF + (size_t)G * TILE_U32);  // 3*65536 shorts
    float* out = (float*)d_out;

    k_wsplit<<<384, 256, 0, stream>>>(Wr1, Wrel1, Wr2, Wrel2, Wr3, Wrel3, Wf);

    // stage 1
    k_agg1<<<G * 2, 256, 0, stream>>>(x, src, dst, AGGF);
    k_gemm<256, true><<<512, 512, 0, stream>>>(x, A, AGGF, nullptr, Wf, b1);
    // pool1 + agg2 fused
    k_poolagg<256, 128, 1><<<G, 1024, 0, stream>>>(A, R, cmap, wp1, src, dst, XF, AGGF);
    // stage 2
    k_gemm<128, false><<<256, 512, 0, stream>>>(nullptr, A, AGGF, XF, Wf + 65536, b2);
    // pool2 + agg3 fused
    k_poolagg<128, 64, 2><<<G, 1024, 0, stream>>>(A, R, cmap, wp2, src, dst, XF, AGGF);
    // stage 3
    k_gemm<64, false><<<128, 512, 0, stream>>>(nullptr, A, AGGF, XF, Wf + 131072, b3);
    k_pool<64, 32, 3><<<G, 1024, 0, stream>>>(A, R, cmap, wp3);
    // head
    k_mlp<<<G, 1024, 0, stream>>>(R, L1w, L1b, L2w, L2b, L3w, L3b, out);
}

// Round 14
// 138.998 us; speedup vs baseline: 1.1462x; 1.0370x over previous
//
#include <hip/hip_runtime.h>
#include <cstdint>
#include <cstddef>

#define G 256
#define EPER 4096
#define F 128
#define TILE_U32 16384  // fragment tile: 16 ko * 128 row * 8 j (u32 each)

typedef __attribute__((ext_vector_type(8))) short short8;
typedef __attribute__((ext_vector_type(4))) float f32x4;

__device__ inline unsigned short f2bf(float f) {
    unsigned u = __float_as_uint(f);
    u += 0x7FFFu + ((u >> 16) & 1u);
    return (unsigned short)(u >> 16);
}
__device__ inline float bf2f(unsigned short b) { return __uint_as_float(((unsigned)b) << 16); }

// -------------------- W pre-split: [Wr;Wl] -> fragment-major bf16 hi/lo --------------------
__global__ __launch_bounds__(256) void k_wsplit(const float* __restrict__ Wr1, const float* __restrict__ Wl1,
                                                const float* __restrict__ Wr2, const float* __restrict__ Wl2,
                                                const float* __restrict__ Wr3, const float* __restrict__ Wl3,
                                                unsigned short* __restrict__ Wf) {
    int gid = blockIdx.x * 256 + threadIdx.x;   // 0..98303
    int s = gid >> 15;
    int idx = gid & 32767;
    int j = idx & 7, col = (idx >> 3) & 127, ko = idx >> 10;
    int k = ko * 8 + j;
    const float* Wr = (s == 0) ? Wr1 : (s == 1) ? Wr2 : Wr3;
    const float* Wl = (s == 0) ? Wl1 : (s == 1) ? Wl2 : Wl3;
    float f = (k < 128) ? Wr[(size_t)k * 128 + col] : Wl[(size_t)(k - 128) * 128 + col];
    unsigned short h1 = f2bf(f), h2 = f2bf(f - bf2f(h1));
    Wf[(size_t)s * 65536 + idx] = h1;
    Wf[(size_t)s * 65536 + 32768 + idx] = h2;
}

// -------------------- stage-1 aggregation: agg = Adj @ x on MFMA --------------------
// One block per graph, 1024 threads (16 waves), BM = NS = 256. Edge scan and x
// load happen ONCE per graph (R13's dst-halving did both twice). LDS 96 KB ->
// 1 block/CU but 16 waves/CU (2x R13's 8).
__global__ __launch_bounds__(1024) void k_agg1(const float* __restrict__ X,
                                               const int* __restrict__ src,
                                               const int* __restrict__ dst,
                                               unsigned* __restrict__ AGGF) {
    constexpr int NS = 256, NS4 = NS / 4;
    __shared__ unsigned adjc[NS * NS4];   // 64 KB packed u8 counts, row d rotated by 4d bytes
    __shared__ short adjT[4 * NS * 8];    // 16 KB [koct][m][8k]
    __shared__ short xs[2][4 * 128 * 8];  // 16 KB [split][koct][n][8k]

    const int g = blockIdx.x, t = threadIdx.x;
    const int lane = t & 63, wv = t >> 6;  // 16 waves

    {
        uint4* z = (uint4*)adjc;
        #pragma unroll
        for (int i = t; i < NS * NS4 / 4; i += 1024) z[i] = uint4{0, 0, 0, 0};
    }
    __syncthreads();

    // build counts: one u32 atomic per edge (4/thread)
    const int* sg = src + (size_t)g * EPER;
    const int* dg = dst + (size_t)g * EPER;
    #pragma unroll
    for (int j = 0; j < 4; ++j) {
        int e = j * 1024 + t;
        int s = sg[e], d = dg[e];
        int pos = (s + 4 * d) & (NS - 1);
        __hip_atomic_fetch_add(&adjc[d * NS4 + (pos >> 2)], 1u << ((pos & 3) * 8),
                               __ATOMIC_RELAXED, __HIP_MEMORY_SCOPE_WORKGROUP);
    }

    f32x4 acc[8];
    #pragma unroll
    for (int c = 0; c < 8; ++c) acc[c] = f32x4{0.f, 0.f, 0.f, 0.f};

    const int mA = t >> 2, kgA = (t & 3) * 8;   // adjT convert: 256 rows x 4 octets
    const int nX = t & 127, oX = (t >> 7) & 3;  // xs staging (t < 512)

    for (int k0 = 0; k0 < NS; k0 += 32) {
        __syncthreads();
        // --- convert adj u8 tile -> bf16 [koct][m][8k]: 1024 tasks, 1/thread ---
        {
            unsigned short cs[8];
            #pragma unroll
            for (int q = 0; q < 2; ++q) {
                unsigned w = adjc[mA * NS4 + ((((k0 + kgA) >> 2) + mA + q) & (NS4 - 1))];
                cs[q * 4 + 0] = f2bf((float)(w & 255u));
                cs[q * 4 + 1] = f2bf((float)((w >> 8) & 255u));
                cs[q * 4 + 2] = f2bf((float)((w >> 16) & 255u));
                cs[q * 4 + 3] = f2bf((float)(w >> 24));
            }
            short8 w8;
            #pragma unroll
            for (int j = 0; j < 8; ++j) w8[j] = (short)cs[j];
            *(short8*)&adjT[(t & 3) * NS * 8 + mA * 8] = w8;
        }
        // --- stage x rows k0..k0+31 (512 threads x 8 rows), 2-way bf16 split ---
        if (t < 512) {
            short8 h1, h2;
            #pragma unroll
            for (int j = 0; j < 8; ++j) {
                float f = X[(size_t)g * 32768 + (size_t)(k0 + oX * 8 + j) * F + nX];
                unsigned short a1 = f2bf(f);
                unsigned short a2 = f2bf(f - bf2f(a1));
                h1[j] = (short)a1; h2[j] = (short)a2;
            }
            *(short8*)&xs[0][oX * 1024 + nX * 8] = h1;
            *(short8*)&xs[1][oX * 1024 + nX * 8] = h2;
        }
        __syncthreads();
        // --- MFMA: wave wv owns rows wv*16..wv*16+15, all 8 col-tiles ---
        short8 afr = *(const short8*)&adjT[(lane >> 4) * NS * 8 + (wv * 16 + (lane & 15)) * 8];
        #pragma unroll
        for (int s = 0; s < 2; ++s) {
            #pragma unroll
            for (int ct = 0; ct < 8; ++ct) {
                short8 bfr = *(const short8*)&xs[s][(lane >> 4) * 1024 + (ct * 16 + (lane & 15)) * 8];
                acc[ct] = __builtin_amdgcn_mfma_f32_16x16x32_bf16(afr, bfr, acc[ct], 0, 0, 0);
            }
        }
    }

    // epilogue: pack to (hi|lo) u32 fragments
    #pragma unroll
    for (int ct = 0; ct < 8; ++ct) {
        int feat = ct * 16 + (lane & 15);
        size_t fb = (size_t)(feat >> 3) * 1024 + (feat & 7);
        int r0 = wv * 16 + (lane >> 4) * 4;
        #pragma unroll
        for (int r = 0; r < 4; ++r) {
            int m = g * NS + r0 + r;
            float v = acc[ct][r];
            unsigned short hi = f2bf(v);
            unsigned short lo = f2bf(v - bf2f(hi));
            AGGF[(size_t)(m >> 7) * TILE_U32 + fb + (size_t)(m & 127) * 8] =
                (unsigned)hi | ((unsigned)lo << 16);
        }
    }
}

// -------------------- conv GEMM on MFMA (unchanged from R13) --------------------
template<int NS, bool FIRST>
__global__ __launch_bounds__(512, 4) void k_gemm(const float* __restrict__ X,
                                                 float* __restrict__ A,
                                                 const unsigned* __restrict__ AGGF,
                                                 const unsigned* __restrict__ XF,
                                                 const unsigned short* __restrict__ Wf,
                                                 const float* __restrict__ bias) {
    constexpr int L2NS = (NS == 256) ? 8 : (NS == 128) ? 7 : 6;
    __shared__ uint4 Whi[32][128];
    __shared__ uint4 Afs[2][4][128];
    const int t = threadIdx.x;
    const int m0 = blockIdx.x * 128;
    const int lane = t & 63;
    const int wv = t >> 6, wr = wv >> 1, wc = wv & 1;
    const int l15 = lane & 15, lko = lane >> 4;
    const unsigned short* Wlo = Wf + 32768;

    {
        const uint4* Wf4 = (const uint4*)Wf;
        uint4* Wd = (uint4*)Whi;
        #pragma unroll
        for (int i = 0; i < 8; ++i) Wd[t + i * 512] = Wf4[t + i * 512];
    }

    f32x4 acc[2][4];
    #pragma unroll
    for (int i = 0; i < 2; ++i)
        #pragma unroll
        for (int c = 0; c < 4; ++c) acc[i][c] = f32x4{0.f, 0.f, 0.f, 0.f};

    const int rs = t >> 2, ck = t & 3;
    const int rowp = t & 127, kop = t >> 7;
    const float* xrow = FIRST ? (X + (size_t)(m0 + rs) * F) : nullptr;

    for (int kt = 0; kt < 8; ++kt) {
        __syncthreads();
        if (FIRST && kt < 4) {
            const float* srow = xrow + kt * 32 + ck * 8;
            float4 fa = *(const float4*)srow;
            float4 fb = *(const float4*)(srow + 4);
            float vv[8] = {fa.x, fa.y, fa.z, fa.w, fb.x, fb.y, fb.z, fb.w};
            short8 h1, h2;
            #pragma unroll
            for (int j = 0; j < 8; ++j) {
                unsigned short a1 = f2bf(vv[j]);
                unsigned short a2 = f2bf(vv[j] - bf2f(a1));
                h1[j] = (short)a1; h2[j] = (short)a2;
            }
            int rw = rs ^ (ck << 2);
            *reinterpret_cast<short8*>(&Afs[0][ck][rw]) = h1;
            *reinterpret_cast<short8*>(&Afs[1][ck][rw]) = h2;
        } else {
            const unsigned* P = (kt < 4) ? XF : AGGF;
            int ko = (kt & 3) * 4 + kop;
            size_t idx = (size_t)blockIdx.x * TILE_U32 + (size_t)ko * 1024 + (size_t)rowp * 8;
            uint4 qa = *(const uint4*)(P + idx);
            uint4 qb = *(const uint4*)(P + idx + 4);
            short8 h1, h2;
            h1[0] = (short)qa.x; h2[0] = (short)(qa.x >> 16);
            h1[1] = (short)qa.y; h2[1] = (short)(qa.y >> 16);
            h1[2] = (short)qa.z; h2[2] = (short)(qa.z >> 16);
            h1[3] = (short)qa.w; h2[3] = (short)(qa.w >> 16);
            h1[4] = (short)qb.x; h2[4] = (short)(qb.x >> 16);
            h1[5] = (short)qb.y; h2[5] = (short)(qb.y >> 16);
            h1[6] = (short)qb.z; h2[6] = (short)(qb.z >> 16);
            h1[7] = (short)qb.w; h2[7] = (short)(qb.w >> 16);
            int rw = rowp ^ (kop << 2);
            *reinterpret_cast<short8*>(&Afs[0][kop][rw]) = h1;
            *reinterpret_cast<short8*>(&Afs[1][kop][rw]) = h2;
        }
        __syncthreads();

        short8 a1f[2], a2f[2];
        #pragma unroll
        for (int mt = 0; mt < 2; ++mt) {
            int row = (wr * 32 + mt * 16 + l15) ^ (lko << 2);
            a1f[mt] = *reinterpret_cast<const short8*>(&Afs[0][lko][row]);
            a2f[mt] = *reinterpret_cast<const short8*>(&Afs[1][lko][row]);
        }
        const int kog = kt * 4 + lko;
        #pragma unroll
        for (int ct = 0; ct < 4; ++ct) {
            int col = wc * 64 + ct * 16 + l15;
            short8 w1 = *reinterpret_cast<const short8*>(&Whi[kog][col]);
            short8 w2 = *reinterpret_cast<const short8*>(Wlo + ((size_t)kog * 128 + col) * 8);
            #pragma unroll
            for (int mt = 0; mt < 2; ++mt) {
                acc[mt][ct] = __builtin_amdgcn_mfma_f32_16x16x32_bf16(a1f[mt], w1, acc[mt][ct], 0, 0, 0);
                acc[mt][ct] = __builtin_amdgcn_mfma_f32_16x16x32_bf16(a2f[mt], w1, acc[mt][ct], 0, 0, 0);
                acc[mt][ct] = __builtin_amdgcn_mfma_f32_16x16x32_bf16(a1f[mt], w2, acc[mt][ct], 0, 0, 0);
            }
        }
    }

    #pragma unroll
    for (int ct = 0; ct < 4; ++ct) {
        int col = wc * 64 + ct * 16 + l15;
        float bv = bias[col];
        #pragma unroll
        for (int mt = 0; mt < 2; ++mt) {
            int r0 = m0 + wr * 32 + mt * 16 + lko * 4;
            #pragma unroll
            for (int r = 0; r < 4; ++r) {
                int m = r0 + r;
                int gg = m >> L2NS, nn = m & (NS - 1);
                A[(size_t)gg * 32768 + (size_t)nn * F + col] = fmaxf(acc[mt][ct][r] + bv, 0.f);
            }
        }
    }
}

// -------------------- fused pool + next-stage agg (unchanged from R13) ------------
template<int N, int K, int STAGE>
__global__ __launch_bounds__(1024) void k_poolagg(const float* __restrict__ A,
                                                  float* __restrict__ R,
                                                  int* __restrict__ cmap,
                                                  const float* __restrict__ wp,
                                                  const int* __restrict__ src,
                                                  const int* __restrict__ dst,
                                                  unsigned* __restrict__ XF,
                                                  unsigned* __restrict__ AGGF) {
    constexpr int NS4 = K / 4;
    __shared__ float sc[N];
    __shared__ unsigned long long keys[N];
    __shared__ float hp[K * F];
    __shared__ int sel[K];
    __shared__ int inv[N];
    __shared__ float wn[F];
    __shared__ float gates[K];
    __shared__ float pmx[8 * F];
    __shared__ float psm[8 * F];
    __shared__ float snorm_s;
    __shared__ int ncm[256];
    __shared__ unsigned adjc[K * NS4];
    __shared__ short adjT[4 * K * 8];
    __shared__ short xs[2][4 * 128 * 8];

    const int g = blockIdx.x, t = threadIdx.x;
    const float* h = A + (size_t)g * 32768;
    const int lane = t & 63, wv16 = t >> 6;

    {
        uint4* z = (uint4*)adjc;
        for (int i = t; i < K * NS4 / 4; i += 1024) z[i] = uint4{0, 0, 0, 0};
    }
    if (t < 64) {
        float v = wp[t] * wp[t] + wp[t + 64] * wp[t + 64];
        #pragma unroll
        for (int o = 32; o; o >>= 1) v += __shfl_xor(v, o);
        if (t == 0) snorm_s = sqrtf(v);
    }
    __syncthreads();
    if (t < 128) wn[t] = wp[t] / snorm_s;
    __syncthreads();

    {
        const int r16 = lane >> 4, l16 = lane & 15;
        float4 w0 = *(const float4*)&wn[l16 * 8];
        float4 w1 = *(const float4*)&wn[l16 * 8 + 4];
        #pragma unroll
        for (int n0 = 0; n0 < N; n0 += 64) {
            int r = n0 + wv16 * 4 + r16;
            const float* hr = h + (size_t)r * F + l16 * 8;
            float4 v0 = *(const float4*)hr;
            float4 v1 = *(const float4*)(hr + 4);
            float p = v0.x * w0.x + v0.y * w0.y + v0.z * w0.z + v0.w * w0.w
                    + v1.x * w1.x + v1.y * w1.y + v1.z * w1.z + v1.w * w1.w;
            p += __shfl_xor(p, 1); p += __shfl_xor(p, 2);
            p += __shfl_xor(p, 4); p += __shfl_xor(p, 8);
            if (l16 == 0) sc[r] = p;
        }
    }
    __syncthreads();

    if (t < N) {
        unsigned u = __float_as_uint(sc[t]);
        u = (u & 0x80000000u) ? ~u : (u | 0x80000000u);
        keys[t] = ((unsigned long long)u << 32) | (unsigned)(~t);
    }
    __syncthreads();
    for (int kk = 2; kk <= N; kk <<= 1) {
        for (int j = kk >> 1; j > 0; j >>= 1) {
            if (t < N) {
                int ixj = t ^ j;
                if (ixj > t) {
                    unsigned long long a = keys[t], b = keys[ixj];
                    bool up = (t & kk) == 0;
                    if (up ? (a < b) : (a > b)) { keys[t] = b; keys[ixj] = a; }
                }
            }
            __syncthreads();
        }
    }

    if (t < K) sel[t] = (int)(~(unsigned)keys[t]);
    if (t < N) inv[t] = -1;
    __syncthreads();
    if (t < K) {
        inv[sel[t]] = t;
        gates[t] = tanhf(sc[sel[t]]);
    }
    __syncthreads();

    if (t < 256) {
        int c = (STAGE == 1) ? t : cmap[g * 256 + t];
        int nc = (c >= 0) ? inv[c] : -1;
        ncm[t] = nc;
        cmap[g * 256 + t] = nc;
    }
    {
        const int f = t & 127, seg = t >> 7;
        float mx = -INFINITY, sm = 0.f;
        for (int j = seg; j < K; j += 8) {
            float v = h[(size_t)sel[j] * F + f] * gates[j];
            hp[j * F + f] = v;
            mx = fmaxf(mx, v);
            sm += v;
        }
        pmx[seg * F + f] = mx;
        psm[seg * F + f] = sm;
    }
    __syncthreads();

    {
        const int* sg = src + (size_t)g * EPER;
        const int* dg = dst + (size_t)g * EPER;
        #pragma unroll
        for (int j = 0; j < 4; ++j) {
            int e = j * 1024 + t;
            int s = ncm[sg[e]], d = ncm[dg[e]];
            if (s >= 0 && d >= 0) {
                int pos = (s + 4 * d) & (K - 1);
                __hip_atomic_fetch_add(&adjc[d * NS4 + (pos >> 2)], 1u << ((pos & 3) * 8),
                                       __ATOMIC_RELAXED, __HIP_MEMORY_SCOPE_WORKGROUP);
            }
        }
    }
    if (t < 128) {
        float m = -INFINITY, s = 0.f;
        #pragma unroll
        for (int q = 0; q < 8; ++q) {
            m = fmaxf(m, pmx[q * F + t]);
            s += psm[q * F + t];
        }
        R[(size_t)g * 768 + (STAGE - 1) * 256 + t] = m;
        R[(size_t)g * 768 + (STAGE - 1) * 256 + 128 + t] = s * (1.0f / K);
    }
    for (int i = t; i < K * F; i += 1024) {
        int j = i >> 7, f = i & 127;
        float v = hp[j * F + f];
        unsigned short hi = f2bf(v);
        unsigned short lo = f2bf(v - bf2f(hi));
        int m = g * K + j;
        XF[(size_t)(m >> 7) * TILE_U32 + (size_t)(f >> 3) * 1024 + (size_t)(m & 127) * 8 + (f & 7)] =
            (unsigned)hi | ((unsigned)lo << 16);
    }
    __syncthreads();

    constexpr int CTN = (K == 128) ? 4 : 2;
    const int rt = (K == 128) ? (wv16 >> 1) : (wv16 >> 2);
    const int cq = (K == 128) ? (wv16 & 1) : (wv16 & 3);
    f32x4 acc[CTN];
    #pragma unroll
    for (int c = 0; c < CTN; ++c) acc[c] = f32x4{0.f, 0.f, 0.f, 0.f};

    for (int k0 = 0; k0 < K; k0 += 32) {
        __syncthreads();
        if (t < K * 4) {
            const int m = t >> 2, kg = (t & 3) * 8;
            unsigned short cs[8];
            #pragma unroll
            for (int q = 0; q < 2; ++q) {
                unsigned w = adjc[m * NS4 + ((((k0 + kg) >> 2) + m + q) & (NS4 - 1))];
                cs[q * 4 + 0] = f2bf((float)(w & 255u));
                cs[q * 4 + 1] = f2bf((float)((w >> 8) & 255u));
                cs[q * 4 + 2] = f2bf((float)((w >> 16) & 255u));
                cs[q * 4 + 3] = f2bf((float)(w >> 24));
            }
            short8 w8;
            #pragma unroll
            for (int j = 0; j < 8; ++j) w8[j] = (short)cs[j];
            *(short8*)&adjT[(t & 3) * K * 8 + m * 8] = w8;
        }
        if (t >= 512) {
            const int feat = t & 127, o = (t >> 7) & 3;
            short8 h1, h2;
            #pragma unroll
            for (int j = 0; j < 8; ++j) {
                float f = hp[(k0 + o * 8 + j) * F + feat];
                unsigned short a1 = f2bf(f);
                unsigned short a2 = f2bf(f - bf2f(a1));
                h1[j] = (short)a1; h2[j] = (short)a2;
            }
            *(short8*)&xs[0][o * 1024 + feat * 8] = h1;
            *(short8*)&xs[1][o * 1024 + feat * 8] = h2;
        }
        __syncthreads();

        short8 afr = *(const short8*)&adjT[(lane >> 4) * K * 8 + (rt * 16 + (lane & 15)) * 8];
        #pragma unroll
        for (int s = 0; s < 2; ++s) {
            #pragma unroll
            for (int ct = 0; ct < CTN; ++ct) {
                int feat = cq * (CTN * 16) + ct * 16 + (lane & 15);
                short8 bfr = *(const short8*)&xs[s][(lane >> 4) * 1024 + feat * 8];
                acc[ct] = __builtin_amdgcn_mfma_f32_16x16x32_bf16(afr, bfr, acc[ct], 0, 0, 0);
            }
        }
    }

    #pragma unroll
    for (int ct = 0; ct < CTN; ++ct) {
        int feat = cq * (CTN * 16) + ct * 16 + (lane & 15);
        size_t fb = (size_t)(feat >> 3) * 1024 + (feat & 7);
        int r0 = rt * 16 + (lane >> 4) * 4;
        #pragma unroll
        for (int r = 0; r < 4; ++r) {
            int m = g * K + r0 + r;
            float v = acc[ct][r];
            unsigned short hi = f2bf(v);
            unsigned short lo = f2bf(v - bf2f(hi));
            AGGF[(size_t)(m >> 7) * TILE_U32 + fb + (size_t)(m & 127) * 8] =
                (unsigned)hi | ((unsigned)lo << 16);
        }
    }
}

// -------------------- final top-k pool + readout (stage 3, standalone) --------------------
template<int N, int K, int STAGE>
__global__ __launch_bounds__(1024) void k_pool(float* __restrict__ A,
                                               float* __restrict__ R,
                                               int* __restrict__ cmap,
                                               const float* __restrict__ wp) {
    __shared__ float sc[N];
    __shared__ unsigned long long keys[N];
    __shared__ float hp[K * F];
    __shared__ int sel[K];
    __shared__ float wn[F];
    __shared__ float gates[K];
    __shared__ float pmx[8 * F];
    __shared__ float psm[8 * F];
    __shared__ float snorm_s;
    const int g = blockIdx.x, t = threadIdx.x;
    const float* h = A + (size_t)g * 32768;
    const int lane = t & 63, wv16 = t >> 6;

    if (t < 64) {
        float v = wp[t] * wp[t] + wp[t + 64] * wp[t + 64];
        #pragma unroll
        for (int o = 32; o; o >>= 1) v += __shfl_xor(v, o);
        if (t == 0) snorm_s = sqrtf(v);
    }
    __syncthreads();
    if (t < 128) wn[t] = wp[t] / snorm_s;
    __syncthreads();

    {
        const int r16 = lane >> 4, l16 = lane & 15;
        float4 w0 = *(const float4*)&wn[l16 * 8];
        float4 w1 = *(const float4*)&wn[l16 * 8 + 4];
        #pragma unroll
        for (int n0 = 0; n0 < N; n0 += 64) {
            int r = n0 + wv16 * 4 + r16;
            if (r < N) {
                const float* hr = h + (size_t)r * F + l16 * 8;
                float4 v0 = *(const float4*)hr;
                float4 v1 = *(const float4*)(hr + 4);
                float p = v0.x * w0.x + v0.y * w0.y + v0.z * w0.z + v0.w * w0.w
                        + v1.x * w1.x + v1.y * w1.y + v1.z * w1.z + v1.w * w1.w;
                p += __shfl_xor(p, 1); p += __shfl_xor(p, 2);
                p += __shfl_xor(p, 4); p += __shfl_xor(p, 8);
                if (l16 == 0) sc[r] = p;
            }
        }
    }
    __syncthreads();

    if (t < N) {
        unsigned u = __float_as_uint(sc[t]);
        u = (u & 0x80000000u) ? ~u : (u | 0x80000000u);
        keys[t] = ((unsigned long long)u << 32) | (unsigned)(~t);
    }
    __syncthreads();
    for (int kk = 2; kk <= N; kk <<= 1) {
        for (int j = kk >> 1; j > 0; j >>= 1) {
            if (t < N) {
                int ixj = t ^ j;
                if (ixj > t) {
                    unsigned long long a = keys[t], b = keys[ixj];
                    bool up = (t & kk) == 0;
                    if (up ? (a < b) : (a > b)) { keys[t] = b; keys[ixj] = a; }
                }
            }
            __syncthreads();
        }
    }

    if (t < K) {
        sel[t] = (int)(~(unsigned)keys[t]);
        gates[t] = tanhf(sc[sel[t]]);
    }
    __syncthreads();

    {
        const int f = t & 127, seg = t >> 7;
        float mx = -INFINITY, sm = 0.f;
        for (int j = seg; j < K; j += 8) {
            float v = h[(size_t)sel[j] * F + f] * gates[j];
            hp[j * F + f] = v;
            mx = fmaxf(mx, v);
            sm += v;
        }
        pmx[seg * F + f] = mx;
        psm[seg * F + f] = sm;
    }
    __syncthreads();

    if (t < 128) {
        float m = -INFINITY, s = 0.f;
        #pragma unroll
        for (int q = 0; q < 8; ++q) {
            m = fmaxf(m, pmx[q * F + t]);
            s += psm[q * F + t];
        }
        R[(size_t)g * 768 + (STAGE - 1) * 256 + t] = m;
        R[(size_t)g * 768 + (STAGE - 1) * 256 + 128 + t] = s * (1.0f / K);
    }
}

// -------------------- final MLP + log_softmax (split-K, 1024 threads) --------------------
__global__ __launch_bounds__(1024) void k_mlp(const float* __restrict__ R,
                                              const float* __restrict__ W1, const float* __restrict__ b1,
                                              const float* __restrict__ W2, const float* __restrict__ b2,
                                              const float* __restrict__ W3, const float* __restrict__ b3,
                                              float* __restrict__ out) {
    __shared__ float z[768];
    __shared__ float part[8][128];
    __shared__ float z2[128];
    __shared__ float z3[64];
    __shared__ float lg[10];
    __shared__ float lse;
    const int g = blockIdx.x, t = threadIdx.x;

    if (t < 768) z[t] = R[(size_t)g * 768 + t];
    __syncthreads();

    {
        const int f = t & 127, seg = t >> 7;
        float acc = 0.f;
        const float* w = W1 + (size_t)(seg * 96) * 128 + f;
        const float* zz = z + seg * 96;
        #pragma unroll 8
        for (int k = 0; k < 96; ++k) acc = fmaf(zz[k], w[(size_t)k * 128], acc);
        part[seg][f] = acc;
    }
    __syncthreads();
    if (t < 128) {
        float a = b1[t];
        #pragma unroll
        for (int q = 0; q < 8; ++q) a += part[q][t];
        z2[t] = fmaxf(a, 0.f);
    }
    __syncthreads();

    if (t < 512) {
        const int f = t & 63, seg = t >> 6;
        float acc = 0.f;
        const float* w = W2 + (size_t)(seg * 16) * 64 + f;
        const float* zz = z2 + seg * 16;
        #pragma unroll
        for (int k = 0; k < 16; ++k) acc = fmaf(zz[k], w[(size_t)k * 64], acc);
        part[seg][f] = acc;
    }
    __syncthreads();
    if (t < 64) {
        float a = b2[t];
        #pragma unroll
        for (int q = 0; q < 8; ++q) a += part[q][t];
        z3[t] = fmaxf(a, 0.f);
    }
    __syncthreads();

    if (t < 10) {
        float a3 = b3[t];
        #pragma unroll 8
        for (int k = 0; k < 64; ++k) a3 = fmaf(z3[k], W3[(size_t)k * 10 + t], a3);
        lg[t] = a3;
    }
    __syncthreads();

    if (t == 0) {
        float m = lg[0];
        for (int c = 1; c < 10; ++c) m = fmaxf(m, lg[c]);
        float s = 0.f;
        for (int c = 0; c < 10; ++c) s += expf(lg[c] - m);
        lse = m + logf(s);
    }
    __syncthreads();
    if (t < 10) out[(size_t)g * 10 + t] = lg[t] - lse;
}

extern "C" void kernel_launch(void* const* d_in, const int* in_sizes, int n_in,
                              void* d_out, int out_size, void* d_ws, size_t ws_size,
                              hipStream_t stream) {
    (void)in_sizes; (void)n_in; (void)out_size; (void)ws_size;
    const float* x    = (const float*)d_in[0];
    const int*   src  = (const int*)d_in[1];
    const int*   dst  = (const int*)d_in[2];
    const float* Wr1  = (const float*)d_in[3];
    const float* Wrel1= (const float*)d_in[4];
    const float* b1   = (const float*)d_in[5];
    const float* wp1  = (const float*)d_in[6];
    const float* Wr2  = (const float*)d_in[7];
    const float* Wrel2= (const float*)d_in[8];
    const float* b2   = (const float*)d_in[9];
    const float* wp2  = (const float*)d_in[10];
    const float* Wr3  = (const float*)d_in[11];
    const float* Wrel3= (const float*)d_in[12];
    const float* b3   = (const float*)d_in[13];
    const float* wp3  = (const float*)d_in[14];
    const float* L1w  = (const float*)d_in[15];
    const float* L1b  = (const float*)d_in[16];
    const float* L2w  = (const float*)d_in[17];
    const float* L2b  = (const float*)d_in[18];
    const float* L3w  = (const float*)d_in[19];
    const float* L3b  = (const float*)d_in[20];

    float*    A    = (float*)d_ws;                               // G*32768 f32 (h)
    int*      cmap = (int*)(A + (size_t)G * 32768);              // G*256 i32
    float*    R    = (float*)(cmap + (size_t)G * 256);           // G*768 f32
    unsigned* AGGF = (unsigned*)(R + (size_t)G * 768);           // G*2 tiles * 16384 u32
    unsigned* XF   = AGGF + (size_t)G * 2 * TILE_U32;            // G tiles * 16384 u32
    unsigned short* Wf = (unsigned short*)(XF + (size_t)G * TILE_U32);  // 3*65536 shorts
    float* out = (float*)d_out;

    k_wsplit<<<384, 256, 0, stream>>>(Wr1, Wrel1, Wr2, Wrel2, Wr3, Wrel3, Wf);

    // stage 1
    k_agg1<<<G, 1024, 0, stream>>>(x, src, dst, AGGF);
    k_gemm<256, true><<<512, 512, 0, stream>>>(x, A, AGGF, nullptr, Wf, b1);
    // pool1 + agg2 fused
    k_poolagg<256, 128, 1><<<G, 1024, 0, stream>>>(A, R, cmap, wp1, src, dst, XF, AGGF);
    // stage 2
    k_gemm<128, false><<<256, 512, 0, stream>>>(nullptr, A, AGGF, XF, Wf + 65536, b2);
    // pool2 + agg3 fused
    k_poolagg<128, 64, 2><<<G, 1024, 0, stream>>>(A, R, cmap, wp2, src, dst, XF, AGGF);
    // stage 3
    k_gemm<64, false><<<128, 512, 0, stream>>>(nullptr, A, AGGF, XF, Wf + 131072, b3);
    k_pool<64, 32, 3><<<G, 1024, 0, stream>>>(A, R, cmap, wp3);
    // head
    k_mlp<<<G, 1024, 0, stream>>>(R, L1w, L1b, L2w, L2b, L3w, L3b, out);
}

// Round 16
// 130.731 us; speedup vs baseline: 1.2187x; 1.0632x over previous
//
#include <hip/hip_runtime.h>
#include <cstdint>
#include <cstddef>

#define G 256
#define EPER 4096
#define F 128
#define TILE_U32 16384  // fragment tile: 16 ko * 128 row * 8 j (u32 each)

typedef __attribute__((ext_vector_type(8))) short short8;
typedef __attribute__((ext_vector_type(4))) float f32x4;

__device__ inline unsigned short f2bf(float f) {
    unsigned u = __float_as_uint(f);
    u += 0x7FFFu + ((u >> 16) & 1u);
    return (unsigned short)(u >> 16);
}
__device__ inline float bf2f(unsigned short b) { return __uint_as_float(((unsigned)b) << 16); }

// -------------------- W pre-split: [Wr;Wl] -> fragment-major bf16 hi/lo --------------------
__global__ __launch_bounds__(256) void k_wsplit(const float* __restrict__ Wr1, const float* __restrict__ Wl1,
                                                const float* __restrict__ Wr2, const float* __restrict__ Wl2,
                                                const float* __restrict__ Wr3, const float* __restrict__ Wl3,
                                                unsigned short* __restrict__ Wf) {
    int gid = blockIdx.x * 256 + threadIdx.x;   // 0..98303
    int s = gid >> 15;
    int idx = gid & 32767;
    int j = idx & 7, col = (idx >> 3) & 127, ko = idx >> 10;
    int k = ko * 8 + j;
    const float* Wr = (s == 0) ? Wr1 : (s == 1) ? Wr2 : Wr3;
    const float* Wl = (s == 0) ? Wl1 : (s == 1) ? Wl2 : Wl3;
    float f = (k < 128) ? Wr[(size_t)k * 128 + col] : Wl[(size_t)(k - 128) * 128 + col];
    unsigned short h1 = f2bf(f), h2 = f2bf(f - bf2f(h1));
    Wf[(size_t)s * 65536 + idx] = h1;
    Wf[(size_t)s * 65536 + 32768 + idx] = h2;
}

// -------------------- fused stage 1: agg1 + conv-gemm + pool + agg2 --------------------
// One block per graph, 1024 threads. h never leaves the block (regs -> LDS hp for
// the K selected rows only). AGG round-trips via AGGF1 (same-block L2). Outputs:
// R slice 1, cmap, XF (pooled rows, packed frags), AGGF2 (stage-2 agg frags).
__global__ __launch_bounds__(1024) void k_stage1(const float* __restrict__ X,
                                                 const int* __restrict__ src,
                                                 const int* __restrict__ dst,
                                                 const float* __restrict__ wp,
                                                 const float* __restrict__ bias,
                                                 const unsigned short* __restrict__ Wf,
                                                 int* __restrict__ cmap,
                                                 float* __restrict__ R,
                                                 unsigned* __restrict__ XF,
                                                 unsigned* __restrict__ AGGF1,
                                                 unsigned* __restrict__ AGGF2) {
    __shared__ __align__(16) char smem[107520];
    __shared__ float sc[256];
    __shared__ unsigned long long keys[256];
    __shared__ int sel[128];
    __shared__ int inv[256];
    __shared__ float wn[128];
    __shared__ float gates[128];
    __shared__ float pmx[8 * 128];
    __shared__ float psm[8 * 128];
    __shared__ int ncm[256];
    __shared__ float snorm_s;

    const int g = blockIdx.x, t = threadIdx.x;
    const int lane = t & 63, wv = t >> 6;
    const int l15 = lane & 15, lko = lane >> 4;

    // ---- wn = wp / ||wp|| ----
    if (t < 64) {
        float v = wp[t] * wp[t] + wp[t + 64] * wp[t + 64];
        #pragma unroll
        for (int o = 32; o; o >>= 1) v += __shfl_xor(v, o);
        if (t == 0) snorm_s = sqrtf(v);
    }

    // ================= phase A: agg1 = Adj @ x -> AGGF1 =================
    {
        unsigned* adjc = (unsigned*)smem;                  // 64 KB
        short* adjT = (short*)(smem + 65536);              // 16 KB
        short* xsA = (short*)(smem + 81920);               // 2 x 8 KB (hi at 0, lo at +4096 shorts)
        constexpr int NS = 256, NS4 = 64;
        {
            uint4* z = (uint4*)adjc;
            #pragma unroll
            for (int i = t; i < NS * NS4 / 4; i += 1024) z[i] = uint4{0, 0, 0, 0};
        }
        __syncthreads();
        if (t < 128) wn[t] = wp[t] / snorm_s;

        const int* sg = src + (size_t)g * EPER;
        const int* dg = dst + (size_t)g * EPER;
        #pragma unroll
        for (int j = 0; j < 4; ++j) {
            int e = j * 1024 + t;
            int s = sg[e], d = dg[e];
            int pos = (s + 4 * d) & (NS - 1);
            __hip_atomic_fetch_add(&adjc[d * NS4 + (pos >> 2)], 1u << ((pos & 3) * 8),
                                   __ATOMIC_RELAXED, __HIP_MEMORY_SCOPE_WORKGROUP);
        }

        f32x4 acc[8];
        #pragma unroll
        for (int c = 0; c < 8; ++c) acc[c] = f32x4{0.f, 0.f, 0.f, 0.f};
        const int mA = t >> 2, kgA = (t & 3) * 8;
        const int nX = t & 127, oX = (t >> 7) & 3;

        for (int k0 = 0; k0 < NS; k0 += 32) {
            __syncthreads();
            {
                unsigned short cs[8];
                #pragma unroll
                for (int q = 0; q < 2; ++q) {
                    unsigned w = adjc[mA * NS4 + ((((k0 + kgA) >> 2) + mA + q) & (NS4 - 1))];
                    cs[q * 4 + 0] = f2bf((float)(w & 255u));
                    cs[q * 4 + 1] = f2bf((float)((w >> 8) & 255u));
                    cs[q * 4 + 2] = f2bf((float)((w >> 16) & 255u));
                    cs[q * 4 + 3] = f2bf((float)(w >> 24));
                }
                short8 w8;
                #pragma unroll
                for (int j = 0; j < 8; ++j) w8[j] = (short)cs[j];
                *(short8*)&adjT[(t & 3) * NS * 8 + mA * 8] = w8;
            }
            if (t < 512) {
                short8 h1, h2;
                #pragma unroll
                for (int j = 0; j < 8; ++j) {
                    float f = X[(size_t)g * 32768 + (size_t)(k0 + oX * 8 + j) * F + nX];
                    unsigned short a1 = f2bf(f);
                    unsigned short a2 = f2bf(f - bf2f(a1));
                    h1[j] = (short)a1; h2[j] = (short)a2;
                }
                *(short8*)&xsA[oX * 1024 + nX * 8] = h1;
                *(short8*)&xsA[4096 + oX * 1024 + nX * 8] = h2;  // FIX (was 8192: read-uninit)
            }
            __syncthreads();
            short8 afr = *(const short8*)&adjT[lko * NS * 8 + (wv * 16 + l15) * 8];
            #pragma unroll
            for (int s = 0; s < 2; ++s) {
                #pragma unroll
                for (int ct = 0; ct < 8; ++ct) {
                    short8 bfr = *(const short8*)&xsA[s * 4096 + lko * 1024 + (ct * 16 + l15) * 8];
                    acc[ct] = __builtin_amdgcn_mfma_f32_16x16x32_bf16(afr, bfr, acc[ct], 0, 0, 0);
                }
            }
        }

        #pragma unroll
        for (int ct = 0; ct < 8; ++ct) {
            int feat = ct * 16 + l15;
            size_t fb = (size_t)(feat >> 3) * 1024 + (feat & 7);
            int r0 = wv * 16 + lko * 4;
            #pragma unroll
            for (int r = 0; r < 4; ++r) {
                int m = g * NS + r0 + r;
                float v = acc[ct][r];
                unsigned short hi = f2bf(v);
                unsigned short lo = f2bf(v - bf2f(hi));
                AGGF1[(size_t)(m >> 7) * TILE_U32 + fb + (size_t)(m & 127) * 8] =
                    (unsigned)hi | ((unsigned)lo << 16);
            }
        }
    }
    __syncthreads();  // drains vmcnt: AGGF1 visible; phase-A LDS dead

    // ================= phase B: h = relu([X|AGG] @ [Wr;Wl] + b), in regs =================
    f32x4 acc2[8];
    {
        uint4* Whi = (uint4*)smem;                 // 64 KB
        uint4* Afs = (uint4*)(smem + 65536);       // [2][4][256] = 32 KB
        const unsigned short* Wlo = Wf + 32768;
        {
            const uint4* Wf4 = (const uint4*)Wf;
            #pragma unroll
            for (int i = 0; i < 4; ++i) Whi[t + i * 1024] = Wf4[t + i * 1024];
        }
        #pragma unroll
        for (int c = 0; c < 8; ++c) acc2[c] = f32x4{0.f, 0.f, 0.f, 0.f};

        const int rs = t >> 2, ck = t & 3;       // f32 staging map
        const int rowp = t & 255, kop = t >> 8;  // packed staging map

        for (int kt = 0; kt < 8; ++kt) {
            __syncthreads();
            if (kt < 4) {
                const float* srow = X + (size_t)g * 32768 + (size_t)rs * 128 + kt * 32 + ck * 8;
                float4 fa = *(const float4*)srow;
                float4 fb = *(const float4*)(srow + 4);
                float vv[8] = {fa.x, fa.y, fa.z, fa.w, fb.x, fb.y, fb.z, fb.w};
                short8 h1, h2;
                #pragma unroll
                for (int j = 0; j < 8; ++j) {
                    unsigned short a1 = f2bf(vv[j]);
                    unsigned short a2 = f2bf(vv[j] - bf2f(a1));
                    h1[j] = (short)a1; h2[j] = (short)a2;
                }
                int rw = rs ^ (ck << 2);
                *reinterpret_cast<short8*>(&Afs[(0 * 4 + ck) * 256 + rw]) = h1;
                *reinterpret_cast<short8*>(&Afs[(1 * 4 + ck) * 256 + rw]) = h2;
            } else {
                int ko = (kt & 3) * 4 + kop;
                int tile = 2 * g + (rowp >> 7);
                size_t idx = (size_t)tile * TILE_U32 + (size_t)ko * 1024 + (size_t)(rowp & 127) * 8;
                uint4 qa = *(const uint4*)(AGGF1 + idx);
                uint4 qb = *(const uint4*)(AGGF1 + idx + 4);
                short8 h1, h2;
                h1[0] = (short)qa.x; h2[0] = (short)(qa.x >> 16);
                h1[1] = (short)qa.y; h2[1] = (short)(qa.y >> 16);
                h1[2] = (short)qa.z; h2[2] = (short)(qa.z >> 16);
                h1[3] = (short)qa.w; h2[3] = (short)(qa.w >> 16);
                h1[4] = (short)qb.x; h2[4] = (short)(qb.x >> 16);
                h1[5] = (short)qb.y; h2[5] = (short)(qb.y >> 16);
                h1[6] = (short)qb.z; h2[6] = (short)(qb.z >> 16);
                h1[7] = (short)qb.w; h2[7] = (short)(qb.w >> 16);
                int rw = rowp ^ (kop << 2);
                *reinterpret_cast<short8*>(&Afs[(0 * 4 + kop) * 256 + rw]) = h1;
                *reinterpret_cast<short8*>(&Afs[(1 * 4 + kop) * 256 + rw]) = h2;
            }
            __syncthreads();

            int row = (wv * 16 + l15) ^ (lko << 2);
            short8 a1f = *reinterpret_cast<const short8*>(&Afs[(0 * 4 + lko) * 256 + row]);
            short8 a2f = *reinterpret_cast<const short8*>(&Afs[(1 * 4 + lko) * 256 + row]);
            const int kog = kt * 4 + lko;
            #pragma unroll
            for (int ct = 0; ct < 8; ++ct) {
                int col = ct * 16 + l15;
                short8 w1 = *reinterpret_cast<const short8*>(&Whi[kog * 128 + col]);
                short8 w2 = *reinterpret_cast<const short8*>(Wlo + ((size_t)kog * 128 + col) * 8);
                acc2[ct] = __builtin_amdgcn_mfma_f32_16x16x32_bf16(a1f, w1, acc2[ct], 0, 0, 0);
                acc2[ct] = __builtin_amdgcn_mfma_f32_16x16x32_bf16(a2f, w1, acc2[ct], 0, 0, 0);
                acc2[ct] = __builtin_amdgcn_mfma_f32_16x16x32_bf16(a1f, w2, acc2[ct], 0, 0, 0);
            }
        }
    }
    __syncthreads();  // Afs dead

    // bias + relu fold (h stays in acc2; row = wv*16 + lko*4 + r, col = ct*16 + l15)
    #pragma unroll
    for (int ct = 0; ct < 8; ++ct) {
        float bv = bias[ct * 16 + l15];
        #pragma unroll
        for (int r = 0; r < 4; ++r) acc2[ct][r] = fmaxf(acc2[ct][r] + bv, 0.f);
    }

    // ================= phase C: scores + top-k =================
    {
        unsigned* adjc2 = (unsigned*)(smem + 66560);
        for (int i = t; i < 4096; i += 1024) adjc2[i] = 0;  // zero 16 KB for agg2
        float wnv[8];
        #pragma unroll
        for (int ct = 0; ct < 8; ++ct) wnv[ct] = wn[ct * 16 + l15];
        #pragma unroll
        for (int r = 0; r < 4; ++r) {
            float p = 0.f;
            #pragma unroll
            for (int ct = 0; ct < 8; ++ct) p += acc2[ct][r] * wnv[ct];
            p += __shfl_xor(p, 1); p += __shfl_xor(p, 2);
            p += __shfl_xor(p, 4); p += __shfl_xor(p, 8);
            if (l15 == 0) sc[wv * 16 + lko * 4 + r] = p;
        }
    }
    __syncthreads();

    if (t < 256) {
        unsigned u = __float_as_uint(sc[t]);
        u = (u & 0x80000000u) ? ~u : (u | 0x80000000u);
        keys[t] = ((unsigned long long)u << 32) | (unsigned)(~t);
    }
    __syncthreads();
    for (int kk = 2; kk <= 256; kk <<= 1) {
        for (int j = kk >> 1; j > 0; j >>= 1) {
            if (t < 256) {
                int ixj = t ^ j;
                if (ixj > t) {
                    unsigned long long a = keys[t], b = keys[ixj];
                    bool up = (t & kk) == 0;
                    if (up ? (a < b) : (a > b)) { keys[t] = b; keys[ixj] = a; }
                }
            }
            __syncthreads();
        }
    }
    if (t < 128) sel[t] = (int)(~(unsigned)keys[t]);
    if (t < 256) inv[t] = -1;
    __syncthreads();
    if (t < 128) {
        inv[sel[t]] = t;
        gates[t] = tanhf(sc[sel[t]]);
    }
    __syncthreads();
    if (t < 256) {
        int nc = inv[t];  // STAGE 1: composed map = inv
        ncm[t] = nc;
        cmap[g * 256 + t] = nc;
    }
    __syncthreads();

    // ================= phase D: write selected rows to hp (packed u32, pad 130) ==========
    {
        unsigned* hp = (unsigned*)smem;  // 128 x 130 u32 = 66560 B
        #pragma unroll
        for (int r = 0; r < 4; ++r) {
            int rowg = wv * 16 + lko * 4 + r;
            int j = inv[rowg];
            if (j >= 0) {
                float gt = gates[j];
                #pragma unroll
                for (int ct = 0; ct < 8; ++ct) {
                    float v = acc2[ct][r] * gt;
                    unsigned short hi = f2bf(v);
                    unsigned short lo = f2bf(v - bf2f(hi));
                    hp[j * 130 + ct * 16 + l15] = (unsigned)hi | ((unsigned)lo << 16);
                }
            }
        }
    }
    __syncthreads();

    // ================= phase E: edge-build + readout + XF + agg2 -> AGGF2 ================
    {
        unsigned* hp = (unsigned*)smem;
        unsigned* adjc2 = (unsigned*)(smem + 66560);   // 16 KB
        short* adjT2 = (short*)(smem + 82944);         // 8 KB
        short* xs2 = (short*)(smem + 91136);           // 2 x 8 KB
        constexpr int K = 128, NS4 = 32;

        {
            const int* sg = src + (size_t)g * EPER;
            const int* dg = dst + (size_t)g * EPER;
            #pragma unroll
            for (int j = 0; j < 4; ++j) {
                int e = j * 1024 + t;
                int s = ncm[sg[e]], d = ncm[dg[e]];
                if (s >= 0 && d >= 0) {
                    int pos = (s + 4 * d) & (K - 1);
                    __hip_atomic_fetch_add(&adjc2[d * NS4 + (pos >> 2)], 1u << ((pos & 3) * 8),
                                           __ATOMIC_RELAXED, __HIP_MEMORY_SCOPE_WORKGROUP);
                }
            }
        }
        // readout partials
        {
            const int f = t & 127, seg = t >> 7;
            float mx = -INFINITY, sm = 0.f;
            for (int j = seg; j < K; j += 8) {
                unsigned u = hp[j * 130 + f];
                float v = bf2f((unsigned short)(u & 0xffffu)) + bf2f((unsigned short)(u >> 16));
                mx = fmaxf(mx, v);
                sm += v;
            }
            pmx[seg * 128 + f] = mx;
            psm[seg * 128 + f] = sm;
        }
        // XF write (packed copy, frag layout)
        for (int i = t; i < K * F; i += 1024) {
            int j = i >> 7, f = i & 127;
            int m = g * K + j;
            XF[(size_t)(m >> 7) * TILE_U32 + (size_t)(f >> 3) * 1024 + (size_t)(m & 127) * 8 + (f & 7)] =
                hp[j * 130 + f];
        }
        __syncthreads();
        if (t < 128) {
            float m = -INFINITY, s = 0.f;
            #pragma unroll
            for (int q = 0; q < 8; ++q) {
                m = fmaxf(m, pmx[q * 128 + t]);
                s += psm[q * 128 + t];
            }
            R[(size_t)g * 768 + t] = m;
            R[(size_t)g * 768 + 128 + t] = s * (1.0f / K);
        }

        // agg2 MFMA: 16 waves, rt = wv>>1 (8 row-tiles), cq = wv&1 (2 col-halves x 4 ct)
        const int rt = wv >> 1, cq = wv & 1;
        f32x4 acc3[4];
        #pragma unroll
        for (int c = 0; c < 4; ++c) acc3[c] = f32x4{0.f, 0.f, 0.f, 0.f};

        for (int k0 = 0; k0 < K; k0 += 32) {
            __syncthreads();
            if (t < K * 4) {
                const int m = t >> 2, kg = (t & 3) * 8;
                unsigned short cs[8];
                #pragma unroll
                for (int q = 0; q < 2; ++q) {
                    unsigned w = adjc2[m * NS4 + ((((k0 + kg) >> 2) + m + q) & (NS4 - 1))];
                    cs[q * 4 + 0] = f2bf((float)(w & 255u));
                    cs[q * 4 + 1] = f2bf((float)((w >> 8) & 255u));
                    cs[q * 4 + 2] = f2bf((float)((w >> 16) & 255u));
                    cs[q * 4 + 3] = f2bf((float)(w >> 24));
                }
                short8 w8;
                #pragma unroll
                for (int j = 0; j < 8; ++j) w8[j] = (short)cs[j];
                *(short8*)&adjT2[(t & 3) * K * 8 + m * 8] = w8;
            }
            if (t >= 512) {
                const int feat = t & 127, o = (t >> 7) & 3;
                short8 h1, h2;
                #pragma unroll
                for (int j = 0; j < 8; ++j) {
                    unsigned u = hp[(k0 + o * 8 + j) * 130 + feat];
                    h1[j] = (short)(u & 0xffffu);
                    h2[j] = (short)(u >> 16);
                }
                *(short8*)&xs2[o * 1024 + feat * 8] = h1;
                *(short8*)&xs2[4096 + o * 1024 + feat * 8] = h2;
            }
            __syncthreads();

            short8 afr = *(const short8*)&adjT2[lko * K * 8 + (rt * 16 + l15) * 8];
            #pragma unroll
            for (int s = 0; s < 2; ++s) {
                #pragma unroll
                for (int ct = 0; ct < 4; ++ct) {
                    int feat = cq * 64 + ct * 16 + l15;
                    short8 bfr = *(const short8*)&xs2[s * 4096 + lko * 1024 + feat * 8];
                    acc3[ct] = __builtin_amdgcn_mfma_f32_16x16x32_bf16(afr, bfr, acc3[ct], 0, 0, 0);
                }
            }
        }

        #pragma unroll
        for (int ct = 0; ct < 4; ++ct) {
            int feat = cq * 64 + ct * 16 + l15;
            size_t fb = (size_t)(feat >> 3) * 1024 + (feat & 7);
            int r0 = rt * 16 + lko * 4;
            #pragma unroll
            for (int r = 0; r < 4; ++r) {
                int m = g * K + r0 + r;
                float v = acc3[ct][r];
                unsigned short hi = f2bf(v);
                unsigned short lo = f2bf(v - bf2f(hi));
                AGGF2[(size_t)(m >> 7) * TILE_U32 + fb + (size_t)(m & 127) * 8] =
                    (unsigned)hi | ((unsigned)lo << 16);
            }
        }
    }
}

// -------------------- conv GEMM on MFMA (stages 2/3) --------------------
template<int NS, bool FIRST>
__global__ __launch_bounds__(512, 4) void k_gemm(const float* __restrict__ X,
                                                 float* __restrict__ A,
                                                 const unsigned* __restrict__ AGGF,
                                                 const unsigned* __restrict__ XF,
                                                 const unsigned short* __restrict__ Wf,
                                                 const float* __restrict__ bias) {
    constexpr int L2NS = (NS == 256) ? 8 : (NS == 128) ? 7 : 6;
    __shared__ uint4 Whi[32][128];
    __shared__ uint4 Afs[2][4][128];
    const int t = threadIdx.x;
    const int m0 = blockIdx.x * 128;
    const int lane = t & 63;
    const int wv = t >> 6, wr = wv >> 1, wc = wv & 1;
    const int l15 = lane & 15, lko = lane >> 4;
    const unsigned short* Wlo = Wf + 32768;

    {
        const uint4* Wf4 = (const uint4*)Wf;
        uint4* Wd = (uint4*)Whi;
        #pragma unroll
        for (int i = 0; i < 8; ++i) Wd[t + i * 512] = Wf4[t + i * 512];
    }

    f32x4 acc[2][4];
    #pragma unroll
    for (int i = 0; i < 2; ++i)
        #pragma unroll
        for (int c = 0; c < 4; ++c) acc[i][c] = f32x4{0.f, 0.f, 0.f, 0.f};

    const int rowp = t & 127, kop = t >> 7;

    for (int kt = 0; kt < 8; ++kt) {
        __syncthreads();
        {
            const unsigned* P = (kt < 4) ? XF : AGGF;
            int ko = (kt & 3) * 4 + kop;
            size_t idx = (size_t)blockIdx.x * TILE_U32 + (size_t)ko * 1024 + (size_t)rowp * 8;
            uint4 qa = *(const uint4*)(P + idx);
            uint4 qb = *(const uint4*)(P + idx + 4);
            short8 h1, h2;
            h1[0] = (short)qa.x; h2[0] = (short)(qa.x >> 16);
            h1[1] = (short)qa.y; h2[1] = (short)(qa.y >> 16);
            h1[2] = (short)qa.z; h2[2] = (short)(qa.z >> 16);
            h1[3] = (short)qa.w; h2[3] = (short)(qa.w >> 16);
            h1[4] = (short)qb.x; h2[4] = (short)(qb.x >> 16);
            h1[5] = (short)qb.y; h2[5] = (short)(qb.y >> 16);
            h1[6] = (short)qb.z; h2[6] = (short)(qb.z >> 16);
            h1[7] = (short)qb.w; h2[7] = (short)(qb.w >> 16);
            int rw = rowp ^ (kop << 2);
            *reinterpret_cast<short8*>(&Afs[0][kop][rw]) = h1;
            *reinterpret_cast<short8*>(&Afs[1][kop][rw]) = h2;
        }
        __syncthreads();

        short8 a1f[2], a2f[2];
        #pragma unroll
        for (int mt = 0; mt < 2; ++mt) {
            int row = (wr * 32 + mt * 16 + l15) ^ (lko << 2);
            a1f[mt] = *reinterpret_cast<const short8*>(&Afs[0][lko][row]);
            a2f[mt] = *reinterpret_cast<const short8*>(&Afs[1][lko][row]);
        }
        const int kog = kt * 4 + lko;
        #pragma unroll
        for (int ct = 0; ct < 4; ++ct) {
            int col = wc * 64 + ct * 16 + l15;
            short8 w1 = *reinterpret_cast<const short8*>(&Whi[kog][col]);
            short8 w2 = *reinterpret_cast<const short8*>(Wlo + ((size_t)kog * 128 + col) * 8);
            #pragma unroll
            for (int mt = 0; mt < 2; ++mt) {
                acc[mt][ct] = __builtin_amdgcn_mfma_f32_16x16x32_bf16(a1f[mt], w1, acc[mt][ct], 0, 0, 0);
                acc[mt][ct] = __builtin_amdgcn_mfma_f32_16x16x32_bf16(a2f[mt], w1, acc[mt][ct], 0, 0, 0);
                acc[mt][ct] = __builtin_amdgcn_mfma_f32_16x16x32_bf16(a1f[mt], w2, acc[mt][ct], 0, 0, 0);
            }
        }
    }

    #pragma unroll
    for (int ct = 0; ct < 4; ++ct) {
        int col = wc * 64 + ct * 16 + l15;
        float bv = bias[col];
        #pragma unroll
        for (int mt = 0; mt < 2; ++mt) {
            int r0 = m0 + wr * 32 + mt * 16 + lko * 4;
            #pragma unroll
            for (int r = 0; r < 4; ++r) {
                int m = r0 + r;
                int gg = m >> L2NS, nn = m & (NS - 1);
                A[(size_t)gg * 32768 + (size_t)nn * F + col] = fmaxf(acc[mt][ct][r] + bv, 0.f);
            }
        }
    }
}

// -------------------- fused pool + next-stage agg --------------------
template<int N, int K, int STAGE>
__global__ __launch_bounds__(1024) void k_poolagg(const float* __restrict__ A,
                                                  float* __restrict__ R,
                                                  int* __restrict__ cmap,
                                                  const float* __restrict__ wp,
                                                  const int* __restrict__ src,
                                                  const int* __restrict__ dst,
                                                  unsigned* __restrict__ XF,
                                                  unsigned* __restrict__ AGGF) {
    constexpr int NS4 = K / 4;
    __shared__ float sc[N];
    __shared__ unsigned long long keys[N];
    __shared__ float hp[K * F];
    __shared__ int sel[K];
    __shared__ int inv[N];
    __shared__ float wn[F];
    __shared__ float gates[K];
    __shared__ float pmx[8 * F];
    __shared__ float psm[8 * F];
    __shared__ float snorm_s;
    __shared__ int ncm[256];
    __shared__ unsigned adjc[K * NS4];
    __shared__ short adjT[4 * K * 8];
    __shared__ short xs[2][4 * 128 * 8];

    const int g = blockIdx.x, t = threadIdx.x;
    const float* h = A + (size_t)g * 32768;
    const int lane = t & 63, wv16 = t >> 6;

    {
        uint4* z = (uint4*)adjc;
        for (int i = t; i < K * NS4 / 4; i += 1024) z[i] = uint4{0, 0, 0, 0};
    }
    if (t < 64) {
        float v = wp[t] * wp[t] + wp[t + 64] * wp[t + 64];
        #pragma unroll
        for (int o = 32; o; o >>= 1) v += __shfl_xor(v, o);
        if (t == 0) snorm_s = sqrtf(v);
    }
    __syncthreads();
    if (t < 128) wn[t] = wp[t] / snorm_s;
    __syncthreads();

    {
        const int r16 = lane >> 4, l16 = lane & 15;
        float4 w0 = *(const float4*)&wn[l16 * 8];
        float4 w1 = *(const float4*)&wn[l16 * 8 + 4];
        #pragma unroll
        for (int n0 = 0; n0 < N; n0 += 64) {
            int r = n0 + wv16 * 4 + r16;
            const float* hr = h + (size_t)r * F + l16 * 8;
            float4 v0 = *(const float4*)hr;
            float4 v1 = *(const float4*)(hr + 4);
            float p = v0.x * w0.x + v0.y * w0.y + v0.z * w0.z + v0.w * w0.w
                    + v1.x * w1.x + v1.y * w1.y + v1.z * w1.z + v1.w * w1.w;
            p += __shfl_xor(p, 1); p += __shfl_xor(p, 2);
            p += __shfl_xor(p, 4); p += __shfl_xor(p, 8);
            if (l16 == 0) sc[r] = p;
        }
    }
    __syncthreads();

    if (t < N) {
        unsigned u = __float_as_uint(sc[t]);
        u = (u & 0x80000000u) ? ~u : (u | 0x80000000u);
        keys[t] = ((unsigned long long)u << 32) | (unsigned)(~t);
    }
    __syncthreads();
    for (int kk = 2; kk <= N; kk <<= 1) {
        for (int j = kk >> 1; j > 0; j >>= 1) {
            if (t < N) {
                int ixj = t ^ j;
                if (ixj > t) {
                    unsigned long long a = keys[t], b = keys[ixj];
                    bool up = (t & kk) == 0;
                    if (up ? (a < b) : (a > b)) { keys[t] = b; keys[ixj] = a; }
                }
            }
            __syncthreads();
        }
    }

    if (t < K) sel[t] = (int)(~(unsigned)keys[t]);
    if (t < N) inv[t] = -1;
    __syncthreads();
    if (t < K) {
        inv[sel[t]] = t;
        gates[t] = tanhf(sc[sel[t]]);
    }
    __syncthreads();

    if (t < 256) {
        int c = (STAGE == 1) ? t : cmap[g * 256 + t];
        int nc = (c >= 0) ? inv[c] : -1;
        ncm[t] = nc;
        cmap[g * 256 + t] = nc;
    }
    {
        const int f = t & 127, seg = t >> 7;
        float mx = -INFINITY, sm = 0.f;
        for (int j = seg; j < K; j += 8) {
            float v = h[(size_t)sel[j] * F + f] * gates[j];
            hp[j * F + f] = v;
            mx = fmaxf(mx, v);
            sm += v;
        }
        pmx[seg * F + f] = mx;
        psm[seg * F + f] = sm;
    }
    __syncthreads();

    {
        const int* sg = src + (size_t)g * EPER;
        const int* dg = dst + (size_t)g * EPER;
        #pragma unroll
        for (int j = 0; j < 4; ++j) {
            int e = j * 1024 + t;
            int s = ncm[sg[e]], d = ncm[dg[e]];
            if (s >= 0 && d >= 0) {
                int pos = (s + 4 * d) & (K - 1);
                __hip_atomic_fetch_add(&adjc[d * NS4 + (pos >> 2)], 1u << ((pos & 3) * 8),
                                       __ATOMIC_RELAXED, __HIP_MEMORY_SCOPE_WORKGROUP);
            }
        }
    }
    if (t < 128) {
        float m = -INFINITY, s = 0.f;
        #pragma unroll
        for (int q = 0; q < 8; ++q) {
            m = fmaxf(m, pmx[q * F + t]);
            s += psm[q * F + t];
        }
        R[(size_t)g * 768 + (STAGE - 1) * 256 + t] = m;
        R[(size_t)g * 768 + (STAGE - 1) * 256 + 128 + t] = s * (1.0f / K);
    }
    for (int i = t; i < K * F; i += 1024) {
        int j = i >> 7, f = i & 127;
        float v = hp[j * F + f];
        unsigned short hi = f2bf(v);
        unsigned short lo = f2bf(v - bf2f(hi));
        int m = g * K + j;
        XF[(size_t)(m >> 7) * TILE_U32 + (size_t)(f >> 3) * 1024 + (size_t)(m & 127) * 8 + (f & 7)] =
            (unsigned)hi | ((unsigned)lo << 16);
    }
    __syncthreads();

    constexpr int CTN = (K == 128) ? 4 : 2;
    const int rt = (K == 128) ? (wv16 >> 1) : (wv16 >> 2);
    const int cq = (K == 128) ? (wv16 & 1) : (wv16 & 3);
    f32x4 acc[CTN];
    #pragma unroll
    for (int c = 0; c < CTN; ++c) acc[c] = f32x4{0.f, 0.f, 0.f, 0.f};

    for (int k0 = 0; k0 < K; k0 += 32) {
        __syncthreads();
        if (t < K * 4) {
            const int m = t >> 2, kg = (t & 3) * 8;
            unsigned short cs[8];
            #pragma unroll
            for (int q = 0; q < 2; ++q) {
                unsigned w = adjc[m * NS4 + ((((k0 + kg) >> 2) + m + q) & (NS4 - 1))];
                cs[q * 4 + 0] = f2bf((float)(w & 255u));
                cs[q * 4 + 1] = f2bf((float)((w >> 8) & 255u));
                cs[q * 4 + 2] = f2bf((float)((w >> 16) & 255u));
                cs[q * 4 + 3] = f2bf((float)(w >> 24));
            }
            short8 w8;
            #pragma unroll
            for (int j = 0; j < 8; ++j) w8[j] = (short)cs[j];
            *(short8*)&adjT[(t & 3) * K * 8 + m * 8] = w8;
        }
        if (t >= 512) {
            const int feat = t & 127, o = (t >> 7) & 3;
            short8 h1, h2;
            #pragma unroll
            for (int j = 0; j < 8; ++j) {
                float f = hp[(k0 + o * 8 + j) * F + feat];
                unsigned short a1 = f2bf(f);
                unsigned short a2 = f2bf(f - bf2f(a1));
                h1[j] = (short)a1; h2[j] = (short)a2;
            }
            *(short8*)&xs[0][o * 1024 + feat * 8] = h1;
            *(short8*)&xs[1][o * 1024 + feat * 8] = h2;
        }
        __syncthreads();

        short8 afr = *(const short8*)&adjT[(lane >> 4) * K * 8 + (rt * 16 + (lane & 15)) * 8];
        #pragma unroll
        for (int s = 0; s < 2; ++s) {
            #pragma unroll
            for (int ct = 0; ct < CTN; ++ct) {
                int feat = cq * (CTN * 16) + ct * 16 + (lane & 15);
                short8 bfr = *(const short8*)&xs[s][(lane >> 4) * 1024 + feat * 8];
                acc[ct] = __builtin_amdgcn_mfma_f32_16x16x32_bf16(afr, bfr, acc[ct], 0, 0, 0);
            }
        }
    }

    #pragma unroll
    for (int ct = 0; ct < CTN; ++ct) {
        int feat = cq * (CTN * 16) + ct * 16 + (lane & 15);
        size_t fb = (size_t)(feat >> 3) * 1024 + (feat & 7);
        int r0 = rt * 16 + (lane >> 4) * 4;
        #pragma unroll
        for (int r = 0; r < 4; ++r) {
            int m = g * K + r0 + r;
            float v = acc[ct][r];
            unsigned short hi = f2bf(v);
            unsigned short lo = f2bf(v - bf2f(hi));
            AGGF[(size_t)(m >> 7) * TILE_U32 + fb + (size_t)(m & 127) * 8] =
                (unsigned)hi | ((unsigned)lo << 16);
        }
    }
}

// -------------------- final top-k pool + readout (stage 3) --------------------
template<int N, int K, int STAGE>
__global__ __launch_bounds__(1024) void k_pool(float* __restrict__ A,
                                               float* __restrict__ R,
                                               int* __restrict__ cmap,
                                               const float* __restrict__ wp) {
    __shared__ float sc[N];
    __shared__ unsigned long long keys[N];
    __shared__ float hp[K * F];
    __shared__ int sel[K];
    __shared__ float wn[F];
    __shared__ float gates[K];
    __shared__ float pmx[8 * F];
    __shared__ float psm[8 * F];
    __shared__ float snorm_s;
    const int g = blockIdx.x, t = threadIdx.x;
    const float* h = A + (size_t)g * 32768;
    const int lane = t & 63, wv16 = t >> 6;

    if (t < 64) {
        float v = wp[t] * wp[t] + wp[t + 64] * wp[t + 64];
        #pragma unroll
        for (int o = 32; o; o >>= 1) v += __shfl_xor(v, o);
        if (t == 0) snorm_s = sqrtf(v);
    }
    __syncthreads();
    if (t < 128) wn[t] = wp[t] / snorm_s;
    __syncthreads();

    {
        const int r16 = lane >> 4, l16 = lane & 15;
        float4 w0 = *(const float4*)&wn[l16 * 8];
        float4 w1 = *(const float4*)&wn[l16 * 8 + 4];
        #pragma unroll
        for (int n0 = 0; n0 < N; n0 += 64) {
            int r = n0 + wv16 * 4 + r16;
            if (r < N) {
                const float* hr = h + (size_t)r * F + l16 * 8;
                float4 v0 = *(const float4*)hr;
                float4 v1 = *(const float4*)(hr + 4);
                float p = v0.x * w0.x + v0.y * w0.y + v0.z * w0.z + v0.w * w0.w
                        + v1.x * w1.x + v1.y * w1.y + v1.z * w1.z + v1.w * w1.w;
                p += __shfl_xor(p, 1); p += __shfl_xor(p, 2);
                p += __shfl_xor(p, 4); p += __shfl_xor(p, 8);
                if (l16 == 0) sc[r] = p;
            }
        }
    }
    __syncthreads();

    if (t < N) {
        unsigned u = __float_as_uint(sc[t]);
        u = (u & 0x80000000u) ? ~u : (u | 0x80000000u);
        keys[t] = ((unsigned long long)u << 32) | (unsigned)(~t);
    }
    __syncthreads();
    for (int kk = 2; kk <= N; kk <<= 1) {
        for (int j = kk >> 1; j > 0; j >>= 1) {
            if (t < N) {
                int ixj = t ^ j;
                if (ixj > t) {
                    unsigned long long a = keys[t], b = keys[ixj];
                    bool up = (t & kk) == 0;
                    if (up ? (a < b) : (a > b)) { keys[t] = b; keys[ixj] = a; }
                }
            }
            __syncthreads();
        }
    }

    if (t < K) {
        sel[t] = (int)(~(unsigned)keys[t]);
        gates[t] = tanhf(sc[sel[t]]);
    }
    __syncthreads();

    {
        const int f = t & 127, seg = t >> 7;
        float mx = -INFINITY, sm = 0.f;
        for (int j = seg; j < K; j += 8) {
            float v = h[(size_t)sel[j] * F + f] * gates[j];
            hp[j * F + f] = v;
            mx = fmaxf(mx, v);
            sm += v;
        }
        pmx[seg * F + f] = mx;
        psm[seg * F + f] = sm;
    }
    __syncthreads();

    if (t < 128) {
        float m = -INFINITY, s = 0.f;
        #pragma unroll
        for (int q = 0; q < 8; ++q) {
            m = fmaxf(m, pmx[q * F + t]);
            s += psm[q * F + t];
        }
        R[(size_t)g * 768 + (STAGE - 1) * 256 + t] = m;
        R[(size_t)g * 768 + (STAGE - 1) * 256 + 128 + t] = s * (1.0f / K);
    }
}

// -------------------- final MLP + log_softmax (split-K, 1024 threads) --------------------
__global__ __launch_bounds__(1024) void k_mlp(const float* __restrict__ R,
                                              const float* __restrict__ W1, const float* __restrict__ b1,
                                              const float* __restrict__ W2, const float* __restrict__ b2,
                                              const float* __restrict__ W3, const float* __restrict__ b3,
                                              float* __restrict__ out) {
    __shared__ float z[768];
    __shared__ float part[8][128];
    __shared__ float z2[128];
    __shared__ float z3[64];
    __shared__ float lg[10];
    __shared__ float lse;
    const int g = blockIdx.x, t = threadIdx.x;

    if (t < 768) z[t] = R[(size_t)g * 768 + t];
    __syncthreads();

    {
        const int f = t & 127, seg = t >> 7;
        float acc = 0.f;
        const float* w = W1 + (size_t)(seg * 96) * 128 + f;
        const float* zz = z + seg * 96;
        #pragma unroll 8
        for (int k = 0; k < 96; ++k) acc = fmaf(zz[k], w[(size_t)k * 128], acc);
        part[seg][f] = acc;
    }
    __syncthreads();
    if (t < 128) {
        float a = b1[t];
        #pragma unroll
        for (int q = 0; q < 8; ++q) a += part[q][t];
        z2[t] = fmaxf(a, 0.f);
    }
    __syncthreads();

    if (t < 512) {
        const int f = t & 63, seg = t >> 6;
        float acc = 0.f;
        const float* w = W2 + (size_t)(seg * 16) * 64 + f;
        const float* zz = z2 + seg * 16;
        #pragma unroll
        for (int k = 0; k < 16; ++k) acc = fmaf(zz[k], w[(size_t)k * 64], acc);
        part[seg][f] = acc;
    }
    __syncthreads();
    if (t < 64) {
        float a = b2[t];
        #pragma unroll
        for (int q = 0; q < 8; ++q) a += part[q][t];
        z3[t] = fmaxf(a, 0.f);
    }
    __syncthreads();

    if (t < 10) {
        float a3 = b3[t];
        #pragma unroll 8
        for (int k = 0; k < 64; ++k) a3 = fmaf(z3[k], W3[(size_t)k * 10 + t], a3);
        lg[t] = a3;
    }
    __syncthreads();

    if (t == 0) {
        float m = lg[0];
        for (int c = 1; c < 10; ++c) m = fmaxf(m, lg[c]);
        float s = 0.f;
        for (int c = 0; c < 10; ++c) s += expf(lg[c] - m);
        lse = m + logf(s);
    }
    __syncthreads();
    if (t < 10) out[(size_t)g * 10 + t] = lg[t] - lse;
}

extern "C" void kernel_launch(void* const* d_in, const int* in_sizes, int n_in,
                              void* d_out, int out_size, void* d_ws, size_t ws_size,
                              hipStream_t stream) {
    (void)in_sizes; (void)n_in; (void)out_size; (void)ws_size;
    const float* x    = (const float*)d_in[0];
    const int*   src  = (const int*)d_in[1];
    const int*   dst  = (const int*)d_in[2];
    const float* Wr1  = (const float*)d_in[3];
    const float* Wrel1= (const float*)d_in[4];
    const float* b1   = (const float*)d_in[5];
    const float* wp1  = (const float*)d_in[6];
    const float* Wr2  = (const float*)d_in[7];
    const float* Wrel2= (const float*)d_in[8];
    const float* b2   = (const float*)d_in[9];
    const float* wp2  = (const float*)d_in[10];
    const float* Wr3  = (const float*)d_in[11];
    const float* Wrel3= (const float*)d_in[12];
    const float* b3   = (const float*)d_in[13];
    const float* wp3  = (const float*)d_in[14];
    const float* L1w  = (const float*)d_in[15];
    const float* L1b  = (const float*)d_in[16];
    const float* L2w  = (const float*)d_in[17];
    const float* L2b  = (const float*)d_in[18];
    const float* L3w  = (const float*)d_in[19];
    const float* L3b  = (const float*)d_in[20];

    float*    A     = (float*)d_ws;                               // G*32768 f32 (h, stages 2/3)
    int*      cmap  = (int*)(A + (size_t)G * 32768);              // G*256 i32
    float*    R     = (float*)(cmap + (size_t)G * 256);           // G*768 f32
    unsigned* AGGF1 = (unsigned*)(R + (size_t)G * 768);           // G*2 tiles (stage-1 agg)
    unsigned* AGGF2 = AGGF1 + (size_t)G * 2 * TILE_U32;           // G tiles (agg2/agg3)
    unsigned* XF    = AGGF2 + (size_t)G * TILE_U32;               // G tiles (pooled rows)
    unsigned short* Wf = (unsigned short*)(XF + (size_t)G * TILE_U32);  // 3*65536 shorts
    float* out = (float*)d_out;

    k_wsplit<<<384, 256, 0, stream>>>(Wr1, Wrel1, Wr2, Wrel2, Wr3, Wrel3, Wf);

    // stage 1 fused: agg1 + gemm1 + pool1 + agg2
    k_stage1<<<G, 1024, 0, stream>>>(x, src, dst, wp1, b1, Wf, cmap, R, XF, AGGF1, AGGF2);
    // stage 2
    k_gemm<128, false><<<256, 512, 0, stream>>>(nullptr, A, AGGF2, XF, Wf + 65536, b2);
    k_poolagg<128, 64, 2><<<G, 1024, 0, stream>>>(A, R, cmap, wp2, src, dst, XF, AGGF2);
    // stage 3
    k_gemm<64, false><<<128, 512, 0, stream>>>(nullptr, A, AGGF2, XF, Wf + 131072, b3);
    k_pool<64, 32, 3><<<G, 1024, 0, stream>>>(A, R, cmap, wp3);
    // head
    k_mlp<<<G, 1024, 0, stream>>>(R, L1w, L1b, L2w, L2b, L3w, L3b, out);
}

// Round 17
// 118.360 us; speedup vs baseline: 1.3460x; 1.1045x over previous
//
#include <hip/hip_runtime.h>
#include <cstdint>
#include <cstddef>

#define G 256
#define EPER 4096
#define F 128
#define TILE_U32 16384  // fragment tile: 16 ko * 128 row * 8 j (u32 each)

typedef __attribute__((ext_vector_type(8))) short short8;
typedef __attribute__((ext_vector_type(4))) float f32x4;

__device__ inline unsigned short f2bf(float f) {
    unsigned u = __float_as_uint(f);
    u += 0x7FFFu + ((u >> 16) & 1u);
    return (unsigned short)(u >> 16);
}
__device__ inline float bf2f(unsigned short b) { return __uint_as_float(((unsigned)b) << 16); }

__device__ inline void unpack2(uint4 qa, uint4 qb, short8& h1, short8& h2) {
    h1[0] = (short)qa.x; h2[0] = (short)(qa.x >> 16);
    h1[1] = (short)qa.y; h2[1] = (short)(qa.y >> 16);
    h1[2] = (short)qa.z; h2[2] = (short)(qa.z >> 16);
    h1[3] = (short)qa.w; h2[3] = (short)(qa.w >> 16);
    h1[4] = (short)qb.x; h2[4] = (short)(qb.x >> 16);
    h1[5] = (short)qb.y; h2[5] = (short)(qb.y >> 16);
    h1[6] = (short)qb.z; h2[6] = (short)(qb.z >> 16);
    h1[7] = (short)qb.w; h2[7] = (short)(qb.w >> 16);
}

// -------------------- W pre-split: [Wr;Wl] -> fragment-major bf16 hi/lo --------------------
__global__ __launch_bounds__(256) void k_wsplit(const float* __restrict__ Wr1, const float* __restrict__ Wl1,
                                                const float* __restrict__ Wr2, const float* __restrict__ Wl2,
                                                const float* __restrict__ Wr3, const float* __restrict__ Wl3,
                                                unsigned short* __restrict__ Wf) {
    int gid = blockIdx.x * 256 + threadIdx.x;   // 0..98303
    int s = gid >> 15;
    int idx = gid & 32767;
    int j = idx & 7, col = (idx >> 3) & 127, ko = idx >> 10;
    int k = ko * 8 + j;
    const float* Wr = (s == 0) ? Wr1 : (s == 1) ? Wr2 : Wr3;
    const float* Wl = (s == 0) ? Wl1 : (s == 1) ? Wl2 : Wl3;
    float f = (k < 128) ? Wr[(size_t)k * 128 + col] : Wl[(size_t)(k - 128) * 128 + col];
    unsigned short h1 = f2bf(f), h2 = f2bf(f - bf2f(h1));
    Wf[(size_t)s * 65536 + idx] = h1;
    Wf[(size_t)s * 65536 + 32768 + idx] = h2;
}

// -------------------- fused stage 1: agg1 + conv-gemm + pool + agg2 (unchanged R16) --------
__global__ __launch_bounds__(1024) void k_stage1(const float* __restrict__ X,
                                                 const int* __restrict__ src,
                                                 const int* __restrict__ dst,
                                                 const float* __restrict__ wp,
                                                 const float* __restrict__ bias,
                                                 const unsigned short* __restrict__ Wf,
                                                 int* __restrict__ cmap,
                                                 float* __restrict__ R,
                                                 unsigned* __restrict__ XF,
                                                 unsigned* __restrict__ AGGF1,
                                                 unsigned* __restrict__ AGGF2) {
    __shared__ __align__(16) char smem[107520];
    __shared__ float sc[256];
    __shared__ unsigned long long keys[256];
    __shared__ int sel[128];
    __shared__ int inv[256];
    __shared__ float wn[128];
    __shared__ float gates[128];
    __shared__ float pmx[8 * 128];
    __shared__ float psm[8 * 128];
    __shared__ int ncm[256];
    __shared__ float snorm_s;

    const int g = blockIdx.x, t = threadIdx.x;
    const int lane = t & 63, wv = t >> 6;
    const int l15 = lane & 15, lko = lane >> 4;

    if (t < 64) {
        float v = wp[t] * wp[t] + wp[t + 64] * wp[t + 64];
        #pragma unroll
        for (int o = 32; o; o >>= 1) v += __shfl_xor(v, o);
        if (t == 0) snorm_s = sqrtf(v);
    }

    // phase A: agg1
    {
        unsigned* adjc = (unsigned*)smem;
        short* adjT = (short*)(smem + 65536);
        short* xsA = (short*)(smem + 81920);
        constexpr int NS = 256, NS4 = 64;
        {
            uint4* z = (uint4*)adjc;
            #pragma unroll
            for (int i = t; i < NS * NS4 / 4; i += 1024) z[i] = uint4{0, 0, 0, 0};
        }
        __syncthreads();
        if (t < 128) wn[t] = wp[t] / snorm_s;

        const int* sg = src + (size_t)g * EPER;
        const int* dg = dst + (size_t)g * EPER;
        #pragma unroll
        for (int j = 0; j < 4; ++j) {
            int e = j * 1024 + t;
            int s = sg[e], d = dg[e];
            int pos = (s + 4 * d) & (NS - 1);
            __hip_atomic_fetch_add(&adjc[d * NS4 + (pos >> 2)], 1u << ((pos & 3) * 8),
                                   __ATOMIC_RELAXED, __HIP_MEMORY_SCOPE_WORKGROUP);
        }

        f32x4 acc[8];
        #pragma unroll
        for (int c = 0; c < 8; ++c) acc[c] = f32x4{0.f, 0.f, 0.f, 0.f};
        const int mA = t >> 2, kgA = (t & 3) * 8;
        const int nX = t & 127, oX = (t >> 7) & 3;

        for (int k0 = 0; k0 < NS; k0 += 32) {
            __syncthreads();
            {
                unsigned short cs[8];
                #pragma unroll
                for (int q = 0; q < 2; ++q) {
                    unsigned w = adjc[mA * NS4 + ((((k0 + kgA) >> 2) + mA + q) & (NS4 - 1))];
                    cs[q * 4 + 0] = f2bf((float)(w & 255u));
                    cs[q * 4 + 1] = f2bf((float)((w >> 8) & 255u));
                    cs[q * 4 + 2] = f2bf((float)((w >> 16) & 255u));
                    cs[q * 4 + 3] = f2bf((float)(w >> 24));
                }
                short8 w8;
                #pragma unroll
                for (int j = 0; j < 8; ++j) w8[j] = (short)cs[j];
                *(short8*)&adjT[(t & 3) * NS * 8 + mA * 8] = w8;
            }
            if (t < 512) {
                short8 h1, h2;
                #pragma unroll
                for (int j = 0; j < 8; ++j) {
                    float f = X[(size_t)g * 32768 + (size_t)(k0 + oX * 8 + j) * F + nX];
                    unsigned short a1 = f2bf(f);
                    unsigned short a2 = f2bf(f - bf2f(a1));
                    h1[j] = (short)a1; h2[j] = (short)a2;
                }
                *(short8*)&xsA[oX * 1024 + nX * 8] = h1;
                *(short8*)&xsA[4096 + oX * 1024 + nX * 8] = h2;
            }
            __syncthreads();
            short8 afr = *(const short8*)&adjT[lko * NS * 8 + (wv * 16 + l15) * 8];
            #pragma unroll
            for (int s = 0; s < 2; ++s) {
                #pragma unroll
                for (int ct = 0; ct < 8; ++ct) {
                    short8 bfr = *(const short8*)&xsA[s * 4096 + lko * 1024 + (ct * 16 + l15) * 8];
                    acc[ct] = __builtin_amdgcn_mfma_f32_16x16x32_bf16(afr, bfr, acc[ct], 0, 0, 0);
                }
            }
        }

        #pragma unroll
        for (int ct = 0; ct < 8; ++ct) {
            int feat = ct * 16 + l15;
            size_t fb = (size_t)(feat >> 3) * 1024 + (feat & 7);
            int r0 = wv * 16 + lko * 4;
            #pragma unroll
            for (int r = 0; r < 4; ++r) {
                int m = g * NS + r0 + r;
                float v = acc[ct][r];
                unsigned short hi = f2bf(v);
                unsigned short lo = f2bf(v - bf2f(hi));
                AGGF1[(size_t)(m >> 7) * TILE_U32 + fb + (size_t)(m & 127) * 8] =
                    (unsigned)hi | ((unsigned)lo << 16);
            }
        }
    }
    __syncthreads();

    // phase B: gemm1
    f32x4 acc2[8];
    {
        uint4* Whi = (uint4*)smem;
        uint4* Afs = (uint4*)(smem + 65536);
        const unsigned short* Wlo = Wf + 32768;
        {
            const uint4* Wf4 = (const uint4*)Wf;
            #pragma unroll
            for (int i = 0; i < 4; ++i) Whi[t + i * 1024] = Wf4[t + i * 1024];
        }
        #pragma unroll
        for (int c = 0; c < 8; ++c) acc2[c] = f32x4{0.f, 0.f, 0.f, 0.f};

        const int rs = t >> 2, ck = t & 3;
        const int rowp = t & 255, kop = t >> 8;

        for (int kt = 0; kt < 8; ++kt) {
            __syncthreads();
            if (kt < 4) {
                const float* srow = X + (size_t)g * 32768 + (size_t)rs * 128 + kt * 32 + ck * 8;
                float4 fa = *(const float4*)srow;
                float4 fb = *(const float4*)(srow + 4);
                float vv[8] = {fa.x, fa.y, fa.z, fa.w, fb.x, fb.y, fb.z, fb.w};
                short8 h1, h2;
                #pragma unroll
                for (int j = 0; j < 8; ++j) {
                    unsigned short a1 = f2bf(vv[j]);
                    unsigned short a2 = f2bf(vv[j] - bf2f(a1));
                    h1[j] = (short)a1; h2[j] = (short)a2;
                }
                int rw = rs ^ (ck << 2);
                *reinterpret_cast<short8*>(&Afs[(0 * 4 + ck) * 256 + rw]) = h1;
                *reinterpret_cast<short8*>(&Afs[(1 * 4 + ck) * 256 + rw]) = h2;
            } else {
                int ko = (kt & 3) * 4 + kop;
                int tile = 2 * g + (rowp >> 7);
                size_t idx = (size_t)tile * TILE_U32 + (size_t)ko * 1024 + (size_t)(rowp & 127) * 8;
                uint4 qa = *(const uint4*)(AGGF1 + idx);
                uint4 qb = *(const uint4*)(AGGF1 + idx + 4);
                short8 h1, h2;
                unpack2(qa, qb, h1, h2);
                int rw = rowp ^ (kop << 2);
                *reinterpret_cast<short8*>(&Afs[(0 * 4 + kop) * 256 + rw]) = h1;
                *reinterpret_cast<short8*>(&Afs[(1 * 4 + kop) * 256 + rw]) = h2;
            }
            __syncthreads();

            int row = (wv * 16 + l15) ^ (lko << 2);
            short8 a1f = *reinterpret_cast<const short8*>(&Afs[(0 * 4 + lko) * 256 + row]);
            short8 a2f = *reinterpret_cast<const short8*>(&Afs[(1 * 4 + lko) * 256 + row]);
            const int kog = kt * 4 + lko;
            #pragma unroll
            for (int ct = 0; ct < 8; ++ct) {
                int col = ct * 16 + l15;
                short8 w1 = *reinterpret_cast<const short8*>(&Whi[kog * 128 + col]);
                short8 w2 = *reinterpret_cast<const short8*>(Wlo + ((size_t)kog * 128 + col) * 8);
                acc2[ct] = __builtin_amdgcn_mfma_f32_16x16x32_bf16(a1f, w1, acc2[ct], 0, 0, 0);
                acc2[ct] = __builtin_amdgcn_mfma_f32_16x16x32_bf16(a2f, w1, acc2[ct], 0, 0, 0);
                acc2[ct] = __builtin_amdgcn_mfma_f32_16x16x32_bf16(a1f, w2, acc2[ct], 0, 0, 0);
            }
        }
    }
    __syncthreads();

    #pragma unroll
    for (int ct = 0; ct < 8; ++ct) {
        float bv = bias[ct * 16 + l15];
        #pragma unroll
        for (int r = 0; r < 4; ++r) acc2[ct][r] = fmaxf(acc2[ct][r] + bv, 0.f);
    }

    // phase C: scores + top-k
    {
        unsigned* adjc2 = (unsigned*)(smem + 66560);
        for (int i = t; i < 4096; i += 1024) adjc2[i] = 0;
        float wnv[8];
        #pragma unroll
        for (int ct = 0; ct < 8; ++ct) wnv[ct] = wn[ct * 16 + l15];
        #pragma unroll
        for (int r = 0; r < 4; ++r) {
            float p = 0.f;
            #pragma unroll
            for (int ct = 0; ct < 8; ++ct) p += acc2[ct][r] * wnv[ct];
            p += __shfl_xor(p, 1); p += __shfl_xor(p, 2);
            p += __shfl_xor(p, 4); p += __shfl_xor(p, 8);
            if (l15 == 0) sc[wv * 16 + lko * 4 + r] = p;
        }
    }
    __syncthreads();

    if (t < 256) {
        unsigned u = __float_as_uint(sc[t]);
        u = (u & 0x80000000u) ? ~u : (u | 0x80000000u);
        keys[t] = ((unsigned long long)u << 32) | (unsigned)(~t);
    }
    __syncthreads();
    for (int kk = 2; kk <= 256; kk <<= 1) {
        for (int j = kk >> 1; j > 0; j >>= 1) {
            if (t < 256) {
                int ixj = t ^ j;
                if (ixj > t) {
                    unsigned long long a = keys[t], b = keys[ixj];
                    bool up = (t & kk) == 0;
                    if (up ? (a < b) : (a > b)) { keys[t] = b; keys[ixj] = a; }
                }
            }
            __syncthreads();
        }
    }
    if (t < 128) sel[t] = (int)(~(unsigned)keys[t]);
    if (t < 256) inv[t] = -1;
    __syncthreads();
    if (t < 128) {
        inv[sel[t]] = t;
        gates[t] = tanhf(sc[sel[t]]);
    }
    __syncthreads();
    if (t < 256) {
        int nc = inv[t];
        ncm[t] = nc;
        cmap[g * 256 + t] = nc;
    }
    __syncthreads();

    // phase D: hp
    {
        unsigned* hp = (unsigned*)smem;
        #pragma unroll
        for (int r = 0; r < 4; ++r) {
            int rowg = wv * 16 + lko * 4 + r;
            int j = inv[rowg];
            if (j >= 0) {
                float gt = gates[j];
                #pragma unroll
                for (int ct = 0; ct < 8; ++ct) {
                    float v = acc2[ct][r] * gt;
                    unsigned short hi = f2bf(v);
                    unsigned short lo = f2bf(v - bf2f(hi));
                    hp[j * 130 + ct * 16 + l15] = (unsigned)hi | ((unsigned)lo << 16);
                }
            }
        }
    }
    __syncthreads();

    // phase E
    {
        unsigned* hp = (unsigned*)smem;
        unsigned* adjc2 = (unsigned*)(smem + 66560);
        short* adjT2 = (short*)(smem + 82944);
        short* xs2 = (short*)(smem + 91136);
        constexpr int K = 128, NS4 = 32;

        {
            const int* sg = src + (size_t)g * EPER;
            const int* dg = dst + (size_t)g * EPER;
            #pragma unroll
            for (int j = 0; j < 4; ++j) {
                int e = j * 1024 + t;
                int s = ncm[sg[e]], d = ncm[dg[e]];
                if (s >= 0 && d >= 0) {
                    int pos = (s + 4 * d) & (K - 1);
                    __hip_atomic_fetch_add(&adjc2[d * NS4 + (pos >> 2)], 1u << ((pos & 3) * 8),
                                           __ATOMIC_RELAXED, __HIP_MEMORY_SCOPE_WORKGROUP);
                }
            }
        }
        {
            const int f = t & 127, seg = t >> 7;
            float mx = -INFINITY, sm = 0.f;
            for (int j = seg; j < K; j += 8) {
                unsigned u = hp[j * 130 + f];
                float v = bf2f((unsigned short)(u & 0xffffu)) + bf2f((unsigned short)(u >> 16));
                mx = fmaxf(mx, v);
                sm += v;
            }
            pmx[seg * 128 + f] = mx;
            psm[seg * 128 + f] = sm;
        }
        for (int i = t; i < K * F; i += 1024) {
            int j = i >> 7, f = i & 127;
            int m = g * K + j;
            XF[(size_t)(m >> 7) * TILE_U32 + (size_t)(f >> 3) * 1024 + (size_t)(m & 127) * 8 + (f & 7)] =
                hp[j * 130 + f];
        }
        __syncthreads();
        if (t < 128) {
            float m = -INFINITY, s = 0.f;
            #pragma unroll
            for (int q = 0; q < 8; ++q) {
                m = fmaxf(m, pmx[q * 128 + t]);
                s += psm[q * 128 + t];
            }
            R[(size_t)g * 768 + t] = m;
            R[(size_t)g * 768 + 128 + t] = s * (1.0f / K);
        }

        const int rt = wv >> 1, cq = wv & 1;
        f32x4 acc3[4];
        #pragma unroll
        for (int c = 0; c < 4; ++c) acc3[c] = f32x4{0.f, 0.f, 0.f, 0.f};

        for (int k0 = 0; k0 < K; k0 += 32) {
            __syncthreads();
            if (t < K * 4) {
                const int m = t >> 2, kg = (t & 3) * 8;
                unsigned short cs[8];
                #pragma unroll
                for (int q = 0; q < 2; ++q) {
                    unsigned w = adjc2[m * NS4 + ((((k0 + kg) >> 2) + m + q) & (NS4 - 1))];
                    cs[q * 4 + 0] = f2bf((float)(w & 255u));
                    cs[q * 4 + 1] = f2bf((float)((w >> 8) & 255u));
                    cs[q * 4 + 2] = f2bf((float)((w >> 16) & 255u));
                    cs[q * 4 + 3] = f2bf((float)(w >> 24));
                }
                short8 w8;
                #pragma unroll
                for (int j = 0; j < 8; ++j) w8[j] = (short)cs[j];
                *(short8*)&adjT2[(t & 3) * K * 8 + m * 8] = w8;
            }
            if (t >= 512) {
                const int feat = t & 127, o = (t >> 7) & 3;
                short8 h1, h2;
                #pragma unroll
                for (int j = 0; j < 8; ++j) {
                    unsigned u = hp[(k0 + o * 8 + j) * 130 + feat];
                    h1[j] = (short)(u & 0xffffu);
                    h2[j] = (short)(u >> 16);
                }
                *(short8*)&xs2[o * 1024 + feat * 8] = h1;
                *(short8*)&xs2[4096 + o * 1024 + feat * 8] = h2;
            }
            __syncthreads();

            short8 afr = *(const short8*)&adjT2[lko * K * 8 + (rt * 16 + l15) * 8];
            #pragma unroll
            for (int s = 0; s < 2; ++s) {
                #pragma unroll
                for (int ct = 0; ct < 4; ++ct) {
                    int feat = cq * 64 + ct * 16 + l15;
                    short8 bfr = *(const short8*)&xs2[s * 4096 + lko * 1024 + feat * 8];
                    acc3[ct] = __builtin_amdgcn_mfma_f32_16x16x32_bf16(afr, bfr, acc3[ct], 0, 0, 0);
                }
            }
        }

        #pragma unroll
        for (int ct = 0; ct < 4; ++ct) {
            int feat = cq * 64 + ct * 16 + l15;
            size_t fb = (size_t)(feat >> 3) * 1024 + (feat & 7);
            int r0 = rt * 16 + lko * 4;
            #pragma unroll
            for (int r = 0; r < 4; ++r) {
                int m = g * K + r0 + r;
                float v = acc3[ct][r];
                unsigned short hi = f2bf(v);
                unsigned short lo = f2bf(v - bf2f(hi));
                AGGF2[(size_t)(m >> 7) * TILE_U32 + fb + (size_t)(m & 127) * 8] =
                    (unsigned)hi | ((unsigned)lo << 16);
            }
        }
    }
}

// -------------------- fused stage 2: gemm2 + pool2 + agg3 (per graph, 1024 thr) ------------
// Reads XF/AGGF2 (tile g), cmap; writes R slice 2, XF2/AGGF3 (tile g>>1, disjoint halves).
__global__ __launch_bounds__(1024) void k_stage2(const int* __restrict__ src,
                                                 const int* __restrict__ dst,
                                                 const float* __restrict__ wp,
                                                 const float* __restrict__ bias,
                                                 const unsigned short* __restrict__ Wf,
                                                 const int* __restrict__ cmap,
                                                 float* __restrict__ R,
                                                 const unsigned* __restrict__ XF,
                                                 const unsigned* __restrict__ AGGF,
                                                 unsigned* __restrict__ XF2,
                                                 unsigned* __restrict__ AGGF3) {
    __shared__ __align__(16) char smem[81920];
    __shared__ float sc[128];
    __shared__ unsigned long long keys[128];
    __shared__ int sel[64];
    __shared__ int inv[128];
    __shared__ float wn[128];
    __shared__ float gates[64];
    __shared__ float scp[2][128];
    __shared__ float pmx[8 * 128];
    __shared__ float psm[8 * 128];
    __shared__ int ncm[256];
    __shared__ float snorm_s;

    const int g = blockIdx.x, t = threadIdx.x;
    const int lane = t & 63, wv = t >> 6;
    const int l15 = lane & 15, lko = lane >> 4;
    const int rt = wv >> 1, cq = wv & 1;   // 8 row-tiles x 2 col-halves

    if (t < 64) {
        float v = wp[t] * wp[t] + wp[t + 64] * wp[t + 64];
        #pragma unroll
        for (int o = 32; o; o >>= 1) v += __shfl_xor(v, o);
        if (t == 0) snorm_s = sqrtf(v);
    }
    __syncthreads();
    if (t < 128) wn[t] = wp[t] / snorm_s;

    // ---- phase B: h2 = relu([X2|AGG2] @ W + b), h2 in regs ----
    f32x4 acc2[4];
    {
        uint4* Whi = (uint4*)smem;                 // 64 KB
        uint4* Afs = (uint4*)(smem + 65536);       // [2][4][128] = 16 KB
        const unsigned short* Wlo = Wf + 32768;
        {
            const uint4* Wf4 = (const uint4*)Wf;
            #pragma unroll
            for (int i = 0; i < 4; ++i) Whi[t + i * 1024] = Wf4[t + i * 1024];
        }
        #pragma unroll
        for (int c = 0; c < 4; ++c) acc2[c] = f32x4{0.f, 0.f, 0.f, 0.f};

        const int rowp = t & 127, kop = (t >> 7) & 3;

        for (int kt = 0; kt < 8; ++kt) {
            __syncthreads();
            if (t < 512) {
                const unsigned* P = (kt < 4) ? XF : AGGF;
                int ko = (kt & 3) * 4 + kop;
                size_t idx = (size_t)g * TILE_U32 + (size_t)ko * 1024 + (size_t)rowp * 8;
                uint4 qa = *(const uint4*)(P + idx);
                uint4 qb = *(const uint4*)(P + idx + 4);
                short8 h1, h2;
                unpack2(qa, qb, h1, h2);
                int rw = rowp ^ (kop << 2);
                *reinterpret_cast<short8*>(&Afs[(0 * 4 + kop) * 128 + rw]) = h1;
                *reinterpret_cast<short8*>(&Afs[(1 * 4 + kop) * 128 + rw]) = h2;
            }
            __syncthreads();

            int row = (rt * 16 + l15) ^ (lko << 2);
            short8 a1f = *reinterpret_cast<const short8*>(&Afs[(0 * 4 + lko) * 128 + row]);
            short8 a2f = *reinterpret_cast<const short8*>(&Afs[(1 * 4 + lko) * 128 + row]);
            const int kog = kt * 4 + lko;
            #pragma unroll
            for (int ct = 0; ct < 4; ++ct) {
                int col = cq * 64 + ct * 16 + l15;
                short8 w1 = *reinterpret_cast<const short8*>(&Whi[kog * 128 + col]);
                short8 w2 = *reinterpret_cast<const short8*>(Wlo + ((size_t)kog * 128 + col) * 8);
                acc2[ct] = __builtin_amdgcn_mfma_f32_16x16x32_bf16(a1f, w1, acc2[ct], 0, 0, 0);
                acc2[ct] = __builtin_amdgcn_mfma_f32_16x16x32_bf16(a2f, w1, acc2[ct], 0, 0, 0);
                acc2[ct] = __builtin_amdgcn_mfma_f32_16x16x32_bf16(a1f, w2, acc2[ct], 0, 0, 0);
            }
        }
    }
    __syncthreads();

    #pragma unroll
    for (int ct = 0; ct < 4; ++ct) {
        float bv = bias[cq * 64 + ct * 16 + l15];
        #pragma unroll
        for (int r = 0; r < 4; ++r) acc2[ct][r] = fmaxf(acc2[ct][r] + bv, 0.f);
    }

    // ---- scores (2-wave combine) ----
    {
        float wnv[4];
        #pragma unroll
        for (int ct = 0; ct < 4; ++ct) wnv[ct] = wn[cq * 64 + ct * 16 + l15];
        #pragma unroll
        for (int r = 0; r < 4; ++r) {
            float p = 0.f;
            #pragma unroll
            for (int ct = 0; ct < 4; ++ct) p += acc2[ct][r] * wnv[ct];
            p += __shfl_xor(p, 1); p += __shfl_xor(p, 2);
            p += __shfl_xor(p, 4); p += __shfl_xor(p, 8);
            if (l15 == 0) scp[cq][rt * 16 + lko * 4 + r] = p;
        }
    }
    // zero adjc3 while Whi region is dead
    {
        unsigned* adjc3 = (unsigned*)(smem + 33280);
        if (t < 1024) adjc3[t] = 0;  // 64*16 = 1024 u32
    }
    __syncthreads();
    if (t < 128) sc[t] = scp[0][t] + scp[1][t];
    __syncthreads();

    if (t < 128) {
        unsigned u = __float_as_uint(sc[t]);
        u = (u & 0x80000000u) ? ~u : (u | 0x80000000u);
        keys[t] = ((unsigned long long)u << 32) | (unsigned)(~t);
    }
    __syncthreads();
    for (int kk = 2; kk <= 128; kk <<= 1) {
        for (int j = kk >> 1; j > 0; j >>= 1) {
            if (t < 128) {
                int ixj = t ^ j;
                if (ixj > t) {
                    unsigned long long a = keys[t], b = keys[ixj];
                    bool up = (t & kk) == 0;
                    if (up ? (a < b) : (a > b)) { keys[t] = b; keys[ixj] = a; }
                }
            }
            __syncthreads();
        }
    }
    if (t < 64) sel[t] = (int)(~(unsigned)keys[t]);
    if (t < 128) inv[t] = -1;
    __syncthreads();
    if (t < 64) {
        inv[sel[t]] = t;
        gates[t] = tanhf(sc[sel[t]]);
    }
    __syncthreads();
    if (t < 256) {
        int c = cmap[g * 256 + t];
        ncm[t] = (c >= 0) ? inv[c] : -1;
    }
    __syncthreads();

    // ---- hp: selected rows, packed u32, stride 130 ----
    {
        unsigned* hp = (unsigned*)smem;  // 64 x 130 u32 = 33280 B
        #pragma unroll
        for (int r = 0; r < 4; ++r) {
            int rowg = rt * 16 + lko * 4 + r;
            int j = inv[rowg];
            if (j >= 0) {
                float gt = gates[j];
                #pragma unroll
                for (int ct = 0; ct < 4; ++ct) {
                    float v = acc2[ct][r] * gt;
                    unsigned short hi = f2bf(v);
                    unsigned short lo = f2bf(v - bf2f(hi));
                    hp[j * 130 + cq * 64 + ct * 16 + l15] = (unsigned)hi | ((unsigned)lo << 16);
                }
            }
        }
    }
    __syncthreads();

    // ---- phase E: edges + readout + XF2 + agg3 -> AGGF3 ----
    {
        unsigned* hp = (unsigned*)smem;
        unsigned* adjc3 = (unsigned*)(smem + 33280);   // 4 KB
        short* adjT3 = (short*)(smem + 37376);         // 4 KB
        short* xs3 = (short*)(smem + 41472);           // 16 KB
        constexpr int K = 64, NS4 = 16;

        {
            const int* sg = src + (size_t)g * EPER;
            const int* dg = dst + (size_t)g * EPER;
            #pragma unroll
            for (int j = 0; j < 4; ++j) {
                int e = j * 1024 + t;
                int s = ncm[sg[e]], d = ncm[dg[e]];
                if (s >= 0 && d >= 0) {
                    int pos = (s + 4 * d) & (K - 1);
                    __hip_atomic_fetch_add(&adjc3[d * NS4 + (pos >> 2)], 1u << ((pos & 3) * 8),
                                           __ATOMIC_RELAXED, __HIP_MEMORY_SCOPE_WORKGROUP);
                }
            }
        }
        {
            const int f = t & 127, seg = t >> 7;
            float mx = -INFINITY, sm = 0.f;
            for (int j = seg; j < K; j += 8) {
                unsigned u = hp[j * 130 + f];
                float v = bf2f((unsigned short)(u & 0xffffu)) + bf2f((unsigned short)(u >> 16));
                mx = fmaxf(mx, v);
                sm += v;
            }
            pmx[seg * 128 + f] = mx;
            psm[seg * 128 + f] = sm;
        }
        for (int i = t; i < K * F; i += 1024) {
            int j = i >> 7, f = i & 127;
            int m = g * K + j;
            XF2[(size_t)(m >> 7) * TILE_U32 + (size_t)(f >> 3) * 1024 + (size_t)(m & 127) * 8 + (f & 7)] =
                hp[j * 130 + f];
        }
        __syncthreads();
        if (t < 128) {
            float m = -INFINITY, s = 0.f;
            #pragma unroll
            for (int q = 0; q < 8; ++q) {
                m = fmaxf(m, pmx[q * 128 + t]);
                s += psm[q * 128 + t];
            }
            R[(size_t)g * 768 + 256 + t] = m;
            R[(size_t)g * 768 + 384 + t] = s * (1.0f / K);
        }

        // agg3: K=64, 2 K-steps; 16 waves: 4 row-tiles x 4 col-quads (CTN=2)
        const int rt3 = wv >> 2, cq3 = wv & 3;
        f32x4 acc3[2];
        acc3[0] = f32x4{0.f, 0.f, 0.f, 0.f};
        acc3[1] = f32x4{0.f, 0.f, 0.f, 0.f};

        for (int k0 = 0; k0 < K; k0 += 32) {
            __syncthreads();
            if (t < K * 4) {
                const int m = t >> 2, kg = (t & 3) * 8;
                unsigned short cs[8];
                #pragma unroll
                for (int q = 0; q < 2; ++q) {
                    unsigned w = adjc3[m * NS4 + ((((k0 + kg) >> 2) + m + q) & (NS4 - 1))];
                    cs[q * 4 + 0] = f2bf((float)(w & 255u));
                    cs[q * 4 + 1] = f2bf((float)((w >> 8) & 255u));
                    cs[q * 4 + 2] = f2bf((float)((w >> 16) & 255u));
                    cs[q * 4 + 3] = f2bf((float)(w >> 24));
                }
                short8 w8;
                #pragma unroll
                for (int j = 0; j < 8; ++j) w8[j] = (short)cs[j];
                *(short8*)&adjT3[(t & 3) * K * 8 + m * 8] = w8;
            }
            if (t >= 512) {
                const int feat = t & 127, o = (t >> 7) & 3;
                short8 h1, h2;
                #pragma unroll
                for (int j = 0; j < 8; ++j) {
                    unsigned u = hp[(k0 + o * 8 + j) * 130 + feat];
                    h1[j] = (short)(u & 0xffffu);
                    h2[j] = (short)(u >> 16);
                }
                *(short8*)&xs3[o * 1024 + feat * 8] = h1;
                *(short8*)&xs3[4096 + o * 1024 + feat * 8] = h2;
            }
            __syncthreads();

            short8 afr = *(const short8*)&adjT3[lko * K * 8 + (rt3 * 16 + l15) * 8];
            #pragma unroll
            for (int s = 0; s < 2; ++s) {
                #pragma unroll
                for (int ct = 0; ct < 2; ++ct) {
                    int feat = cq3 * 32 + ct * 16 + l15;
                    short8 bfr = *(const short8*)&xs3[s * 4096 + lko * 1024 + feat * 8];
                    acc3[ct] = __builtin_amdgcn_mfma_f32_16x16x32_bf16(afr, bfr, acc3[ct], 0, 0, 0);
                }
            }
        }

        #pragma unroll
        for (int ct = 0; ct < 2; ++ct) {
            int feat = cq3 * 32 + ct * 16 + l15;
            size_t fb = (size_t)(feat >> 3) * 1024 + (feat & 7);
            int r0 = rt3 * 16 + lko * 4;
            #pragma unroll
            for (int r = 0; r < 4; ++r) {
                int m = g * K + r0 + r;
                float v = acc3[ct][r];
                unsigned short hi = f2bf(v);
                unsigned short lo = f2bf(v - bf2f(hi));
                AGGF3[(size_t)(m >> 7) * TILE_U32 + fb + (size_t)(m & 127) * 8] =
                    (unsigned)hi | ((unsigned)lo << 16);
            }
        }
    }
}

// -------------------- fused stage 3: gemm3 + pool3 + MLP + log_softmax --------------------
// Reads XF2/AGGF3 (tile g>>1, half (g&1)), R slices 1,2; writes out.
__global__ __launch_bounds__(1024) void k_stage3(const float* __restrict__ wp,
                                                 const float* __restrict__ bias,
                                                 const unsigned short* __restrict__ Wf,
                                                 const float* __restrict__ R,
                                                 const unsigned* __restrict__ XF2,
                                                 const unsigned* __restrict__ AGGF3,
                                                 const float* __restrict__ W1, const float* __restrict__ b1,
                                                 const float* __restrict__ W2, const float* __restrict__ b2,
                                                 const float* __restrict__ W3, const float* __restrict__ b3,
                                                 float* __restrict__ out) {
    __shared__ __align__(16) char smem[73728];   // phaseB: Whi 64K + Afs 8K; later: hp 16.6K
    __shared__ float sc[64];
    __shared__ unsigned long long keys[64];
    __shared__ int sel[32];
    __shared__ int inv[64];
    __shared__ float wn[128];
    __shared__ float gates[32];
    __shared__ float scp[4][64];
    __shared__ float pmx[8 * 128];
    __shared__ float psm[8 * 128];
    __shared__ float z[768];
    __shared__ float part[8][128];
    __shared__ float z2[128];
    __shared__ float z3[64];
    __shared__ float lg[10];
    __shared__ float lse;
    __shared__ float snorm_s;

    const int g = blockIdx.x, t = threadIdx.x;
    const int lane = t & 63, wv = t >> 6;
    const int l15 = lane & 15, lko = lane >> 4;
    const int rt = wv >> 2, cq = wv & 3;   // 4 row-tiles (64 rows) x 4 col-quads (32 cols, CTN=2)

    if (t < 64) {
        float v = wp[t] * wp[t] + wp[t + 64] * wp[t + 64];
        #pragma unroll
        for (int o = 32; o; o >>= 1) v += __shfl_xor(v, o);
        if (t == 0) snorm_s = sqrtf(v);
    }
    __syncthreads();
    if (t < 128) wn[t] = wp[t] / snorm_s;
    if (t < 512) z[t] = R[(size_t)g * 768 + t];  // slices 1,2

    // ---- phase B: h3 = relu([X3|AGG3] @ W + b), in regs ----
    f32x4 acc2[2];
    {
        uint4* Whi = (uint4*)smem;                 // 64 KB
        uint4* Afs = (uint4*)(smem + 65536);       // [2][4][64] = 8 KB
        const unsigned short* Wlo = Wf + 32768;
        {
            const uint4* Wf4 = (const uint4*)Wf;
            #pragma unroll
            for (int i = 0; i < 4; ++i) Whi[t + i * 1024] = Wf4[t + i * 1024];
        }
        acc2[0] = f32x4{0.f, 0.f, 0.f, 0.f};
        acc2[1] = f32x4{0.f, 0.f, 0.f, 0.f};

        const int rowp = t & 63, kop = (t >> 6) & 3;

        for (int kt = 0; kt < 8; ++kt) {
            __syncthreads();
            if (t < 256) {
                const unsigned* P = (kt < 4) ? XF2 : AGGF3;
                int ko = (kt & 3) * 4 + kop;
                size_t idx = (size_t)(g >> 1) * TILE_U32 + (size_t)ko * 1024
                           + (size_t)((g & 1) * 64 + rowp) * 8;
                uint4 qa = *(const uint4*)(P + idx);
                uint4 qb = *(const uint4*)(P + idx + 4);
                short8 h1, h2;
                unpack2(qa, qb, h1, h2);
                int rw = rowp ^ (kop << 2);
                *reinterpret_cast<short8*>(&Afs[(0 * 4 + kop) * 64 + rw]) = h1;
                *reinterpret_cast<short8*>(&Afs[(1 * 4 + kop) * 64 + rw]) = h2;
            }
            __syncthreads();

            int row = (rt * 16 + l15) ^ (lko << 2);
            short8 a1f = *reinterpret_cast<const short8*>(&Afs[(0 * 4 + lko) * 64 + row]);
            short8 a2f = *reinterpret_cast<const short8*>(&Afs[(1 * 4 + lko) * 64 + row]);
            const int kog = kt * 4 + lko;
            #pragma unroll
            for (int ct = 0; ct < 2; ++ct) {
                int col = cq * 32 + ct * 16 + l15;
                short8 w1 = *reinterpret_cast<const short8*>(&Whi[kog * 128 + col]);
                short8 w2 = *reinterpret_cast<const short8*>(Wlo + ((size_t)kog * 128 + col) * 8);
                acc2[ct] = __builtin_amdgcn_mfma_f32_16x16x32_bf16(a1f, w1, acc2[ct], 0, 0, 0);
                acc2[ct] = __builtin_amdgcn_mfma_f32_16x16x32_bf16(a2f, w1, acc2[ct], 0, 0, 0);
                acc2[ct] = __builtin_amdgcn_mfma_f32_16x16x32_bf16(a1f, w2, acc2[ct], 0, 0, 0);
            }
        }
    }
    __syncthreads();

    #pragma unroll
    for (int ct = 0; ct < 2; ++ct) {
        float bv = bias[cq * 32 + ct * 16 + l15];
        #pragma unroll
        for (int r = 0; r < 4; ++r) acc2[ct][r] = fmaxf(acc2[ct][r] + bv, 0.f);
    }

    // ---- scores (4-wave combine) ----
    {
        float wnv[2];
        wnv[0] = wn[cq * 32 + l15];
        wnv[1] = wn[cq * 32 + 16 + l15];
        #pragma unroll
        for (int r = 0; r < 4; ++r) {
            float p = acc2[0][r] * wnv[0] + acc2[1][r] * wnv[1];
            p += __shfl_xor(p, 1); p += __shfl_xor(p, 2);
            p += __shfl_xor(p, 4); p += __shfl_xor(p, 8);
            if (l15 == 0) scp[cq][rt * 16 + lko * 4 + r] = p;
        }
    }
    __syncthreads();
    if (t < 64) sc[t] = scp[0][t] + scp[1][t] + scp[2][t] + scp[3][t];
    __syncthreads();

    if (t < 64) {
        unsigned u = __float_as_uint(sc[t]);
        u = (u & 0x80000000u) ? ~u : (u | 0x80000000u);
        keys[t] = ((unsigned long long)u << 32) | (unsigned)(~t);
    }
    __syncthreads();
    for (int kk = 2; kk <= 64; kk <<= 1) {
        for (int j = kk >> 1; j > 0; j >>= 1) {
            if (t < 64) {
                int ixj = t ^ j;
                if (ixj > t) {
                    unsigned long long a = keys[t], b = keys[ixj];
                    bool up = (t & kk) == 0;
                    if (up ? (a < b) : (a > b)) { keys[t] = b; keys[ixj] = a; }
                }
            }
            __syncthreads();
        }
    }
    if (t < 32) sel[t] = (int)(~(unsigned)keys[t]);
    if (t < 64) inv[t] = -1;
    __syncthreads();
    if (t < 32) {
        inv[sel[t]] = t;
        gates[t] = tanhf(sc[sel[t]]);
    }
    __syncthreads();

    // ---- hp: selected 32 rows, packed ----
    {
        unsigned* hp = (unsigned*)smem;  // 32 x 130 u32 = 16640 B
        #pragma unroll
        for (int r = 0; r < 4; ++r) {
            int rowg = rt * 16 + lko * 4 + r;
            int j = inv[rowg];
            if (j >= 0) {
                float gt = gates[j];
                #pragma unroll
                for (int ct = 0; ct < 2; ++ct) {
                    float v = acc2[ct][r] * gt;
                    unsigned short hi = f2bf(v);
                    unsigned short lo = f2bf(v - bf2f(hi));
                    hp[j * 130 + cq * 32 + ct * 16 + l15] = (unsigned)hi | ((unsigned)lo << 16);
                }
            }
        }
    }
    __syncthreads();

    // ---- readout -> z[512..767] ----
    {
        unsigned* hp = (unsigned*)smem;
        const int f = t & 127, seg = t >> 7;
        float mx = -INFINITY, sm = 0.f;
        for (int j = seg; j < 32; j += 8) {
            unsigned u = hp[j * 130 + f];
            float v = bf2f((unsigned short)(u & 0xffffu)) + bf2f((unsigned short)(u >> 16));
            mx = fmaxf(mx, v);
            sm += v;
        }
        pmx[seg * 128 + f] = mx;
        psm[seg * 128 + f] = sm;
    }
    __syncthreads();
    if (t < 128) {
        float m = -INFINITY, s = 0.f;
        #pragma unroll
        for (int q = 0; q < 8; ++q) {
            m = fmaxf(m, pmx[q * 128 + t]);
            s += psm[q * 128 + t];
        }
        z[512 + t] = m;
        z[640 + t] = s * (1.0f / 32);
    }
    __syncthreads();

    // ---- MLP + log_softmax ----
    {
        const int f = t & 127, seg = t >> 7;
        float acc = 0.f;
        const float* w = W1 + (size_t)(seg * 96) * 128 + f;
        const float* zz = z + seg * 96;
        #pragma unroll 8
        for (int k = 0; k < 96; ++k) acc = fmaf(zz[k], w[(size_t)k * 128], acc);
        part[seg][f] = acc;
    }
    __syncthreads();
    if (t < 128) {
        float a = b1[t];
        #pragma unroll
        for (int q = 0; q < 8; ++q) a += part[q][t];
        z2[t] = fmaxf(a, 0.f);
    }
    __syncthreads();
    if (t < 512) {
        const int f = t & 63, seg = t >> 6;
        float acc = 0.f;
        const float* w = W2 + (size_t)(seg * 16) * 64 + f;
        const float* zz = z2 + seg * 16;
        #pragma unroll
        for (int k = 0; k < 16; ++k) acc = fmaf(zz[k], w[(size_t)k * 64], acc);
        part[seg][f] = acc;
    }
    __syncthreads();
    if (t < 64) {
        float a = b2[t];
        #pragma unroll
        for (int q = 0; q < 8; ++q) a += part[q][t];
        z3[t] = fmaxf(a, 0.f);
    }
    __syncthreads();
    if (t < 10) {
        float a3 = b3[t];
        #pragma unroll 8
        for (int k = 0; k < 64; ++k) a3 = fmaf(z3[k], W3[(size_t)k * 10 + t], a3);
        lg[t] = a3;
    }
    __syncthreads();
    if (t == 0) {
        float m = lg[0];
        for (int c = 1; c < 10; ++c) m = fmaxf(m, lg[c]);
        float s = 0.f;
        for (int c = 0; c < 10; ++c) s += expf(lg[c] - m);
        lse = m + logf(s);
    }
    __syncthreads();
    if (t < 10) out[(size_t)g * 10 + t] = lg[t] - lse;
}

extern "C" void kernel_launch(void* const* d_in, const int* in_sizes, int n_in,
                              void* d_out, int out_size, void* d_ws, size_t ws_size,
                              hipStream_t stream) {
    (void)in_sizes; (void)n_in; (void)out_size; (void)ws_size;
    const float* x    = (const float*)d_in[0];
    const int*   src  = (const int*)d_in[1];
    const int*   dst  = (const int*)d_in[2];
    const float* Wr1  = (const float*)d_in[3];
    const float* Wrel1= (const float*)d_in[4];
    const float* b1   = (const float*)d_in[5];
    const float* wp1  = (const float*)d_in[6];
    const float* Wr2  = (const float*)d_in[7];
    const float* Wrel2= (const float*)d_in[8];
    const float* b2   = (const float*)d_in[9];
    const float* wp2  = (const float*)d_in[10];
    const float* Wr3  = (const float*)d_in[11];
    const float* Wrel3= (const float*)d_in[12];
    const float* b3   = (const float*)d_in[13];
    const float* wp3  = (const float*)d_in[14];
    const float* L1w  = (const float*)d_in[15];
    const float* L1b  = (const float*)d_in[16];
    const float* L2w  = (const float*)d_in[17];
    const float* L2b  = (const float*)d_in[18];
    const float* L3w  = (const float*)d_in[19];
    const float* L3b  = (const float*)d_in[20];

    int*      cmap  = (int*)d_ws;                                  // G*256 i32
    float*    R     = (float*)(cmap + (size_t)G * 256);            // G*768 f32
    unsigned* AGGF1 = (unsigned*)(R + (size_t)G * 768);            // G*2 tiles
    unsigned* AGGF2 = AGGF1 + (size_t)G * 2 * TILE_U32;            // G tiles
    unsigned* XF    = AGGF2 + (size_t)G * TILE_U32;                // G tiles
    unsigned* XF2   = XF + (size_t)G * TILE_U32;                   // G/2 tiles
    unsigned* AGGF3 = XF2 + (size_t)(G / 2) * TILE_U32;            // G/2 tiles
    unsigned short* Wf = (unsigned short*)(AGGF3 + (size_t)(G / 2) * TILE_U32);
    float* out = (float*)d_out;

    k_wsplit<<<384, 256, 0, stream>>>(Wr1, Wrel1, Wr2, Wrel2, Wr3, Wrel3, Wf);

    k_stage1<<<G, 1024, 0, stream>>>(x, src, dst, wp1, b1, Wf, cmap, R, XF, AGGF1, AGGF2);
    k_stage2<<<G, 1024, 0, stream>>>(src, dst, wp2, b2, Wf + 65536, cmap, R, XF, AGGF2, XF2, AGGF3);
    k_stage3<<<G, 1024, 0, stream>>>(wp3, b3, Wf + 131072, R, XF2, AGGF3,
                                     L1w, L1b, L2w, L2b, L3w, L3b, out);
}

// Round 19
// 112.767 us; speedup vs baseline: 1.4128x; 1.0496x over previous
//
#include <hip/hip_runtime.h>
#include <cstdint>
#include <cstddef>

#define G 256
#define EPER 4096
#define F 128
#define TILE_U32 16384  // fragment tile: 16 ko * 128 row * 8 j (u32 each)

typedef __attribute__((ext_vector_type(8))) short short8;
typedef __attribute__((ext_vector_type(4))) short s16x4;
typedef __attribute__((ext_vector_type(4))) float f32x4;

__device__ inline unsigned short f2bf(float f) {
    unsigned u = __float_as_uint(f);
    u += 0x7FFFu + ((u >> 16) & 1u);
    return (unsigned short)(u >> 16);
}
__device__ inline float bf2f(unsigned short b) { return __uint_as_float(((unsigned)b) << 16); }

__device__ inline void unpack2(uint4 qa, uint4 qb, short8& h1, short8& h2) {
    h1[0] = (short)qa.x; h2[0] = (short)(qa.x >> 16);
    h1[1] = (short)qa.y; h2[1] = (short)(qa.y >> 16);
    h1[2] = (short)qa.z; h2[2] = (short)(qa.z >> 16);
    h1[3] = (short)qa.w; h2[3] = (short)(qa.w >> 16);
    h1[4] = (short)qb.x; h2[4] = (short)(qb.x >> 16);
    h1[5] = (short)qb.y; h2[5] = (short)(qb.y >> 16);
    h1[6] = (short)qb.z; h2[6] = (short)(qb.z >> 16);
    h1[7] = (short)qb.w; h2[7] = (short)(qb.w >> 16);
}

// exact bf16 of small non-negative int (count <= 255 fits bf16 exactly)
__device__ inline short u8bf(unsigned byte) {
    return (short)(__float_as_uint((float)byte) >> 16);
}

// -------------------- W pre-split: [Wr;Wl] -> fragment-major bf16 hi/lo --------------------
__global__ __launch_bounds__(256) void k_wsplit(const float* __restrict__ Wr1, const float* __restrict__ Wl1,
                                                const float* __restrict__ Wr2, const float* __restrict__ Wl2,
                                                const float* __restrict__ Wr3, const float* __restrict__ Wl3,
                                                unsigned short* __restrict__ Wf) {
    int gid = blockIdx.x * 256 + threadIdx.x;   // 0..98303
    int s = gid >> 15;
    int idx = gid & 32767;
    int j = idx & 7, col = (idx >> 3) & 127, ko = idx >> 10;
    int k = ko * 8 + j;
    const float* Wr = (s == 0) ? Wr1 : (s == 1) ? Wr2 : Wr3;
    const float* Wl = (s == 0) ? Wl1 : (s == 1) ? Wl2 : Wl3;
    float f = (k < 128) ? Wr[(size_t)k * 128 + col] : Wl[(size_t)(k - 128) * 128 + col];
    unsigned short h1 = f2bf(f), h2 = f2bf(f - bf2f(h1));
    Wf[(size_t)s * 65536 + idx] = h1;
    Wf[(size_t)s * 65536 + 32768 + idx] = h2;
}

// -------------------- fused stage 1: agg1 + conv-gemm + pool + agg2 --------------------
// Agg result stays in registers through the gemm (no AGGF1 global round-trip).
// Phase A: adjc-direct A-frags (no adjT), xsA double-buffered + async-split staging.
// Phase B: unified packed-u32 staging tile AGP[row][36] (pad kills bank conflicts),
// double-buffered; kt<4 sourced from X (loads issued pre-MFMA), kt>=4 from acc regs.
__global__ __launch_bounds__(1024) void k_stage1(const float* __restrict__ X,
                                                 const int* __restrict__ src,
                                                 const int* __restrict__ dst,
                                                 const float* __restrict__ wp,
                                                 const float* __restrict__ bias,
                                                 const unsigned short* __restrict__ Wf,
                                                 int* __restrict__ cmap,
                                                 float* __restrict__ R,
                                                 unsigned* __restrict__ XF,
                                                 unsigned* __restrict__ AGGF2) {
    __shared__ __align__(16) char smem[147456];
    __shared__ float sc[256];
    __shared__ unsigned long long keys[256];
    __shared__ int sel[128];
    __shared__ int inv[256];
    __shared__ float wn[128];
    __shared__ float gates[128];
    __shared__ float pmx[8 * 128];
    __shared__ float psm[8 * 128];
    __shared__ int ncm[256];
    __shared__ float snorm_s;

    const int g = blockIdx.x, t = threadIdx.x;
    const int lane = t & 63, wv = t >> 6;
    const int l15 = lane & 15, lko = lane >> 4;

    if (t < 64) {
        float v = wp[t] * wp[t] + wp[t + 64] * wp[t + 64];
        #pragma unroll
        for (int o = 32; o; o >>= 1) v += __shfl_xor(v, o);
        if (t == 0) snorm_s = sqrtf(v);
    }

    f32x4 acc[8];  // agg1 result, lives through phase B

    // ================= phase A: agg1 = Adj @ x (result -> regs) =================
    {
        unsigned* adjc = (unsigned*)smem;            // 64 KB (u8 counts, rotation 8m)
        short* xsA = (short*)(smem + 65536);         // dbuf 2 x 16 KB
        {
            uint4* z = (uint4*)adjc;
            #pragma unroll
            for (int i = t; i < 4096; i += 1024) z[i] = uint4{0, 0, 0, 0};
        }
        __syncthreads();
        if (t < 128) wn[t] = wp[t] / snorm_s;

        const int* sg = src + (size_t)g * EPER;
        const int* dg = dst + (size_t)g * EPER;
        #pragma unroll
        for (int j = 0; j < 4; ++j) {
            int e = j * 1024 + t;
            int s = sg[e], d = dg[e];
            int pos = (s + 8 * d) & 255;
            __hip_atomic_fetch_add(&adjc[d * 64 + (pos >> 2)], 1u << ((pos & 3) * 8),
                                   __ATOMIC_RELAXED, __HIP_MEMORY_SCOPE_WORKGROUP);
        }

        #pragma unroll
        for (int c = 0; c < 8; ++c) acc[c] = f32x4{0.f, 0.f, 0.f, 0.f};

        const float* Xg = X + (size_t)g * 32768;
        const int feat = t & 127, ko2 = (t >> 7) & 3, jh = t >> 9;
        const int stoff = ko2 * 1024 + feat * 8 + jh * 4;

        // prologue: stage step 0 into buf 0
        {
            float v[4];
            #pragma unroll
            for (int i = 0; i < 4; ++i)
                v[i] = Xg[(size_t)(ko2 * 8 + jh * 4 + i) * F + feat];
            s16x4 h1, h2;
            #pragma unroll
            for (int i = 0; i < 4; ++i) {
                unsigned short a1 = f2bf(v[i]);
                unsigned short a2 = f2bf(v[i] - bf2f(a1));
                h1[i] = (short)a1; h2[i] = (short)a2;
            }
            *(s16x4*)&xsA[stoff] = h1;
            *(s16x4*)&xsA[4096 + stoff] = h2;
        }
        __syncthreads();

        for (int kt = 0; kt < 8; ++kt) {
            const int b = kt & 1;
            float v[4];
            if (kt < 7) {
                int k0n = (kt + 1) * 32;
                #pragma unroll
                for (int i = 0; i < 4; ++i)
                    v[i] = Xg[(size_t)(k0n + ko2 * 8 + jh * 4 + i) * F + feat];
            }
            // A-frag direct from adjc (static; no barrier needed)
            {
                int m = wv * 16 + l15;
                int pos = ((kt * 32 + lko * 8) + 8 * m) & 255;
                unsigned w0 = adjc[m * 64 + (pos >> 2)];
                unsigned w1 = adjc[m * 64 + (pos >> 2) + 1];
                short8 afr;
                afr[0] = u8bf(w0 & 255u);
                afr[1] = u8bf((w0 >> 8) & 255u);
                afr[2] = u8bf((w0 >> 16) & 255u);
                afr[3] = u8bf(w0 >> 24);
                afr[4] = u8bf(w1 & 255u);
                afr[5] = u8bf((w1 >> 8) & 255u);
                afr[6] = u8bf((w1 >> 16) & 255u);
                afr[7] = u8bf(w1 >> 24);
                const short* xb = xsA + b * 8192;
                #pragma unroll
                for (int s = 0; s < 2; ++s) {
                    #pragma unroll
                    for (int ct = 0; ct < 8; ++ct) {
                        short8 bfr = *(const short8*)&xb[s * 4096 + lko * 1024 + (ct * 16 + l15) * 8];
                        acc[ct] = __builtin_amdgcn_mfma_f32_16x16x32_bf16(afr, bfr, acc[ct], 0, 0, 0);
                    }
                }
            }
            // write next-step staging (loads already in flight)
            if (kt < 7) {
                s16x4 h1, h2;
                #pragma unroll
                for (int i = 0; i < 4; ++i) {
                    unsigned short a1 = f2bf(v[i]);
                    unsigned short a2 = f2bf(v[i] - bf2f(a1));
                    h1[i] = (short)a1; h2[i] = (short)a2;
                }
                short* xo = xsA + (b ^ 1) * 8192;
                *(s16x4*)&xo[stoff] = h1;
                *(s16x4*)&xo[4096 + stoff] = h2;
            }
            __syncthreads();
        }
    }

    // ================= phase B: h = relu([X|AGG] @ [Wr;Wl] + b), in regs =================
    f32x4 acc2[8];
    {
        uint4* Whi = (uint4*)smem;                    // 64 KB
        unsigned* AGP = (unsigned*)(smem + 65536);    // dbuf 2 x (256*36) u32 = 72 KB
        const unsigned short* Wlo = Wf + 32768;
        {
            const uint4* Wf4 = (const uint4*)Wf;
            #pragma unroll
            for (int i = 0; i < 4; ++i) Whi[t + i * 1024] = Wf4[t + i * 1024];
        }
        #pragma unroll
        for (int c = 0; c < 8; ++c) acc2[c] = f32x4{0.f, 0.f, 0.f, 0.f};

        const int rs = t >> 2, ck = t & 3;
        const float* Xg = X + (size_t)g * 32768;

        // prologue: stage kt=0 (X) into AGP[0]
        {
            const float* srow = Xg + (size_t)rs * F + ck * 8;
            float4 fa = *(const float4*)srow;
            float4 fb = *(const float4*)(srow + 4);
            float vv[8] = {fa.x, fa.y, fa.z, fa.w, fb.x, fb.y, fb.z, fb.w};
            unsigned q[8];
            #pragma unroll
            for (int j = 0; j < 8; ++j) {
                unsigned short hi = f2bf(vv[j]);
                unsigned short lo = f2bf(vv[j] - bf2f(hi));
                q[j] = (unsigned)hi | ((unsigned)lo << 16);
            }
            unsigned* d0 = AGP + rs * 36 + ck * 8;
            *(uint4*)d0 = uint4{q[0], q[1], q[2], q[3]};
            *(uint4*)(d0 + 4) = uint4{q[4], q[5], q[6], q[7]};
        }
        __syncthreads();  // covers Whi copy + AGP[0]

        for (int kt = 0; kt < 8; ++kt) {
            const int b = kt & 1;
            float4 fa, fb;
            if (kt < 3) {
                const float* srow = Xg + (size_t)rs * F + (kt + 1) * 32 + ck * 8;
                fa = *(const float4*)srow;
                fb = *(const float4*)(srow + 4);
            }
            // MFMA on AGP[b]
            {
                int row = wv * 16 + l15;
                const unsigned* ag = AGP + b * 9216 + row * 36 + lko * 8;
                uint4 qa = *(const uint4*)ag;
                uint4 qb = *(const uint4*)(ag + 4);
                short8 a1f, a2f;
                unpack2(qa, qb, a1f, a2f);
                const int kog = kt * 4 + lko;
                #pragma unroll
                for (int ct = 0; ct < 8; ++ct) {
                    int col = ct * 16 + l15;
                    short8 w1 = *(const short8*)&Whi[kog * 128 + col];
                    short8 w2 = *(const short8*)(Wlo + ((size_t)kog * 128 + col) * 8);
                    acc2[ct] = __builtin_amdgcn_mfma_f32_16x16x32_bf16(a1f, w1, acc2[ct], 0, 0, 0);
                    acc2[ct] = __builtin_amdgcn_mfma_f32_16x16x32_bf16(a2f, w1, acc2[ct], 0, 0, 0);
                    acc2[ct] = __builtin_amdgcn_mfma_f32_16x16x32_bf16(a1f, w2, acc2[ct], 0, 0, 0);
                }
            }
            // stage next step into AGP[b^1]
            if (kt < 7) {
                unsigned* dstb = AGP + (b ^ 1) * 9216;
                if (kt < 3) {
                    float vv[8] = {fa.x, fa.y, fa.z, fa.w, fb.x, fb.y, fb.z, fb.w};
                    unsigned q[8];
                    #pragma unroll
                    for (int j = 0; j < 8; ++j) {
                        unsigned short hi = f2bf(vv[j]);
                        unsigned short lo = f2bf(vv[j] - bf2f(hi));
                        q[j] = (unsigned)hi | ((unsigned)lo << 16);
                    }
                    unsigned* d0 = dstb + rs * 36 + ck * 8;
                    *(uint4*)d0 = uint4{q[0], q[1], q[2], q[3]};
                    *(uint4*)(d0 + 4) = uint4{q[4], q[5], q[6], q[7]};
                } else {
                    // from agg regs: next window feats f0=(kt-3)*32, thread owns l={l15,16+l15}
                    int ct0 = (kt - 3) * 2;
                    #pragma unroll
                    for (int r = 0; r < 4; ++r) {
                        int rowo = wv * 16 + lko * 4 + r;
                        #pragma unroll
                        for (int h = 0; h < 2; ++h) {
                            float vv = acc[ct0 + h][r];
                            unsigned short hi = f2bf(vv);
                            unsigned short lo = f2bf(vv - bf2f(hi));
                            dstb[rowo * 36 + h * 16 + l15] = (unsigned)hi | ((unsigned)lo << 16);
                        }
                    }
                }
            }
            __syncthreads();
        }
    }

    // bias + relu fold (h in acc2; row = wv*16 + lko*4 + r, col = ct*16 + l15)
    #pragma unroll
    for (int ct = 0; ct < 8; ++ct) {
        float bv = bias[ct * 16 + l15];
        #pragma unroll
        for (int r = 0; r < 4; ++r) acc2[ct][r] = fmaxf(acc2[ct][r] + bv, 0.f);
    }

    // ================= phase C: scores + top-k =================
    {
        unsigned* adjc2 = (unsigned*)(smem + 66560);
        for (int i = t; i < 4096; i += 1024) adjc2[i] = 0;  // zero 16 KB for agg2
        float wnv[8];
        #pragma unroll
        for (int ct = 0; ct < 8; ++ct) wnv[ct] = wn[ct * 16 + l15];
        #pragma unroll
        for (int r = 0; r < 4; ++r) {
            float p = 0.f;
            #pragma unroll
            for (int ct = 0; ct < 8; ++ct) p += acc2[ct][r] * wnv[ct];
            p += __shfl_xor(p, 1); p += __shfl_xor(p, 2);
            p += __shfl_xor(p, 4); p += __shfl_xor(p, 8);
            if (l15 == 0) sc[wv * 16 + lko * 4 + r] = p;
        }
    }
    __syncthreads();

    if (t < 256) {
        unsigned u = __float_as_uint(sc[t]);
        u = (u & 0x80000000u) ? ~u : (u | 0x80000000u);
        keys[t] = ((unsigned long long)u << 32) | (unsigned)(~t);
    }
    __syncthreads();
    for (int kk = 2; kk <= 256; kk <<= 1) {
        for (int j = kk >> 1; j > 0; j >>= 1) {
            if (t < 256) {
                int ixj = t ^ j;
                if (ixj > t) {
                    unsigned long long a = keys[t], b = keys[ixj];
                    bool up = (t & kk) == 0;
                    if (up ? (a < b) : (a > b)) { keys[t] = b; keys[ixj] = a; }
                }
            }
            __syncthreads();
        }
    }
    if (t < 128) sel[t] = (int)(~(unsigned)keys[t]);
    if (t < 256) inv[t] = -1;
    __syncthreads();
    if (t < 128) {
        inv[sel[t]] = t;
        gates[t] = tanhf(sc[sel[t]]);
    }
    __syncthreads();
    if (t < 256) {
        int nc = inv[t];  // STAGE 1: composed map = inv
        ncm[t] = nc;
        cmap[g * 256 + t] = nc;
    }
    __syncthreads();

    // ================= phase D: write selected rows to hp (packed u32, pad 130) ==========
    {
        unsigned* hp = (unsigned*)smem;  // 128 x 130 u32 = 66560 B
        #pragma unroll
        for (int r = 0; r < 4; ++r) {
            int rowg = wv * 16 + lko * 4 + r;
            int j = inv[rowg];
            if (j >= 0) {
                float gt = gates[j];
                #pragma unroll
                for (int ct = 0; ct < 8; ++ct) {
                    float v = acc2[ct][r] * gt;
                    unsigned short hi = f2bf(v);
                    unsigned short lo = f2bf(v - bf2f(hi));
                    hp[j * 130 + ct * 16 + l15] = (unsigned)hi | ((unsigned)lo << 16);
                }
            }
        }
    }
    __syncthreads();

    // ================= phase E: edge-build + readout + XF + agg2 -> AGGF2 ================
    {
        unsigned* hp = (unsigned*)smem;
        unsigned* adjc2 = (unsigned*)(smem + 66560);   // 16 KB
        short* adjT2 = (short*)(smem + 82944);         // 8 KB
        short* xs2 = (short*)(smem + 91136);           // 2 x 8 KB
        constexpr int K = 128, NS4 = 32;

        {
            const int* sg = src + (size_t)g * EPER;
            const int* dg = dst + (size_t)g * EPER;
            #pragma unroll
            for (int j = 0; j < 4; ++j) {
                int e = j * 1024 + t;
                int s = ncm[sg[e]], d = ncm[dg[e]];
                if (s >= 0 && d >= 0) {
                    int pos = (s + 4 * d) & (K - 1);
                    __hip_atomic_fetch_add(&adjc2[d * NS4 + (pos >> 2)], 1u << ((pos & 3) * 8),
                                           __ATOMIC_RELAXED, __HIP_MEMORY_SCOPE_WORKGROUP);
                }
            }
        }
        {
            const int f = t & 127, seg = t >> 7;
            float mx = -INFINITY, sm = 0.f;
            for (int j = seg; j < K; j += 8) {
                unsigned u = hp[j * 130 + f];
                float v = bf2f((unsigned short)(u & 0xffffu)) + bf2f((unsigned short)(u >> 16));
                mx = fmaxf(mx, v);
                sm += v;
            }
            pmx[seg * 128 + f] = mx;
            psm[seg * 128 + f] = sm;
        }
        for (int i = t; i < K * F; i += 1024) {
            int j = i >> 7, f = i & 127;
            int m = g * K + j;
            XF[(size_t)(m >> 7) * TILE_U32 + (size_t)(f >> 3) * 1024 + (size_t)(m & 127) * 8 + (f & 7)] =
                hp[j * 130 + f];
        }
        __syncthreads();
        if (t < 128) {
            float m = -INFINITY, s = 0.f;
            #pragma unroll
            for (int q = 0; q < 8; ++q) {
                m = fmaxf(m, pmx[q * 128 + t]);
                s += psm[q * 128 + t];
            }
            R[(size_t)g * 768 + t] = m;
            R[(size_t)g * 768 + 128 + t] = s * (1.0f / K);
        }

        const int rt = wv >> 1, cq = wv & 1;
        f32x4 acc3[4];
        #pragma unroll
        for (int c = 0; c < 4; ++c) acc3[c] = f32x4{0.f, 0.f, 0.f, 0.f};

        for (int k0 = 0; k0 < K; k0 += 32) {
            __syncthreads();
            if (t < K * 4) {
                const int m = t >> 2, kg = (t & 3) * 8;
                unsigned short cs[8];
                #pragma unroll
                for (int q = 0; q < 2; ++q) {
                    unsigned w = adjc2[m * NS4 + ((((k0 + kg) >> 2) + m + q) & (NS4 - 1))];
                    cs[q * 4 + 0] = f2bf((float)(w & 255u));
                    cs[q * 4 + 1] = f2bf((float)((w >> 8) & 255u));
                    cs[q * 4 + 2] = f2bf((float)((w >> 16) & 255u));
                    cs[q * 4 + 3] = f2bf((float)(w >> 24));
                }
                short8 w8;
                #pragma unroll
                for (int j = 0; j < 8; ++j) w8[j] = (short)cs[j];
                *(short8*)&adjT2[(t & 3) * K * 8 + m * 8] = w8;
            }
            if (t >= 512) {
                const int feat = t & 127, o = (t >> 7) & 3;
                short8 h1, h2;
                #pragma unroll
                for (int j = 0; j < 8; ++j) {
                    unsigned u = hp[(k0 + o * 8 + j) * 130 + feat];
                    h1[j] = (short)(u & 0xffffu);
                    h2[j] = (short)(u >> 16);
                }
                *(short8*)&xs2[o * 1024 + feat * 8] = h1;
                *(short8*)&xs2[4096 + o * 1024 + feat * 8] = h2;
            }
            __syncthreads();

            short8 afr = *(const short8*)&adjT2[lko * K * 8 + (rt * 16 + l15) * 8];
            #pragma unroll
            for (int s = 0; s < 2; ++s) {
                #pragma unroll
                for (int ct = 0; ct < 4; ++ct) {
                    int feat = cq * 64 + ct * 16 + l15;
                    short8 bfr = *(const short8*)&xs2[s * 4096 + lko * 1024 + feat * 8];
                    acc3[ct] = __builtin_amdgcn_mfma_f32_16x16x32_bf16(afr, bfr, acc3[ct], 0, 0, 0);
                }
            }
        }

        #pragma unroll
        for (int ct = 0; ct < 4; ++ct) {
            int feat = cq * 64 + ct * 16 + l15;
            size_t fb = (size_t)(feat >> 3) * 1024 + (feat & 7);
            int r0 = rt * 16 + lko * 4;
            #pragma unroll
            for (int r = 0; r < 4; ++r) {
                int m = g * K + r0 + r;
                float v = acc3[ct][r];
                unsigned short hi = f2bf(v);
                unsigned short lo = f2bf(v - bf2f(hi));
                AGGF2[(size_t)(m >> 7) * TILE_U32 + fb + (size_t)(m & 127) * 8] =
                    (unsigned)hi | ((unsigned)lo << 16);
            }
        }
    }
}

// -------------------- fused stage 2: gemm2 + pool2 + agg3 (unchanged R17) ------------
__global__ __launch_bounds__(1024) void k_stage2(const int* __restrict__ src,
                                                 const int* __restrict__ dst,
                                                 const float* __restrict__ wp,
                                                 const float* __restrict__ bias,
                                                 const unsigned short* __restrict__ Wf,
                                                 const int* __restrict__ cmap,
                                                 float* __restrict__ R,
                                                 const unsigned* __restrict__ XF,
                                                 const unsigned* __restrict__ AGGF,
                                                 unsigned* __restrict__ XF2,
                                                 unsigned* __restrict__ AGGF3) {
    __shared__ __align__(16) char smem[81920];
    __shared__ float sc[128];
    __shared__ unsigned long long keys[128];
    __shared__ int sel[64];
    __shared__ int inv[128];
    __shared__ float wn[128];
    __shared__ float gates[64];
    __shared__ float scp[2][128];
    __shared__ float pmx[8 * 128];
    __shared__ float psm[8 * 128];
    __shared__ int ncm[256];
    __shared__ float snorm_s;

    const int g = blockIdx.x, t = threadIdx.x;
    const int lane = t & 63, wv = t >> 6;
    const int l15 = lane & 15, lko = lane >> 4;
    const int rt = wv >> 1, cq = wv & 1;

    if (t < 64) {
        float v = wp[t] * wp[t] + wp[t + 64] * wp[t + 64];
        #pragma unroll
        for (int o = 32; o; o >>= 1) v += __shfl_xor(v, o);
        if (t == 0) snorm_s = sqrtf(v);
    }
    __syncthreads();
    if (t < 128) wn[t] = wp[t] / snorm_s;

    f32x4 acc2[4];
    {
        uint4* Whi = (uint4*)smem;
        uint4* Afs = (uint4*)(smem + 65536);
        const unsigned short* Wlo = Wf + 32768;
        {
            const uint4* Wf4 = (const uint4*)Wf;
            #pragma unroll
            for (int i = 0; i < 4; ++i) Whi[t + i * 1024] = Wf4[t + i * 1024];
        }
        #pragma unroll
        for (int c = 0; c < 4; ++c) acc2[c] = f32x4{0.f, 0.f, 0.f, 0.f};

        const int rowp = t & 127, kop = (t >> 7) & 3;

        for (int kt = 0; kt < 8; ++kt) {
            __syncthreads();
            if (t < 512) {
                const unsigned* P = (kt < 4) ? XF : AGGF;
                int ko = (kt & 3) * 4 + kop;
                size_t idx = (size_t)g * TILE_U32 + (size_t)ko * 1024 + (size_t)rowp * 8;
                uint4 qa = *(const uint4*)(P + idx);
                uint4 qb = *(const uint4*)(P + idx + 4);
                short8 h1, h2;
                unpack2(qa, qb, h1, h2);
                int rw = rowp ^ (kop << 2);
                *reinterpret_cast<short8*>(&Afs[(0 * 4 + kop) * 128 + rw]) = h1;
                *reinterpret_cast<short8*>(&Afs[(1 * 4 + kop) * 128 + rw]) = h2;
            }
            __syncthreads();

            int row = (rt * 16 + l15) ^ (lko << 2);
            short8 a1f = *reinterpret_cast<const short8*>(&Afs[(0 * 4 + lko) * 128 + row]);
            short8 a2f = *reinterpret_cast<const short8*>(&Afs[(1 * 4 + lko) * 128 + row]);
            const int kog = kt * 4 + lko;
            #pragma unroll
            for (int ct = 0; ct < 4; ++ct) {
                int col = cq * 64 + ct * 16 + l15;
                short8 w1 = *reinterpret_cast<const short8*>(&Whi[kog * 128 + col]);
                short8 w2 = *reinterpret_cast<const short8*>(Wlo + ((size_t)kog * 128 + col) * 8);
                acc2[ct] = __builtin_amdgcn_mfma_f32_16x16x32_bf16(a1f, w1, acc2[ct], 0, 0, 0);
                acc2[ct] = __builtin_amdgcn_mfma_f32_16x16x32_bf16(a2f, w1, acc2[ct], 0, 0, 0);
                acc2[ct] = __builtin_amdgcn_mfma_f32_16x16x32_bf16(a1f, w2, acc2[ct], 0, 0, 0);
            }
        }
    }
    __syncthreads();

    #pragma unroll
    for (int ct = 0; ct < 4; ++ct) {
        float bv = bias[cq * 64 + ct * 16 + l15];
        #pragma unroll
        for (int r = 0; r < 4; ++r) acc2[ct][r] = fmaxf(acc2[ct][r] + bv, 0.f);
    }

    {
        float wnv[4];
        #pragma unroll
        for (int ct = 0; ct < 4; ++ct) wnv[ct] = wn[cq * 64 + ct * 16 + l15];
        #pragma unroll
        for (int r = 0; r < 4; ++r) {
            float p = 0.f;
            #pragma unroll
            for (int ct = 0; ct < 4; ++ct) p += acc2[ct][r] * wnv[ct];
            p += __shfl_xor(p, 1); p += __shfl_xor(p, 2);
            p += __shfl_xor(p, 4); p += __shfl_xor(p, 8);
            if (l15 == 0) scp[cq][rt * 16 + lko * 4 + r] = p;
        }
    }
    {
        unsigned* adjc3 = (unsigned*)(smem + 33280);
        if (t < 1024) adjc3[t] = 0;
    }
    __syncthreads();
    if (t < 128) sc[t] = scp[0][t] + scp[1][t];
    __syncthreads();

    if (t < 128) {
        unsigned u = __float_as_uint(sc[t]);
        u = (u & 0x80000000u) ? ~u : (u | 0x80000000u);
        keys[t] = ((unsigned long long)u << 32) | (unsigned)(~t);
    }
    __syncthreads();
    for (int kk = 2; kk <= 128; kk <<= 1) {
        for (int j = kk >> 1; j > 0; j >>= 1) {
            if (t < 128) {
                int ixj = t ^ j;
                if (ixj > t) {
                    unsigned long long a = keys[t], b = keys[ixj];
                    bool up = (t & kk) == 0;
                    if (up ? (a < b) : (a > b)) { keys[t] = b; keys[ixj] = a; }
                }
            }
            __syncthreads();
        }
    }
    if (t < 64) sel[t] = (int)(~(unsigned)keys[t]);
    if (t < 128) inv[t] = -1;
    __syncthreads();
    if (t < 64) {
        inv[sel[t]] = t;
        gates[t] = tanhf(sc[sel[t]]);
    }
    __syncthreads();
    if (t < 256) {
        int c = cmap[g * 256 + t];
        ncm[t] = (c >= 0) ? inv[c] : -1;
    }
    __syncthreads();

    {
        unsigned* hp = (unsigned*)smem;
        #pragma unroll
        for (int r = 0; r < 4; ++r) {
            int rowg = rt * 16 + lko * 4 + r;
            int j = inv[rowg];
            if (j >= 0) {
                float gt = gates[j];
                #pragma unroll
                for (int ct = 0; ct < 4; ++ct) {
                    float v = acc2[ct][r] * gt;
                    unsigned short hi = f2bf(v);
                    unsigned short lo = f2bf(v - bf2f(hi));
                    hp[j * 130 + cq * 64 + ct * 16 + l15] = (unsigned)hi | ((unsigned)lo << 16);
                }
            }
        }
    }
    __syncthreads();

    {
        unsigned* hp = (unsigned*)smem;
        unsigned* adjc3 = (unsigned*)(smem + 33280);
        short* adjT3 = (short*)(smem + 37376);
        short* xs3 = (short*)(smem + 41472);
        constexpr int K = 64, NS4 = 16;

        {
            const int* sg = src + (size_t)g * EPER;
            const int* dg = dst + (size_t)g * EPER;
            #pragma unroll
            for (int j = 0; j < 4; ++j) {
                int e = j * 1024 + t;
                int s = ncm[sg[e]], d = ncm[dg[e]];
                if (s >= 0 && d >= 0) {
                    int pos = (s + 4 * d) & (K - 1);
                    __hip_atomic_fetch_add(&adjc3[d * NS4 + (pos >> 2)], 1u << ((pos & 3) * 8),
                                           __ATOMIC_RELAXED, __HIP_MEMORY_SCOPE_WORKGROUP);
                }
            }
        }
        {
            const int f = t & 127, seg = t >> 7;
            float mx = -INFINITY, sm = 0.f;
            for (int j = seg; j < K; j += 8) {
                unsigned u = hp[j * 130 + f];
                float v = bf2f((unsigned short)(u & 0xffffu)) + bf2f((unsigned short)(u >> 16));
                mx = fmaxf(mx, v);
                sm += v;
            }
            pmx[seg * 128 + f] = mx;
            psm[seg * 128 + f] = sm;
        }
        for (int i = t; i < K * F; i += 1024) {
            int j = i >> 7, f = i & 127;
            int m = g * K + j;
            XF2[(size_t)(m >> 7) * TILE_U32 + (size_t)(f >> 3) * 1024 + (size_t)(m & 127) * 8 + (f & 7)] =
                hp[j * 130 + f];
        }
        __syncthreads();
        if (t < 128) {
            float m = -INFINITY, s = 0.f;
            #pragma unroll
            for (int q = 0; q < 8; ++q) {
                m = fmaxf(m, pmx[q * 128 + t]);
                s += psm[q * 128 + t];
            }
            R[(size_t)g * 768 + 256 + t] = m;
            R[(size_t)g * 768 + 384 + t] = s * (1.0f / K);
        }

        const int rt3 = wv >> 2, cq3 = wv & 3;
        f32x4 acc3[2];
        acc3[0] = f32x4{0.f, 0.f, 0.f, 0.f};
        acc3[1] = f32x4{0.f, 0.f, 0.f, 0.f};

        for (int k0 = 0; k0 < K; k0 += 32) {
            __syncthreads();
            if (t < K * 4) {
                const int m = t >> 2, kg = (t & 3) * 8;
                unsigned short cs[8];
                #pragma unroll
                for (int q = 0; q < 2; ++q) {
                    unsigned w = adjc3[m * NS4 + ((((k0 + kg) >> 2) + m + q) & (NS4 - 1))];
                    cs[q * 4 + 0] = f2bf((float)(w & 255u));
                    cs[q * 4 + 1] = f2bf((float)((w >> 8) & 255u));
                    cs[q * 4 + 2] = f2bf((float)((w >> 16) & 255u));
                    cs[q * 4 + 3] = f2bf((float)(w >> 24));
                }
                short8 w8;
                #pragma unroll
                for (int j = 0; j < 8; ++j) w8[j] = (short)cs[j];
                *(short8*)&adjT3[(t & 3) * K * 8 + m * 8] = w8;
            }
            if (t >= 512) {
                const int feat = t & 127, o = (t >> 7) & 3;
                short8 h1, h2;
                #pragma unroll
                for (int j = 0; j < 8; ++j) {
                    unsigned u = hp[(k0 + o * 8 + j) * 130 + feat];
                    h1[j] = (short)(u & 0xffffu);
                    h2[j] = (short)(u >> 16);
                }
                *(short8*)&xs3[o * 1024 + feat * 8] = h1;
                *(short8*)&xs3[4096 + o * 1024 + feat * 8] = h2;
            }
            __syncthreads();

            short8 afr = *(const short8*)&adjT3[lko * K * 8 + (rt3 * 16 + l15) * 8];
            #pragma unroll
            for (int s = 0; s < 2; ++s) {
                #pragma unroll
                for (int ct = 0; ct < 2; ++ct) {
                    int feat = cq3 * 32 + ct * 16 + l15;
                    short8 bfr = *(const short8*)&xs3[s * 4096 + lko * 1024 + feat * 8];
                    acc3[ct] = __builtin_amdgcn_mfma_f32_16x16x32_bf16(afr, bfr, acc3[ct], 0, 0, 0);
                }
            }
        }

        #pragma unroll
        for (int ct = 0; ct < 2; ++ct) {
            int feat = cq3 * 32 + ct * 16 + l15;
            size_t fb = (size_t)(feat >> 3) * 1024 + (feat & 7);
            int r0 = rt3 * 16 + lko * 4;
            #pragma unroll
            for (int r = 0; r < 4; ++r) {
                int m = g * K + r0 + r;
                float v = acc3[ct][r];
                unsigned short hi = f2bf(v);
                unsigned short lo = f2bf(v - bf2f(hi));
                AGGF3[(size_t)(m >> 7) * TILE_U32 + fb + (size_t)(m & 127) * 8] =
                    (unsigned)hi | ((unsigned)lo << 16);
            }
        }
    }
}

// -------------------- fused stage 3: gemm3 + pool3 + MLP + log_softmax (unchanged R17) -----
__global__ __launch_bounds__(1024) void k_stage3(const float* __restrict__ wp,
                                                 const float* __restrict__ bias,
                                                 const unsigned short* __restrict__ Wf,
                                                 const float* __restrict__ R,
                                                 const unsigned* __restrict__ XF2,
                                                 const unsigned* __restrict__ AGGF3,
                                                 const float* __restrict__ W1, const float* __restrict__ b1,
                                                 const float* __restrict__ W2, const float* __restrict__ b2,
                                                 const float* __restrict__ W3, const float* __restrict__ b3,
                                                 float* __restrict__ out) {
    __shared__ __align__(16) char smem[73728];
    __shared__ float sc[64];
    __shared__ unsigned long long keys[64];
    __shared__ int sel[32];
    __shared__ int inv[64];
    __shared__ float wn[128];
    __shared__ float gates[32];
    __shared__ float scp[4][64];
    __shared__ float pmx[8 * 128];
    __shared__ float psm[8 * 128];
    __shared__ float z[768];
    __shared__ float part[8][128];
    __shared__ float z2[128];
    __shared__ float z3[64];
    __shared__ float lg[10];
    __shared__ float lse;
    __shared__ float snorm_s;

    const int g = blockIdx.x, t = threadIdx.x;
    const int lane = t & 63, wv = t >> 6;
    const int l15 = lane & 15, lko = lane >> 4;
    const int rt = wv >> 2, cq = wv & 3;

    if (t < 64) {
        float v = wp[t] * wp[t] + wp[t + 64] * wp[t + 64];
        #pragma unroll
        for (int o = 32; o; o >>= 1) v += __shfl_xor(v, o);
        if (t == 0) snorm_s = sqrtf(v);
    }
    __syncthreads();
    if (t < 128) wn[t] = wp[t] / snorm_s;
    if (t < 512) z[t] = R[(size_t)g * 768 + t];

    f32x4 acc2[2];
    {
        uint4* Whi = (uint4*)smem;
        uint4* Afs = (uint4*)(smem + 65536);
        const unsigned short* Wlo = Wf + 32768;
        {
            const uint4* Wf4 = (const uint4*)Wf;
            #pragma unroll
            for (int i = 0; i < 4; ++i) Whi[t + i * 1024] = Wf4[t + i * 1024];
        }
        acc2[0] = f32x4{0.f, 0.f, 0.f, 0.f};
        acc2[1] = f32x4{0.f, 0.f, 0.f, 0.f};

        const int rowp = t & 63, kop = (t >> 6) & 3;

        for (int kt = 0; kt < 8; ++kt) {
            __syncthreads();
            if (t < 256) {
                const unsigned* P = (kt < 4) ? XF2 : AGGF3;
                int ko = (kt & 3) * 4 + kop;
                size_t idx = (size_t)(g >> 1) * TILE_U32 + (size_t)ko * 1024
                           + (size_t)((g & 1) * 64 + rowp) * 8;
                uint4 qa = *(const uint4*)(P + idx);
                uint4 qb = *(const uint4*)(P + idx + 4);
                short8 h1, h2;
                unpack2(qa, qb, h1, h2);
                int rw = rowp ^ (kop << 2);
                *reinterpret_cast<short8*>(&Afs[(0 * 4 + kop) * 64 + rw]) = h1;
                *reinterpret_cast<short8*>(&Afs[(1 * 4 + kop) * 64 + rw]) = h2;
            }
            __syncthreads();

            int row = (rt * 16 + l15) ^ (lko << 2);
            short8 a1f = *reinterpret_cast<const short8*>(&Afs[(0 * 4 + lko) * 64 + row]);
            short8 a2f = *reinterpret_cast<const short8*>(&Afs[(1 * 4 + lko) * 64 + row]);
            const int kog = kt * 4 + lko;
            #pragma unroll
            for (int ct = 0; ct < 2; ++ct) {
                int col = cq * 32 + ct * 16 + l15;
                short8 w1 = *reinterpret_cast<const short8*>(&Whi[kog * 128 + col]);
                short8 w2 = *reinterpret_cast<const short8*>(Wlo + ((size_t)kog * 128 + col) * 8);
                acc2[ct] = __builtin_amdgcn_mfma_f32_16x16x32_bf16(a1f, w1, acc2[ct], 0, 0, 0);
                acc2[ct] = __builtin_amdgcn_mfma_f32_16x16x32_bf16(a2f, w1, acc2[ct], 0, 0, 0);
                acc2[ct] = __builtin_amdgcn_mfma_f32_16x16x32_bf16(a1f, w2, acc2[ct], 0, 0, 0);
            }
        }
    }
    __syncthreads();

    #pragma unroll
    for (int ct = 0; ct < 2; ++ct) {
        float bv = bias[cq * 32 + ct * 16 + l15];
        #pragma unroll
        for (int r = 0; r < 4; ++r) acc2[ct][r] = fmaxf(acc2[ct][r] + bv, 0.f);
    }

    {
        float wnv[2];
        wnv[0] = wn[cq * 32 + l15];
        wnv[1] = wn[cq * 32 + 16 + l15];
        #pragma unroll
        for (int r = 0; r < 4; ++r) {
            float p = acc2[0][r] * wnv[0] + acc2[1][r] * wnv[1];
            p += __shfl_xor(p, 1); p += __shfl_xor(p, 2);
            p += __shfl_xor(p, 4); p += __shfl_xor(p, 8);
            if (l15 == 0) scp[cq][rt * 16 + lko * 4 + r] = p;
        }
    }
    __syncthreads();
    if (t < 64) sc[t] = scp[0][t] + scp[1][t] + scp[2][t] + scp[3][t];
    __syncthreads();

    if (t < 64) {
        unsigned u = __float_as_uint(sc[t]);
        u = (u & 0x80000000u) ? ~u : (u | 0x80000000u);
        keys[t] = ((unsigned long long)u << 32) | (unsigned)(~t);
    }
    __syncthreads();
    for (int kk = 2; kk <= 64; kk <<= 1) {
        for (int j = kk >> 1; j > 0; j >>= 1) {
            if (t < 64) {
                int ixj = t ^ j;
                if (ixj > t) {
                    unsigned long long a = keys[t], b = keys[ixj];
                    bool up = (t & kk) == 0;
                    if (up ? (a < b) : (a > b)) { keys[t] = b; keys[ixj] = a; }
                }
            }
            __syncthreads();
        }
    }
    if (t < 32) sel[t] = (int)(~(unsigned)keys[t]);
    if (t < 64) inv[t] = -1;
    __syncthreads();
    if (t < 32) {
        inv[sel[t]] = t;
        gates[t] = tanhf(sc[sel[t]]);
    }
    __syncthreads();

    {
        unsigned* hp = (unsigned*)smem;
        #pragma unroll
        for (int r = 0; r < 4; ++r) {
            int rowg = rt * 16 + lko * 4 + r;
            int j = inv[rowg];
            if (j >= 0) {
                float gt = gates[j];
                #pragma unroll
                for (int ct = 0; ct < 2; ++ct) {
                    float v = acc2[ct][r] * gt;
                    unsigned short hi = f2bf(v);
                    unsigned short lo = f2bf(v - bf2f(hi));
                    hp[j * 130 + cq * 32 + ct * 16 + l15] = (unsigned)hi | ((unsigned)lo << 16);
                }
            }
        }
    }
    __syncthreads();

    {
        unsigned* hp = (unsigned*)smem;
        const int f = t & 127, seg = t >> 7;
        float mx = -INFINITY, sm = 0.f;
        for (int j = seg; j < 32; j += 8) {
            unsigned u = hp[j * 130 + f];
            float v = bf2f((unsigned short)(u & 0xffffu)) + bf2f((unsigned short)(u >> 16));
            mx = fmaxf(mx, v);
            sm += v;
        }
        pmx[seg * 128 + f] = mx;
        psm[seg * 128 + f] = sm;
    }
    __syncthreads();
    if (t < 128) {
        float m = -INFINITY, s = 0.f;
        #pragma unroll
        for (int q = 0; q < 8; ++q) {
            m = fmaxf(m, pmx[q * 128 + t]);
            s += psm[q * 128 + t];
        }
        z[512 + t] = m;
        z[640 + t] = s * (1.0f / 32);
    }
    __syncthreads();

    {
        const int f = t & 127, seg = t >> 7;
        float acc = 0.f;
        const float* w = W1 + (size_t)(seg * 96) * 128 + f;
        const float* zz = z + seg * 96;
        #pragma unroll 8
        for (int k = 0; k < 96; ++k) acc = fmaf(zz[k], w[(size_t)k * 128], acc);
        part[seg][f] = acc;
    }
    __syncthreads();
    if (t < 128) {
        float a = b1[t];
        #pragma unroll
        for (int q = 0; q < 8; ++q) a += part[q][t];
        z2[t] = fmaxf(a, 0.f);
    }
    __syncthreads();
    if (t < 512) {
        const int f = t & 63, seg = t >> 6;
        float acc = 0.f;
        const float* w = W2 + (size_t)(seg * 16) * 64 + f;
        const float* zz = z2 + seg * 16;
        #pragma unroll
        for (int k = 0; k < 16; ++k) acc = fmaf(zz[k], w[(size_t)k * 64], acc);
        part[seg][f] = acc;
    }
    __syncthreads();
    if (t < 64) {
        float a = b2[t];
        #pragma unroll
        for (int q = 0; q < 8; ++q) a += part[q][t];
        z3[t] = fmaxf(a, 0.f);
    }
    __syncthreads();
    if (t < 10) {
        float a3 = b3[t];
        #pragma unroll 8
        for (int k = 0; k < 64; ++k) a3 = fmaf(z3[k], W3[(size_t)k * 10 + t], a3);
        lg[t] = a3;
    }
    __syncthreads();
    if (t == 0) {
        float m = lg[0];
        for (int c = 1; c < 10; ++c) m = fmaxf(m, lg[c]);
        float s = 0.f;
        for (int c = 0; c < 10; ++c) s += expf(lg[c] - m);
        lse = m + logf(s);
    }
    __syncthreads();
    if (t < 10) out[(size_t)g * 10 + t] = lg[t] - lse;
}

extern "C" void kernel_launch(void* const* d_in, const int* in_sizes, int n_in,
                              void* d_out, int out_size, void* d_ws, size_t ws_size,
                              hipStream_t stream) {
    (void)in_sizes; (void)n_in; (void)out_size; (void)ws_size;
    const float* x    = (const float*)d_in[0];
    const int*   src  = (const int*)d_in[1];
    const int*   dst  = (const int*)d_in[2];
    const float* Wr1  = (const float*)d_in[3];
    const float* Wrel1= (const float*)d_in[4];
    const float* b1   = (const float*)d_in[5];
    const float* wp1  = (const float*)d_in[6];
    const float* Wr2  = (const float*)d_in[7];
    const float* Wrel2= (const float*)d_in[8];
    const float* b2   = (const float*)d_in[9];
    const float* wp2  = (const float*)d_in[10];
    const float* Wr3  = (const float*)d_in[11];
    const float* Wrel3= (const float*)d_in[12];
    const float* b3   = (const float*)d_in[13];
    const float* wp3  = (const float*)d_in[14];
    const float* L1w  = (const float*)d_in[15];
    const float* L1b  = (const float*)d_in[16];
    const float* L2w  = (const float*)d_in[17];
    const float* L2b  = (const float*)d_in[18];
    const float* L3w  = (const float*)d_in[19];
    const float* L3b  = (const float*)d_in[20];

    int*      cmap  = (int*)d_ws;                                  // G*256 i32
    float*    R     = (float*)(cmap + (size_t)G * 256);            // G*768 f32
    unsigned* AGGF2 = (unsigned*)(R + (size_t)G * 768);            // G tiles
    unsigned* XF    = AGGF2 + (size_t)G * TILE_U32;                // G tiles
    unsigned* XF2   = XF + (size_t)G * TILE_U32;                   // G/2 tiles
    unsigned* AGGF3 = XF2 + (size_t)(G / 2) * TILE_U32;            // G/2 tiles
    unsigned short* Wf = (unsigned short*)(AGGF3 + (size_t)(G / 2) * TILE_U32);
    float* out = (float*)d_out;

    k_wsplit<<<384, 256, 0, stream>>>(Wr1, Wrel1, Wr2, Wrel2, Wr3, Wrel3, Wf);

    k_stage1<<<G, 1024, 0, stream>>>(x, src, dst, wp1, b1, Wf, cmap, R, XF, AGGF2);
    k_stage2<<<G, 1024, 0, stream>>>(src, dst, wp2, b2, Wf + 65536, cmap, R, XF, AGGF2, XF2, AGGF3);
    k_stage3<<<G, 1024, 0, stream>>>(wp3, b3, Wf + 131072, R, XF2, AGGF3,
                                     L1w, L1b, L2w, L2b, L3w, L3b, out);
}

// Round 20
// 109.254 us; speedup vs baseline: 1.4582x; 1.0322x over previous
//
#include <hip/hip_runtime.h>
#include <cstdint>
#include <cstddef>

#define G 256
#define EPER 4096
#define F 128
#define TILE_U32 16384  // fragment tile: 16 ko * 128 row * 8 j (u32 each)

typedef __attribute__((ext_vector_type(8))) short short8;
typedef __attribute__((ext_vector_type(4))) short s16x4;
typedef __attribute__((ext_vector_type(4))) float f32x4;

__device__ inline unsigned short f2bf(float f) {
    unsigned u = __float_as_uint(f);
    u += 0x7FFFu + ((u >> 16) & 1u);
    return (unsigned short)(u >> 16);
}
__device__ inline float bf2f(unsigned short b) { return __uint_as_float(((unsigned)b) << 16); }

__device__ inline void unpack2(uint4 qa, uint4 qb, short8& h1, short8& h2) {
    h1[0] = (short)qa.x; h2[0] = (short)(qa.x >> 16);
    h1[1] = (short)qa.y; h2[1] = (short)(qa.y >> 16);
    h1[2] = (short)qa.z; h2[2] = (short)(qa.z >> 16);
    h1[3] = (short)qa.w; h2[3] = (short)(qa.w >> 16);
    h1[4] = (short)qb.x; h2[4] = (short)(qb.x >> 16);
    h1[5] = (short)qb.y; h2[5] = (short)(qb.y >> 16);
    h1[6] = (short)qb.z; h2[6] = (short)(qb.z >> 16);
    h1[7] = (short)qb.w; h2[7] = (short)(qb.w >> 16);
}

// exact bf16 of small non-negative int (count <= 255 fits bf16 exactly)
__device__ inline short u8bf(unsigned byte) {
    return (short)(__float_as_uint((float)byte) >> 16);
}

// Descending bitonic sort of keys[0..N) (unique keys). Wave-synchronous for
// XOR distances < 64 (CDNA wave64 lockstep; volatile defeats register caching);
// __syncthreads only for cross-wave passes (j >= 64): 3 barriers at N=256,
// 1 at N=128, 0 at N=64 (vs N passes' worth before).
template<int N>
__device__ inline void bitonic_desc(volatile unsigned long long* keys, int t) {
    for (int kk = 2; kk <= N; kk <<= 1) {
        for (int j = kk >> 1; j > 0; j >>= 1) {
            if (j >= 64) __syncthreads();
            if (t < N) {
                unsigned long long a = keys[t];
                unsigned long long b = keys[t ^ j];
                bool up = (t & kk) == 0;
                bool lower = (t & j) == 0;
                unsigned long long mx = a > b ? a : b;
                unsigned long long mn = a > b ? b : a;
                keys[t] = (up == lower) ? mx : mn;
            }
        }
    }
    __syncthreads();
}

// -------------------- W pre-split: [Wr;Wl] -> fragment-major bf16 hi/lo --------------------
__global__ __launch_bounds__(256) void k_wsplit(const float* __restrict__ Wr1, const float* __restrict__ Wl1,
                                                const float* __restrict__ Wr2, const float* __restrict__ Wl2,
                                                const float* __restrict__ Wr3, const float* __restrict__ Wl3,
                                                unsigned short* __restrict__ Wf) {
    int gid = blockIdx.x * 256 + threadIdx.x;   // 0..98303
    int s = gid >> 15;
    int idx = gid & 32767;
    int j = idx & 7, col = (idx >> 3) & 127, ko = idx >> 10;
    int k = ko * 8 + j;
    const float* Wr = (s == 0) ? Wr1 : (s == 1) ? Wr2 : Wr3;
    const float* Wl = (s == 0) ? Wl1 : (s == 1) ? Wl2 : Wl3;
    float f = (k < 128) ? Wr[(size_t)k * 128 + col] : Wl[(size_t)(k - 128) * 128 + col];
    unsigned short h1 = f2bf(f), h2 = f2bf(f - bf2f(h1));
    Wf[(size_t)s * 65536 + idx] = h1;
    Wf[(size_t)s * 65536 + 32768 + idx] = h2;
}

// -------------------- fused stage 1: agg1 + conv-gemm + pool + agg2 --------------------
__global__ __launch_bounds__(1024) void k_stage1(const float* __restrict__ X,
                                                 const int* __restrict__ src,
                                                 const int* __restrict__ dst,
                                                 const float* __restrict__ wp,
                                                 const float* __restrict__ bias,
                                                 const unsigned short* __restrict__ Wf,
                                                 int* __restrict__ cmap,
                                                 float* __restrict__ R,
                                                 unsigned* __restrict__ XF,
                                                 unsigned* __restrict__ AGGF2) {
    __shared__ __align__(16) char smem[147456];
    __shared__ float sc[256];
    __shared__ unsigned long long keys[256];
    __shared__ int sel[128];
    __shared__ int inv[256];
    __shared__ float wn[128];
    __shared__ float gates[128];
    __shared__ float pmx[8 * 128];
    __shared__ float psm[8 * 128];
    __shared__ int ncm[256];
    __shared__ float snorm_s;

    const int g = blockIdx.x, t = threadIdx.x;
    const int lane = t & 63, wv = t >> 6;
    const int l15 = lane & 15, lko = lane >> 4;

    if (t < 64) {
        float v = wp[t] * wp[t] + wp[t + 64] * wp[t + 64];
        #pragma unroll
        for (int o = 32; o; o >>= 1) v += __shfl_xor(v, o);
        if (t == 0) snorm_s = sqrtf(v);
    }

    f32x4 acc[8];  // agg1 result, lives through phase B

    // ================= phase A: agg1 = Adj @ x (result -> regs) =================
    {
        unsigned* adjc = (unsigned*)smem;            // 64 KB (u8 counts, rotation 8m)
        short* xsA = (short*)(smem + 65536);         // dbuf 2 x 16 KB
        {
            uint4* z = (uint4*)adjc;
            #pragma unroll
            for (int i = t; i < 4096; i += 1024) z[i] = uint4{0, 0, 0, 0};
        }
        __syncthreads();
        if (t < 128) wn[t] = wp[t] / snorm_s;

        const int* sg = src + (size_t)g * EPER;
        const int* dg = dst + (size_t)g * EPER;
        #pragma unroll
        for (int j = 0; j < 4; ++j) {
            int e = j * 1024 + t;
            int s = sg[e], d = dg[e];
            int pos = (s + 8 * d) & 255;
            __hip_atomic_fetch_add(&adjc[d * 64 + (pos >> 2)], 1u << ((pos & 3) * 8),
                                   __ATOMIC_RELAXED, __HIP_MEMORY_SCOPE_WORKGROUP);
        }

        #pragma unroll
        for (int c = 0; c < 8; ++c) acc[c] = f32x4{0.f, 0.f, 0.f, 0.f};

        const float* Xg = X + (size_t)g * 32768;
        const int feat = t & 127, ko2 = (t >> 7) & 3, jh = t >> 9;
        const int stoff = ko2 * 1024 + feat * 8 + jh * 4;

        // prologue: stage step 0 into buf 0
        {
            float v[4];
            #pragma unroll
            for (int i = 0; i < 4; ++i)
                v[i] = Xg[(size_t)(ko2 * 8 + jh * 4 + i) * F + feat];
            s16x4 h1, h2;
            #pragma unroll
            for (int i = 0; i < 4; ++i) {
                unsigned short a1 = f2bf(v[i]);
                unsigned short a2 = f2bf(v[i] - bf2f(a1));
                h1[i] = (short)a1; h2[i] = (short)a2;
            }
            *(s16x4*)&xsA[stoff] = h1;
            *(s16x4*)&xsA[4096 + stoff] = h2;
        }
        __syncthreads();

        for (int kt = 0; kt < 8; ++kt) {
            const int b = kt & 1;
            float v[4];
            if (kt < 7) {
                int k0n = (kt + 1) * 32;
                #pragma unroll
                for (int i = 0; i < 4; ++i)
                    v[i] = Xg[(size_t)(k0n + ko2 * 8 + jh * 4 + i) * F + feat];
            }
            // A-frag direct from adjc (static; no barrier needed)
            {
                int m = wv * 16 + l15;
                int pos = ((kt * 32 + lko * 8) + 8 * m) & 255;
                unsigned w0 = adjc[m * 64 + (pos >> 2)];
                unsigned w1 = adjc[m * 64 + (pos >> 2) + 1];
                short8 afr;
                afr[0] = u8bf(w0 & 255u);
                afr[1] = u8bf((w0 >> 8) & 255u);
                afr[2] = u8bf((w0 >> 16) & 255u);
                afr[3] = u8bf(w0 >> 24);
                afr[4] = u8bf(w1 & 255u);
                afr[5] = u8bf((w1 >> 8) & 255u);
                afr[6] = u8bf((w1 >> 16) & 255u);
                afr[7] = u8bf(w1 >> 24);
                const short* xb = xsA + b * 8192;
                #pragma unroll
                for (int s = 0; s < 2; ++s) {
                    #pragma unroll
                    for (int ct = 0; ct < 8; ++ct) {
                        short8 bfr = *(const short8*)&xb[s * 4096 + lko * 1024 + (ct * 16 + l15) * 8];
                        acc[ct] = __builtin_amdgcn_mfma_f32_16x16x32_bf16(afr, bfr, acc[ct], 0, 0, 0);
                    }
                }
            }
            // write next-step staging (loads already in flight)
            if (kt < 7) {
                s16x4 h1, h2;
                #pragma unroll
                for (int i = 0; i < 4; ++i) {
                    unsigned short a1 = f2bf(v[i]);
                    unsigned short a2 = f2bf(v[i] - bf2f(a1));
                    h1[i] = (short)a1; h2[i] = (short)a2;
                }
                short* xo = xsA + (b ^ 1) * 8192;
                *(s16x4*)&xo[stoff] = h1;
                *(s16x4*)&xo[4096 + stoff] = h2;
            }
            __syncthreads();
        }
    }

    // ================= phase B: h = relu([X|AGG] @ [Wr;Wl] + b), in regs =================
    f32x4 acc2[8];
    {
        uint4* Whi = (uint4*)smem;                    // 64 KB
        unsigned* AGP = (unsigned*)(smem + 65536);    // dbuf 2 x (256*36) u32 = 72 KB
        const unsigned short* Wlo = Wf + 32768;
        {
            const uint4* Wf4 = (const uint4*)Wf;
            #pragma unroll
            for (int i = 0; i < 4; ++i) Whi[t + i * 1024] = Wf4[t + i * 1024];
        }
        #pragma unroll
        for (int c = 0; c < 8; ++c) acc2[c] = f32x4{0.f, 0.f, 0.f, 0.f};

        const int rs = t >> 2, ck = t & 3;
        const float* Xg = X + (size_t)g * 32768;

        // prologue: stage kt=0 (X) into AGP[0]
        {
            const float* srow = Xg + (size_t)rs * F + ck * 8;
            float4 fa = *(const float4*)srow;
            float4 fb = *(const float4*)(srow + 4);
            float vv[8] = {fa.x, fa.y, fa.z, fa.w, fb.x, fb.y, fb.z, fb.w};
            unsigned q[8];
            #pragma unroll
            for (int j = 0; j < 8; ++j) {
                unsigned short hi = f2bf(vv[j]);
                unsigned short lo = f2bf(vv[j] - bf2f(hi));
                q[j] = (unsigned)hi | ((unsigned)lo << 16);
            }
            unsigned* d0 = AGP + rs * 36 + ck * 8;
            *(uint4*)d0 = uint4{q[0], q[1], q[2], q[3]};
            *(uint4*)(d0 + 4) = uint4{q[4], q[5], q[6], q[7]};
        }
        __syncthreads();  // covers Whi copy + AGP[0]

        for (int kt = 0; kt < 8; ++kt) {
            const int b = kt & 1;
            float4 fa, fb;
            if (kt < 3) {
                const float* srow = Xg + (size_t)rs * F + (kt + 1) * 32 + ck * 8;
                fa = *(const float4*)srow;
                fb = *(const float4*)(srow + 4);
            }
            // MFMA on AGP[b]
            {
                int row = wv * 16 + l15;
                const unsigned* ag = AGP + b * 9216 + row * 36 + lko * 8;
                uint4 qa = *(const uint4*)ag;
                uint4 qb = *(const uint4*)(ag + 4);
                short8 a1f, a2f;
                unpack2(qa, qb, a1f, a2f);
                const int kog = kt * 4 + lko;
                #pragma unroll
                for (int ct = 0; ct < 8; ++ct) {
                    int col = ct * 16 + l15;
                    short8 w1 = *(const short8*)&Whi[kog * 128 + col];
                    short8 w2 = *(const short8*)(Wlo + ((size_t)kog * 128 + col) * 8);
                    acc2[ct] = __builtin_amdgcn_mfma_f32_16x16x32_bf16(a1f, w1, acc2[ct], 0, 0, 0);
                    acc2[ct] = __builtin_amdgcn_mfma_f32_16x16x32_bf16(a2f, w1, acc2[ct], 0, 0, 0);
                    acc2[ct] = __builtin_amdgcn_mfma_f32_16x16x32_bf16(a1f, w2, acc2[ct], 0, 0, 0);
                }
            }
            // stage next step into AGP[b^1]
            if (kt < 7) {
                unsigned* dstb = AGP + (b ^ 1) * 9216;
                if (kt < 3) {
                    float vv[8] = {fa.x, fa.y, fa.z, fa.w, fb.x, fb.y, fb.z, fb.w};
                    unsigned q[8];
                    #pragma unroll
                    for (int j = 0; j < 8; ++j) {
                        unsigned short hi = f2bf(vv[j]);
                        unsigned short lo = f2bf(vv[j] - bf2f(hi));
                        q[j] = (unsigned)hi | ((unsigned)lo << 16);
                    }
                    unsigned* d0 = dstb + rs * 36 + ck * 8;
                    *(uint4*)d0 = uint4{q[0], q[1], q[2], q[3]};
                    *(uint4*)(d0 + 4) = uint4{q[4], q[5], q[6], q[7]};
                } else {
                    // from agg regs: next window feats f0=(kt-3)*32, thread owns l={l15,16+l15}
                    int ct0 = (kt - 3) * 2;
                    #pragma unroll
                    for (int r = 0; r < 4; ++r) {
                        int rowo = wv * 16 + lko * 4 + r;
                        #pragma unroll
                        for (int h = 0; h < 2; ++h) {
                            float vv = acc[ct0 + h][r];
                            unsigned short hi = f2bf(vv);
                            unsigned short lo = f2bf(vv - bf2f(hi));
                            dstb[rowo * 36 + h * 16 + l15] = (unsigned)hi | ((unsigned)lo << 16);
                        }
                    }
                }
            }
            __syncthreads();
        }
    }

    // bias + relu fold (h in acc2; row = wv*16 + lko*4 + r, col = ct*16 + l15)
    #pragma unroll
    for (int ct = 0; ct < 8; ++ct) {
        float bv = bias[ct * 16 + l15];
        #pragma unroll
        for (int r = 0; r < 4; ++r) acc2[ct][r] = fmaxf(acc2[ct][r] + bv, 0.f);
    }

    // ================= phase C: scores + top-k =================
    {
        unsigned* adjc2 = (unsigned*)(smem + 66560);
        for (int i = t; i < 4096; i += 1024) adjc2[i] = 0;  // zero 16 KB for agg2
        float wnv[8];
        #pragma unroll
        for (int ct = 0; ct < 8; ++ct) wnv[ct] = wn[ct * 16 + l15];
        #pragma unroll
        for (int r = 0; r < 4; ++r) {
            float p = 0.f;
            #pragma unroll
            for (int ct = 0; ct < 8; ++ct) p += acc2[ct][r] * wnv[ct];
            p += __shfl_xor(p, 1); p += __shfl_xor(p, 2);
            p += __shfl_xor(p, 4); p += __shfl_xor(p, 8);
            if (l15 == 0) sc[wv * 16 + lko * 4 + r] = p;
        }
    }
    __syncthreads();

    if (t < 256) {
        unsigned u = __float_as_uint(sc[t]);
        u = (u & 0x80000000u) ? ~u : (u | 0x80000000u);
        keys[t] = ((unsigned long long)u << 32) | (unsigned)(~t);
    }
    bitonic_desc<256>((volatile unsigned long long*)keys, t);

    if (t < 128) sel[t] = (int)(~(unsigned)keys[t]);
    if (t < 256) inv[t] = -1;
    __syncthreads();
    if (t < 128) {
        inv[sel[t]] = t;
        gates[t] = tanhf(sc[sel[t]]);
    }
    __syncthreads();
    if (t < 256) {
        int nc = inv[t];  // STAGE 1: composed map = inv
        ncm[t] = nc;
        cmap[g * 256 + t] = nc;
    }
    __syncthreads();

    // ================= phase D: write selected rows to hp (packed u32, pad 130) ==========
    {
        unsigned* hp = (unsigned*)smem;  // 128 x 130 u32 = 66560 B
        #pragma unroll
        for (int r = 0; r < 4; ++r) {
            int rowg = wv * 16 + lko * 4 + r;
            int j = inv[rowg];
            if (j >= 0) {
                float gt = gates[j];
                #pragma unroll
                for (int ct = 0; ct < 8; ++ct) {
                    float v = acc2[ct][r] * gt;
                    unsigned short hi = f2bf(v);
                    unsigned short lo = f2bf(v - bf2f(hi));
                    hp[j * 130 + ct * 16 + l15] = (unsigned)hi | ((unsigned)lo << 16);
                }
            }
        }
    }
    __syncthreads();

    // ================= phase E: edge-build + readout + XF + agg2 -> AGGF2 ================
    {
        unsigned* hp = (unsigned*)smem;
        unsigned* adjc2 = (unsigned*)(smem + 66560);   // 16 KB
        short* adjT2 = (short*)(smem + 82944);         // 8 KB
        short* xs2 = (short*)(smem + 91136);           // 2 x 8 KB
        constexpr int K = 128, NS4 = 32;

        {
            const int* sg = src + (size_t)g * EPER;
            const int* dg = dst + (size_t)g * EPER;
            #pragma unroll
            for (int j = 0; j < 4; ++j) {
                int e = j * 1024 + t;
                int s = ncm[sg[e]], d = ncm[dg[e]];
                if (s >= 0 && d >= 0) {
                    int pos = (s + 4 * d) & (K - 1);
                    __hip_atomic_fetch_add(&adjc2[d * NS4 + (pos >> 2)], 1u << ((pos & 3) * 8),
                                           __ATOMIC_RELAXED, __HIP_MEMORY_SCOPE_WORKGROUP);
                }
            }
        }
        {
            const int f = t & 127, seg = t >> 7;
            float mx = -INFINITY, sm = 0.f;
            for (int j = seg; j < K; j += 8) {
                unsigned u = hp[j * 130 + f];
                float v = bf2f((unsigned short)(u & 0xffffu)) + bf2f((unsigned short)(u >> 16));
                mx = fmaxf(mx, v);
                sm += v;
            }
            pmx[seg * 128 + f] = mx;
            psm[seg * 128 + f] = sm;
        }
        for (int i = t; i < K * F; i += 1024) {
            int j = i >> 7, f = i & 127;
            int m = g * K + j;
            XF[(size_t)(m >> 7) * TILE_U32 + (size_t)(f >> 3) * 1024 + (size_t)(m & 127) * 8 + (f & 7)] =
                hp[j * 130 + f];
        }
        __syncthreads();
        if (t < 128) {
            float m = -INFINITY, s = 0.f;
            #pragma unroll
            for (int q = 0; q < 8; ++q) {
                m = fmaxf(m, pmx[q * 128 + t]);
                s += psm[q * 128 + t];
            }
            R[(size_t)g * 768 + t] = m;
            R[(size_t)g * 768 + 128 + t] = s * (1.0f / K);
        }

        const int rt = wv >> 1, cq = wv & 1;
        f32x4 acc3[4];
        #pragma unroll
        for (int c = 0; c < 4; ++c) acc3[c] = f32x4{0.f, 0.f, 0.f, 0.f};

        for (int k0 = 0; k0 < K; k0 += 32) {
            __syncthreads();
            if (t < K * 4) {
                const int m = t >> 2, kg = (t & 3) * 8;
                unsigned short cs[8];
                #pragma unroll
                for (int q = 0; q < 2; ++q) {
                    unsigned w = adjc2[m * NS4 + ((((k0 + kg) >> 2) + m + q) & (NS4 - 1))];
                    cs[q * 4 + 0] = f2bf((float)(w & 255u));
                    cs[q * 4 + 1] = f2bf((float)((w >> 8) & 255u));
                    cs[q * 4 + 2] = f2bf((float)((w >> 16) & 255u));
                    cs[q * 4 + 3] = f2bf((float)(w >> 24));
                }
                short8 w8;
                #pragma unroll
                for (int j = 0; j < 8; ++j) w8[j] = (short)cs[j];
                *(short8*)&adjT2[(t & 3) * K * 8 + m * 8] = w8;
            }
            if (t >= 512) {
                const int feat = t & 127, o = (t >> 7) & 3;
                short8 h1, h2;
                #pragma unroll
                for (int j = 0; j < 8; ++j) {
                    unsigned u = hp[(k0 + o * 8 + j) * 130 + feat];
                    h1[j] = (short)(u & 0xffffu);
                    h2[j] = (short)(u >> 16);
                }
                *(short8*)&xs2[o * 1024 + feat * 8] = h1;
                *(short8*)&xs2[4096 + o * 1024 + feat * 8] = h2;
            }
            __syncthreads();

            short8 afr = *(const short8*)&adjT2[lko * K * 8 + (rt * 16 + l15) * 8];
            #pragma unroll
            for (int s = 0; s < 2; ++s) {
                #pragma unroll
                for (int ct = 0; ct < 4; ++ct) {
                    int feat = cq * 64 + ct * 16 + l15;
                    short8 bfr = *(const short8*)&xs2[s * 4096 + lko * 1024 + feat * 8];
                    acc3[ct] = __builtin_amdgcn_mfma_f32_16x16x32_bf16(afr, bfr, acc3[ct], 0, 0, 0);
                }
            }
        }

        #pragma unroll
        for (int ct = 0; ct < 4; ++ct) {
            int feat = cq * 64 + ct * 16 + l15;
            size_t fb = (size_t)(feat >> 3) * 1024 + (feat & 7);
            int r0 = rt * 16 + lko * 4;
            #pragma unroll
            for (int r = 0; r < 4; ++r) {
                int m = g * K + r0 + r;
                float v = acc3[ct][r];
                unsigned short hi = f2bf(v);
                unsigned short lo = f2bf(v - bf2f(hi));
                AGGF2[(size_t)(m >> 7) * TILE_U32 + fb + (size_t)(m & 127) * 8] =
                    (unsigned)hi | ((unsigned)lo << 16);
            }
        }
    }
}

// -------------------- fused stage 2: gemm2 + pool2 + agg3 ------------
__global__ __launch_bounds__(1024) void k_stage2(const int* __restrict__ src,
                                                 const int* __restrict__ dst,
                                                 const float* __restrict__ wp,
                                                 const float* __restrict__ bias,
                                                 const unsigned short* __restrict__ Wf,
                                                 const int* __restrict__ cmap,
                                                 float* __restrict__ R,
                                                 const unsigned* __restrict__ XF,
                                                 const unsigned* __restrict__ AGGF,
                                                 unsigned* __restrict__ XF2,
                                                 unsigned* __restrict__ AGGF3) {
    __shared__ __align__(16) char smem[81920];
    __shared__ float sc[128];
    __shared__ unsigned long long keys[128];
    __shared__ int sel[64];
    __shared__ int inv[128];
    __shared__ float wn[128];
    __shared__ float gates[64];
    __shared__ float scp[2][128];
    __shared__ float pmx[8 * 128];
    __shared__ float psm[8 * 128];
    __shared__ int ncm[256];
    __shared__ float snorm_s;

    const int g = blockIdx.x, t = threadIdx.x;
    const int lane = t & 63, wv = t >> 6;
    const int l15 = lane & 15, lko = lane >> 4;
    const int rt = wv >> 1, cq = wv & 1;

    if (t < 64) {
        float v = wp[t] * wp[t] + wp[t + 64] * wp[t + 64];
        #pragma unroll
        for (int o = 32; o; o >>= 1) v += __shfl_xor(v, o);
        if (t == 0) snorm_s = sqrtf(v);
    }
    __syncthreads();
    if (t < 128) wn[t] = wp[t] / snorm_s;

    f32x4 acc2[4];
    {
        uint4* Whi = (uint4*)smem;
        uint4* Afs = (uint4*)(smem + 65536);
        const unsigned short* Wlo = Wf + 32768;
        {
            const uint4* Wf4 = (const uint4*)Wf;
            #pragma unroll
            for (int i = 0; i < 4; ++i) Whi[t + i * 1024] = Wf4[t + i * 1024];
        }
        #pragma unroll
        for (int c = 0; c < 4; ++c) acc2[c] = f32x4{0.f, 0.f, 0.f, 0.f};

        const int rowp = t & 127, kop = (t >> 7) & 3;

        for (int kt = 0; kt < 8; ++kt) {
            __syncthreads();
            if (t < 512) {
                const unsigned* P = (kt < 4) ? XF : AGGF;
                int ko = (kt & 3) * 4 + kop;
                size_t idx = (size_t)g * TILE_U32 + (size_t)ko * 1024 + (size_t)rowp * 8;
                uint4 qa = *(const uint4*)(P + idx);
                uint4 qb = *(const uint4*)(P + idx + 4);
                short8 h1, h2;
                unpack2(qa, qb, h1, h2);
                int rw = rowp ^ (kop << 2);
                *reinterpret_cast<short8*>(&Afs[(0 * 4 + kop) * 128 + rw]) = h1;
                *reinterpret_cast<short8*>(&Afs[(1 * 4 + kop) * 128 + rw]) = h2;
            }
            __syncthreads();

            int row = (rt * 16 + l15) ^ (lko << 2);
            short8 a1f = *reinterpret_cast<const short8*>(&Afs[(0 * 4 + lko) * 128 + row]);
            short8 a2f = *reinterpret_cast<const short8*>(&Afs[(1 * 4 + lko) * 128 + row]);
            const int kog = kt * 4 + lko;
            #pragma unroll
            for (int ct = 0; ct < 4; ++ct) {
                int col = cq * 64 + ct * 16 + l15;
                short8 w1 = *reinterpret_cast<const short8*>(&Whi[kog * 128 + col]);
                short8 w2 = *reinterpret_cast<const short8*>(Wlo + ((size_t)kog * 128 + col) * 8);
                acc2[ct] = __builtin_amdgcn_mfma_f32_16x16x32_bf16(a1f, w1, acc2[ct], 0, 0, 0);
                acc2[ct] = __builtin_amdgcn_mfma_f32_16x16x32_bf16(a2f, w1, acc2[ct], 0, 0, 0);
                acc2[ct] = __builtin_amdgcn_mfma_f32_16x16x32_bf16(a1f, w2, acc2[ct], 0, 0, 0);
            }
        }
    }
    __syncthreads();

    #pragma unroll
    for (int ct = 0; ct < 4; ++ct) {
        float bv = bias[cq * 64 + ct * 16 + l15];
        #pragma unroll
        for (int r = 0; r < 4; ++r) acc2[ct][r] = fmaxf(acc2[ct][r] + bv, 0.f);
    }

    {
        float wnv[4];
        #pragma unroll
        for (int ct = 0; ct < 4; ++ct) wnv[ct] = wn[cq * 64 + ct * 16 + l15];
        #pragma unroll
        for (int r = 0; r < 4; ++r) {
            float p = 0.f;
            #pragma unroll
            for (int ct = 0; ct < 4; ++ct) p += acc2[ct][r] * wnv[ct];
            p += __shfl_xor(p, 1); p += __shfl_xor(p, 2);
            p += __shfl_xor(p, 4); p += __shfl_xor(p, 8);
            if (l15 == 0) scp[cq][rt * 16 + lko * 4 + r] = p;
        }
    }
    {
        unsigned* adjc3 = (unsigned*)(smem + 33280);
        if (t < 1024) adjc3[t] = 0;
    }
    __syncthreads();
    if (t < 128) sc[t] = scp[0][t] + scp[1][t];
    __syncthreads();

    if (t < 128) {
        unsigned u = __float_as_uint(sc[t]);
        u = (u & 0x80000000u) ? ~u : (u | 0x80000000u);
        keys[t] = ((unsigned long long)u << 32) | (unsigned)(~t);
    }
    bitonic_desc<128>((volatile unsigned long long*)keys, t);

    if (t < 64) sel[t] = (int)(~(unsigned)keys[t]);
    if (t < 128) inv[t] = -1;
    __syncthreads();
    if (t < 64) {
        inv[sel[t]] = t;
        gates[t] = tanhf(sc[sel[t]]);
    }
    __syncthreads();
    if (t < 256) {
        int c = cmap[g * 256 + t];
        ncm[t] = (c >= 0) ? inv[c] : -1;
    }
    __syncthreads();

    {
        unsigned* hp = (unsigned*)smem;
        #pragma unroll
        for (int r = 0; r < 4; ++r) {
            int rowg = rt * 16 + lko * 4 + r;
            int j = inv[rowg];
            if (j >= 0) {
                float gt = gates[j];
                #pragma unroll
                for (int ct = 0; ct < 4; ++ct) {
                    float v = acc2[ct][r] * gt;
                    unsigned short hi = f2bf(v);
                    unsigned short lo = f2bf(v - bf2f(hi));
                    hp[j * 130 + cq * 64 + ct * 16 + l15] = (unsigned)hi | ((unsigned)lo << 16);
                }
            }
        }
    }
    __syncthreads();

    {
        unsigned* hp = (unsigned*)smem;
        unsigned* adjc3 = (unsigned*)(smem + 33280);
        short* adjT3 = (short*)(smem + 37376);
        short* xs3 = (short*)(smem + 41472);
        constexpr int K = 64, NS4 = 16;

        {
            const int* sg = src + (size_t)g * EPER;
            const int* dg = dst + (size_t)g * EPER;
            #pragma unroll
            for (int j = 0; j < 4; ++j) {
                int e = j * 1024 + t;
                int s = ncm[sg[e]], d = ncm[dg[e]];
                if (s >= 0 && d >= 0) {
                    int pos = (s + 4 * d) & (K - 1);
                    __hip_atomic_fetch_add(&adjc3[d * NS4 + (pos >> 2)], 1u << ((pos & 3) * 8),
                                           __ATOMIC_RELAXED, __HIP_MEMORY_SCOPE_WORKGROUP);
                }
            }
        }
        {
            const int f = t & 127, seg = t >> 7;
            float mx = -INFINITY, sm = 0.f;
            for (int j = seg; j < K; j += 8) {
                unsigned u = hp[j * 130 + f];
                float v = bf2f((unsigned short)(u & 0xffffu)) + bf2f((unsigned short)(u >> 16));
                mx = fmaxf(mx, v);
                sm += v;
            }
            pmx[seg * 128 + f] = mx;
            psm[seg * 128 + f] = sm;
        }
        for (int i = t; i < K * F; i += 1024) {
            int j = i >> 7, f = i & 127;
            int m = g * K + j;
            XF2[(size_t)(m >> 7) * TILE_U32 + (size_t)(f >> 3) * 1024 + (size_t)(m & 127) * 8 + (f & 7)] =
                hp[j * 130 + f];
        }
        __syncthreads();
        if (t < 128) {
            float m = -INFINITY, s = 0.f;
            #pragma unroll
            for (int q = 0; q < 8; ++q) {
                m = fmaxf(m, pmx[q * 128 + t]);
                s += psm[q * 128 + t];
            }
            R[(size_t)g * 768 + 256 + t] = m;
            R[(size_t)g * 768 + 384 + t] = s * (1.0f / K);
        }

        const int rt3 = wv >> 2, cq3 = wv & 3;
        f32x4 acc3[2];
        acc3[0] = f32x4{0.f, 0.f, 0.f, 0.f};
        acc3[1] = f32x4{0.f, 0.f, 0.f, 0.f};

        for (int k0 = 0; k0 < K; k0 += 32) {
            __syncthreads();
            if (t < K * 4) {
                const int m = t >> 2, kg = (t & 3) * 8;
                unsigned short cs[8];
                #pragma unroll
                for (int q = 0; q < 2; ++q) {
                    unsigned w = adjc3[m * NS4 + ((((k0 + kg) >> 2) + m + q) & (NS4 - 1))];
                    cs[q * 4 + 0] = f2bf((float)(w & 255u));
                    cs[q * 4 + 1] = f2bf((float)((w >> 8) & 255u));
                    cs[q * 4 + 2] = f2bf((float)((w >> 16) & 255u));
                    cs[q * 4 + 3] = f2bf((float)(w >> 24));
                }
                short8 w8;
                #pragma unroll
                for (int j = 0; j < 8; ++j) w8[j] = (short)cs[j];
                *(short8*)&adjT3[(t & 3) * K * 8 + m * 8] = w8;
            }
            if (t >= 512) {
                const int feat = t & 127, o = (t >> 7) & 3;
                short8 h1, h2;
                #pragma unroll
                for (int j = 0; j < 8; ++j) {
                    unsigned u = hp[(k0 + o * 8 + j) * 130 + feat];
                    h1[j] = (short)(u & 0xffffu);
                    h2[j] = (short)(u >> 16);
                }
                *(short8*)&xs3[o * 1024 + feat * 8] = h1;
                *(short8*)&xs3[4096 + o * 1024 + feat * 8] = h2;
            }
            __syncthreads();

            short8 afr = *(const short8*)&adjT3[lko * K * 8 + (rt3 * 16 + l15) * 8];
            #pragma unroll
            for (int s = 0; s < 2; ++s) {
                #pragma unroll
                for (int ct = 0; ct < 2; ++ct) {
                    int feat = cq3 * 32 + ct * 16 + l15;
                    short8 bfr = *(const short8*)&xs3[s * 4096 + lko * 1024 + feat * 8];
                    acc3[ct] = __builtin_amdgcn_mfma_f32_16x16x32_bf16(afr, bfr, acc3[ct], 0, 0, 0);
                }
            }
        }

        #pragma unroll
        for (int ct = 0; ct < 2; ++ct) {
            int feat = cq3 * 32 + ct * 16 + l15;
            size_t fb = (size_t)(feat >> 3) * 1024 + (feat & 7);
            int r0 = rt3 * 16 + lko * 4;
            #pragma unroll
            for (int r = 0; r < 4; ++r) {
                int m = g * K + r0 + r;
                float v = acc3[ct][r];
                unsigned short hi = f2bf(v);
                unsigned short lo = f2bf(v - bf2f(hi));
                AGGF3[(size_t)(m >> 7) * TILE_U32 + fb + (size_t)(m & 127) * 8] =
                    (unsigned)hi | ((unsigned)lo << 16);
            }
        }
    }
}

// -------------------- fused stage 3: gemm3 + pool3 + MLP + log_softmax -----
__global__ __launch_bounds__(1024) void k_stage3(const float* __restrict__ wp,
                                                 const float* __restrict__ bias,
                                                 const unsigned short* __restrict__ Wf,
                                                 const float* __restrict__ R,
                                                 const unsigned* __restrict__ XF2,
                                                 const unsigned* __restrict__ AGGF3,
                                                 const float* __restrict__ W1, const float* __restrict__ b1,
                                                 const float* __restrict__ W2, const float* __restrict__ b2,
                                                 const float* __restrict__ W3, const float* __restrict__ b3,
                                                 float* __restrict__ out) {
    __shared__ __align__(16) char smem[73728];
    __shared__ float sc[64];
    __shared__ unsigned long long keys[64];
    __shared__ int sel[32];
    __shared__ int inv[64];
    __shared__ float wn[128];
    __shared__ float gates[32];
    __shared__ float scp[4][64];
    __shared__ float pmx[8 * 128];
    __shared__ float psm[8 * 128];
    __shared__ float z[768];
    __shared__ float part[8][128];
    __shared__ float z2[128];
    __shared__ float z3[64];
    __shared__ float lg[10];
    __shared__ float lse;
    __shared__ float snorm_s;

    const int g = blockIdx.x, t = threadIdx.x;
    const int lane = t & 63, wv = t >> 6;
    const int l15 = lane & 15, lko = lane >> 4;
    const int rt = wv >> 2, cq = wv & 3;

    if (t < 64) {
        float v = wp[t] * wp[t] + wp[t + 64] * wp[t + 64];
        #pragma unroll
        for (int o = 32; o; o >>= 1) v += __shfl_xor(v, o);
        if (t == 0) snorm_s = sqrtf(v);
    }
    __syncthreads();
    if (t < 128) wn[t] = wp[t] / snorm_s;
    if (t < 512) z[t] = R[(size_t)g * 768 + t];

    f32x4 acc2[2];
    {
        uint4* Whi = (uint4*)smem;
        uint4* Afs = (uint4*)(smem + 65536);
        const unsigned short* Wlo = Wf + 32768;
        {
            const uint4* Wf4 = (const uint4*)Wf;
            #pragma unroll
            for (int i = 0; i < 4; ++i) Whi[t + i * 1024] = Wf4[t + i * 1024];
        }
        acc2[0] = f32x4{0.f, 0.f, 0.f, 0.f};
        acc2[1] = f32x4{0.f, 0.f, 0.f, 0.f};

        const int rowp = t & 63, kop = (t >> 6) & 3;

        for (int kt = 0; kt < 8; ++kt) {
            __syncthreads();
            if (t < 256) {
                const unsigned* P = (kt < 4) ? XF2 : AGGF3;
                int ko = (kt & 3) * 4 + kop;
                size_t idx = (size_t)(g >> 1) * TILE_U32 + (size_t)ko * 1024
                           + (size_t)((g & 1) * 64 + rowp) * 8;
                uint4 qa = *(const uint4*)(P + idx);
                uint4 qb = *(const uint4*)(P + idx + 4);
                short8 h1, h2;
                unpack2(qa, qb, h1, h2);
                int rw = rowp ^ (kop << 2);
                *reinterpret_cast<short8*>(&Afs[(0 * 4 + kop) * 64 + rw]) = h1;
                *reinterpret_cast<short8*>(&Afs[(1 * 4 + kop) * 64 + rw]) = h2;
            }
            __syncthreads();

            int row = (rt * 16 + l15) ^ (lko << 2);
            short8 a1f = *reinterpret_cast<const short8*>(&Afs[(0 * 4 + lko) * 64 + row]);
            short8 a2f = *reinterpret_cast<const short8*>(&Afs[(1 * 4 + lko) * 64 + row]);
            const int kog = kt * 4 + lko;
            #pragma unroll
            for (int ct = 0; ct < 2; ++ct) {
                int col = cq * 32 + ct * 16 + l15;
                short8 w1 = *reinterpret_cast<const short8*>(&Whi[kog * 128 + col]);
                short8 w2 = *reinterpret_cast<const short8*>(Wlo + ((size_t)kog * 128 + col) * 8);
                acc2[ct] = __builtin_amdgcn_mfma_f32_16x16x32_bf16(a1f, w1, acc2[ct], 0, 0, 0);
                acc2[ct] = __builtin_amdgcn_mfma_f32_16x16x32_bf16(a2f, w1, acc2[ct], 0, 0, 0);
                acc2[ct] = __builtin_amdgcn_mfma_f32_16x16x32_bf16(a1f, w2, acc2[ct], 0, 0, 0);
            }
        }
    }
    __syncthreads();

    #pragma unroll
    for (int ct = 0; ct < 2; ++ct) {
        float bv = bias[cq * 32 + ct * 16 + l15];
        #pragma unroll
        for (int r = 0; r < 4; ++r) acc2[ct][r] = fmaxf(acc2[ct][r] + bv, 0.f);
    }

    {
        float wnv[2];
        wnv[0] = wn[cq * 32 + l15];
        wnv[1] = wn[cq * 32 + 16 + l15];
        #pragma unroll
        for (int r = 0; r < 4; ++r) {
            float p = acc2[0][r] * wnv[0] + acc2[1][r] * wnv[1];
            p += __shfl_xor(p, 1); p += __shfl_xor(p, 2);
            p += __shfl_xor(p, 4); p += __shfl_xor(p, 8);
            if (l15 == 0) scp[cq][rt * 16 + lko * 4 + r] = p;
        }
    }
    __syncthreads();
    if (t < 64) sc[t] = scp[0][t] + scp[1][t] + scp[2][t] + scp[3][t];
    __syncthreads();

    if (t < 64) {
        unsigned u = __float_as_uint(sc[t]);
        u = (u & 0x80000000u) ? ~u : (u | 0x80000000u);
        keys[t] = ((unsigned long long)u << 32) | (unsigned)(~t);
    }
    bitonic_desc<64>((volatile unsigned long long*)keys, t);

    if (t < 32) sel[t] = (int)(~(unsigned)keys[t]);
    if (t < 64) inv[t] = -1;
    __syncthreads();
    if (t < 32) {
        inv[sel[t]] = t;
        gates[t] = tanhf(sc[sel[t]]);
    }
    __syncthreads();

    {
        unsigned* hp = (unsigned*)smem;
        #pragma unroll
        for (int r = 0; r < 4; ++r) {
            int rowg = rt * 16 + lko * 4 + r;
            int j = inv[rowg];
            if (j >= 0) {
                float gt = gates[j];
                #pragma unroll
                for (int ct = 0; ct < 2; ++ct) {
                    float v = acc2[ct][r] * gt;
                    unsigned short hi = f2bf(v);
                    unsigned short lo = f2bf(v - bf2f(hi));
                    hp[j * 130 + cq * 32 + ct * 16 + l15] = (unsigned)hi | ((unsigned)lo << 16);
                }
            }
        }
    }
    __syncthreads();

    {
        unsigned* hp = (unsigned*)smem;
        const int f = t & 127, seg = t >> 7;
        float mx = -INFINITY, sm = 0.f;
        for (int j = seg; j < 32; j += 8) {
            unsigned u = hp[j * 130 + f];
            float v = bf2f((unsigned short)(u & 0xffffu)) + bf2f((unsigned short)(u >> 16));
            mx = fmaxf(mx, v);
            sm += v;
        }
        pmx[seg * 128 + f] = mx;
        psm[seg * 128 + f] = sm;
    }
    __syncthreads();
    if (t < 128) {
        float m = -INFINITY, s = 0.f;
        #pragma unroll
        for (int q = 0; q < 8; ++q) {
            m = fmaxf(m, pmx[q * 128 + t]);
            s += psm[q * 128 + t];
        }
        z[512 + t] = m;
        z[640 + t] = s * (1.0f / 32);
    }
    __syncthreads();

    {
        const int f = t & 127, seg = t >> 7;
        float acc = 0.f;
        const float* w = W1 + (size_t)(seg * 96) * 128 + f;
        const float* zz = z + seg * 96;
        #pragma unroll 8
        for (int k = 0; k < 96; ++k) acc = fmaf(zz[k], w[(size_t)k * 128], acc);
        part[seg][f] = acc;
    }
    __syncthreads();
    if (t < 128) {
        float a = b1[t];
        #pragma unroll
        for (int q = 0; q < 8; ++q) a += part[q][t];
        z2[t] = fmaxf(a, 0.f);
    }
    __syncthreads();
    if (t < 512) {
        const int f = t & 63, seg = t >> 6;
        float acc = 0.f;
        const float* w = W2 + (size_t)(seg * 16) * 64 + f;
        const float* zz = z2 + seg * 16;
        #pragma unroll
        for (int k = 0; k < 16; ++k) acc = fmaf(zz[k], w[(size_t)k * 64], acc);
        part[seg][f] = acc;
    }
    __syncthreads();
    if (t < 64) {
        float a = b2[t];
        #pragma unroll
        for (int q = 0; q < 8; ++q) a += part[q][t];
        z3[t] = fmaxf(a, 0.f);
    }
    __syncthreads();
    if (t < 10) {
        float a3 = b3[t];
        #pragma unroll 8
        for (int k = 0; k < 64; ++k) a3 = fmaf(z3[k], W3[(size_t)k * 10 + t], a3);
        lg[t] = a3;
    }
    __syncthreads();
    if (t == 0) {
        float m = lg[0];
        for (int c = 1; c < 10; ++c) m = fmaxf(m, lg[c]);
        float s = 0.f;
        for (int c = 0; c < 10; ++c) s += expf(lg[c] - m);
        lse = m + logf(s);
    }
    __syncthreads();
    if (t < 10) out[(size_t)g * 10 + t] = lg[t] - lse;
}

extern "C" void kernel_launch(void* const* d_in, const int* in_sizes, int n_in,
                              void* d_out, int out_size, void* d_ws, size_t ws_size,
                              hipStream_t stream) {
    (void)in_sizes; (void)n_in; (void)out_size; (void)ws_size;
    const float* x    = (const float*)d_in[0];
    const int*   src  = (const int*)d_in[1];
    const int*   dst  = (const int*)d_in[2];
    const float* Wr1  = (const float*)d_in[3];
    const float* Wrel1= (const float*)d_in[4];
    const float* b1   = (const float*)d_in[5];
    const float* wp1  = (const float*)d_in[6];
    const float* Wr2  = (const float*)d_in[7];
    const float* Wrel2= (const float*)d_in[8];
    const float* b2   = (const float*)d_in[9];
    const float* wp2  = (const float*)d_in[10];
    const float* Wr3  = (const float*)d_in[11];
    const float* Wrel3= (const float*)d_in[12];
    const float* b3   = (const float*)d_in[13];
    const float* wp3  = (const float*)d_in[14];
    const float* L1w  = (const float*)d_in[15];
    const float* L1b  = (const float*)d_in[16];
    const float* L2w  = (const float*)d_in[17];
    const float* L2b  = (const float*)d_in[18];
    const float* L3w  = (const float*)d_in[19];
    const float* L3b  = (const float*)d_in[20];

    int*      cmap  = (int*)d_ws;                                  // G*256 i32
    float*    R     = (float*)(cmap + (size_t)G * 256);            // G*768 f32
    unsigned* AGGF2 = (unsigned*)(R + (size_t)G * 768);            // G tiles
    unsigned* XF    = AGGF2 + (size_t)G * TILE_U32;                // G tiles
    unsigned* XF2   = XF + (size_t)G * TILE_U32;                   // G/2 tiles
    unsigned* AGGF3 = XF2 + (size_t)(G / 2) * TILE_U32;            // G/2 tiles
    unsigned short* Wf = (unsigned short*)(AGGF3 + (size_t)(G / 2) * TILE_U32);
    float* out = (float*)d_out;

    k_wsplit<<<384, 256, 0, stream>>>(Wr1, Wrel1, Wr2, Wrel2, Wr3, Wrel3, Wf);

    k_stage1<<<G, 1024, 0, stream>>>(x, src, dst, wp1, b1, Wf, cmap, R, XF, AGGF2);
    k_stage2<<<G, 1024, 0, stream>>>(src, dst, wp2, b2, Wf + 65536, cmap, R, XF, AGGF2, XF2, AGGF3);
    k_stage3<<<G, 1024, 0, stream>>>(wp3, b3, Wf + 131072, R, XF2, AGGF3,
                                     L1w, L1b, L2w, L2b, L3w, L3b, out);
}